// Round 6
// baseline (495.515 us; speedup 1.0000x reference)
//
#include <hip/hip_runtime.h>

typedef __bf16 bf16;
typedef bf16 bf16x8 __attribute__((ext_vector_type(8)));
typedef bf16 bf16x4 __attribute__((ext_vector_type(4)));
typedef float f32x4 __attribute__((ext_vector_type(4)));
typedef short s16x4 __attribute__((ext_vector_type(4)));

#define AS1 __attribute__((address_space(1)))
#define AS3 __attribute__((address_space(3)))

__device__ __forceinline__ void load_lds16(const void* g, void* l) {
    __builtin_amdgcn_global_load_lds((const AS1 unsigned int*)g,
                                     (AS3 unsigned int*)l, 16, 0, 0);
}

// ---------------------------------------------------------------------------
// cast fp32 -> bf16 (vectorized)
// ---------------------------------------------------------------------------
__global__ __launch_bounds__(256) void cast_f32_bf16(
        const float* __restrict__ in, bf16* __restrict__ out, int n) {
    int i = (blockIdx.x * 256 + threadIdx.x) * 4;
    if (i < n) {
        float4 v = *(const float4*)(in + i);
        bf16x4 o = { (bf16)v.x, (bf16)v.y, (bf16)v.z, (bf16)v.w };
        *(bf16x4*)(out + i) = o;
    }
}

// ---------------------------------------------------------------------------
// transpose + cast: in fp32 [K][N] -> out bf16 [Np][K]; rows n in [N,Np) = 0
// ---------------------------------------------------------------------------
__global__ __launch_bounds__(256) void transpose_cast(
        const float* __restrict__ in, bf16* __restrict__ out,
        int K, int N, int Np) {
    __shared__ float tile[32][33];
    int bx = blockIdx.x * 32;  // n (output row)
    int by = blockIdx.y * 32;  // k
    int tx = threadIdx.x, ty = threadIdx.y;  // 32 x 8
#pragma unroll
    for (int i = 0; i < 4; ++i) {
        int k = by + ty + i * 8, n = bx + tx;
        float v = (k < K && n < N) ? in[(size_t)k * N + n] : 0.f;
        tile[ty + i * 8][tx] = v;
    }
    __syncthreads();
#pragma unroll
    for (int i = 0; i < 4; ++i) {
        int n = bx + ty + i * 8, k = by + tx;
        if (n < Np && k < K) out[(size_t)n * K + k] = (bf16)tile[tx][ty + i * 8];
    }
}

// ---------------------------------------------------------------------------
// transpose V slice of kvb -> vtb[(b*16+h)*128 + vd][kv]  (bf16 -> bf16)
// ---------------------------------------------------------------------------
__global__ __launch_bounds__(256) void transpose_v(
        const bf16* __restrict__ kvb, bf16* __restrict__ vtb) {
    __shared__ bf16 t[32][34];
    const int kv0 = blockIdx.x * 32;
    const int vd0 = blockIdx.y * 32;
    const int bh = blockIdx.z;                 // b*16 + h
    const int b = bh >> 4, h = bh & 15;
    const int tx = threadIdx.x, ty = threadIdx.y;  // 32 x 8
#pragma unroll
    for (int i = 0; i < 4; ++i)
        t[ty + i * 8][tx] = kvb[(size_t)(b * 2048 + kv0 + ty + i * 8) * 4096
                                + h * 256 + 128 + vd0 + tx];
    __syncthreads();
#pragma unroll
    for (int i = 0; i < 4; ++i)
        vtb[(size_t)(bh * 128 + vd0 + ty + i * 8) * 2048 + kv0 + tx] =
            t[tx][ty + i * 8];
}

// ---------------------------------------------------------------------------
// GEMM: C[M][N] = A[M][K] * Bt[N][K]^T . 128x128 tile, BK=64, 4 waves.
// ---------------------------------------------------------------------------
template <typename OutT>
__global__ __launch_bounds__(256) void gemm_bt(
        const bf16* __restrict__ A, const bf16* __restrict__ Bt,
        OutT* __restrict__ C, int K, int lda, int ldb, int ldc) {
    __shared__ __align__(16) bf16 As[128 * 64];
    __shared__ __align__(16) bf16 Bs[128 * 64];
    const int tid = threadIdx.x;
    const int wave = tid >> 6, lane = tid & 63;
    const int l15 = lane & 15, quad = lane >> 4;
    const int m0 = blockIdx.y * 128, n0 = blockIdx.x * 128;
    const int wm = (wave >> 1) * 64, wn = (wave & 1) * 64;

    f32x4 acc[4][4] = {};

    for (int k0 = 0; k0 < K; k0 += 64) {
#pragma unroll
        for (int c = 0; c < 4; ++c) {
            int e = wave * 2048 + c * 512 + lane * 8;
            int r = e >> 6, col = e & 63;
            load_lds16(A + (size_t)(m0 + r) * lda + k0 + col,
                       &As[wave * 2048 + c * 512]);
            load_lds16(Bt + (size_t)(n0 + r) * ldb + k0 + col,
                       &Bs[wave * 2048 + c * 512]);
        }
        __syncthreads();
#pragma unroll
        for (int kk = 0; kk < 64; kk += 32) {
            bf16x8 af[4], bf[4];
#pragma unroll
            for (int i = 0; i < 4; ++i)
                af[i] = *(const bf16x8*)&As[(wm + i * 16 + l15) * 64 + kk + quad * 8];
#pragma unroll
            for (int j = 0; j < 4; ++j)
                bf[j] = *(const bf16x8*)&Bs[(wn + j * 16 + l15) * 64 + kk + quad * 8];
#pragma unroll
            for (int i = 0; i < 4; ++i)
#pragma unroll
                for (int j = 0; j < 4; ++j)
                    acc[i][j] = __builtin_amdgcn_mfma_f32_16x16x32_bf16(
                        af[i], bf[j], acc[i][j], 0, 0, 0);
        }
        __syncthreads();
    }
#pragma unroll
    for (int i = 0; i < 4; ++i)
#pragma unroll
        for (int j = 0; j < 4; ++j) {
            int row = m0 + wm + i * 16 + quad * 4;
            int col = n0 + wn + j * 16 + l15;
#pragma unroll
            for (int r = 0; r < 4; ++r)
                C[(size_t)(row + r) * ldc + col] = (OutT)acc[i][j][r];
        }
}

// ---------------------------------------------------------------------------
// Fused down-proj GEMM: Bt rows [0,768)=w_q_down^T -> C1, [768,1408)=w_kv_down^T -> C2
// ---------------------------------------------------------------------------
__global__ __launch_bounds__(256) void gemm_down(
        const bf16* __restrict__ A, const bf16* __restrict__ Bt,
        bf16* __restrict__ C1, bf16* __restrict__ C2) {
    const int K = 2048, lda = 2048, ldb = 2048;
    __shared__ __align__(16) bf16 As[128 * 64];
    __shared__ __align__(16) bf16 Bs[128 * 64];
    const int tid = threadIdx.x;
    const int wave = tid >> 6, lane = tid & 63;
    const int l15 = lane & 15, quad = lane >> 4;
    const int m0 = blockIdx.y * 128, n0 = blockIdx.x * 128;
    const int wm = (wave >> 1) * 64, wn = (wave & 1) * 64;

    f32x4 acc[4][4] = {};

    for (int k0 = 0; k0 < K; k0 += 64) {
#pragma unroll
        for (int c = 0; c < 4; ++c) {
            int e = wave * 2048 + c * 512 + lane * 8;
            int r = e >> 6, col = e & 63;
            load_lds16(A + (size_t)(m0 + r) * lda + k0 + col,
                       &As[wave * 2048 + c * 512]);
            load_lds16(Bt + (size_t)(n0 + r) * ldb + k0 + col,
                       &Bs[wave * 2048 + c * 512]);
        }
        __syncthreads();
#pragma unroll
        for (int kk = 0; kk < 64; kk += 32) {
            bf16x8 af[4], bf[4];
#pragma unroll
            for (int i = 0; i < 4; ++i)
                af[i] = *(const bf16x8*)&As[(wm + i * 16 + l15) * 64 + kk + quad * 8];
#pragma unroll
            for (int j = 0; j < 4; ++j)
                bf[j] = *(const bf16x8*)&Bs[(wn + j * 16 + l15) * 64 + kk + quad * 8];
#pragma unroll
            for (int i = 0; i < 4; ++i)
#pragma unroll
                for (int j = 0; j < 4; ++j)
                    acc[i][j] = __builtin_amdgcn_mfma_f32_16x16x32_bf16(
                        af[i], bf[j], acc[i][j], 0, 0, 0);
        }
        __syncthreads();
    }
    bf16* Cp; int ldc, coff;
    if (n0 < 768) { Cp = C1; ldc = 768; coff = 0; }
    else          { Cp = C2; ldc = 640; coff = 768; }
#pragma unroll
    for (int i = 0; i < 4; ++i)
#pragma unroll
        for (int j = 0; j < 4; ++j) {
            int row = m0 + wm + i * 16 + quad * 4;
            int col = n0 + wn + j * 16 + l15 - coff;
#pragma unroll
            for (int r = 0; r < 4; ++r)
                Cp[(size_t)(row + r) * ldc + col] = (bf16)acc[i][j][r];
        }
}

// ---------------------------------------------------------------------------
// Flash attention (causal), SPLIT-K flash-decoding style.
// 16 WAVES / 256 q-rows per block (wave owns 16 q-rows); kv tiles of 64.
// Per (b,h): q-pairs k=0..7, T=4k+4 tiles, np=ceil(T/8) chunks.
// Grid 20x16x2 = 640 blocks, heavy-first.
// LDS = 64 KB EXACTLY (2-block/CU residency line; >64KB caps at 1 block):
//   K double-buffered 2x24KB; V SINGLE-buffered 16KB, staged during the
//   same tile's QK+softmax phase, waited just before PV.
// waves 0-7 stage K (3 DMAs, vmcnt(3)), waves 8-15 stage V (2, vmcnt(0) @PV).
// __launch_bounds__(1024, 4): VGPR cap 128 (min-waves 8 forced spill in r4).
// ---------------------------------------------------------------------------
__global__ __launch_bounds__(1024, 4) void mla_attention_split(
        const bf16* __restrict__ qb, const bf16* __restrict__ kvb,
        const bf16* __restrict__ cb, const bf16* __restrict__ vtb,
        bf16* __restrict__ ob, bf16* __restrict__ part_o,
        float* __restrict__ part_ml) {
    constexpr int S = 2048;
    // chunk tables (heavy chunks first in dispatch order)
    const signed char k_of[20]  = {7,7,7,7, 6,6,6,6, 5,5,5, 4,4,4, 3,3, 2,2, 1, 0};
    const signed char c_of[20]  = {0,1,2,3, 0,1,2,3, 0,1,2, 0,1,2, 0,1, 0,1, 0, 0};
    const signed char np_of[8]  = {1,1,2,2,3,3,4,4};
    const signed char pre_of[8] = {0,0,0,1,2,4,6,9};   // exclusive prefix of (np-1)

    const int k  = k_of[blockIdx.x], c = c_of[blockIdx.x];
    const int np = np_of[k];
    const int h = blockIdx.y, b = blockIdx.z;
    const int T  = 4 * k + 4;
    const int t0 = (c * T) / np, t1 = ((c + 1) * T) / np;
    const int q0 = k * 256;

    const int tid = threadIdx.x, wave = tid >> 6, lane = tid & 63;
    const int l15 = lane & 15, quad = lane >> 4;

    __shared__ __align__(16) bf16 Ks[2][24 * 512];  // frag-major, 2 x 24 KB
    __shared__ __align__(16) bf16 Vs[8 * 1024];     // frag-major, 16 KB single

    const int qrow = q0 + wave * 16 + l15;
    bf16x8 qf[6];
    {
        const bf16* qr = qb + (size_t)(b * S + qrow) * 3072 + h * 192;
#pragma unroll
        for (int ks = 0; ks < 6; ++ks)
            qf[ks] = *(const bf16x8*)(qr + ks * 32 + quad * 8);
    }

    const bf16* vt_head = vtb + (size_t)((b * 16 + h) * 128) * 2048;

    // waves 0-7: K frag-blocks mt=w>>1, ks=(w&1)*3+i (3 DMAs / tile)
    auto stage_k = [&](int kt, int bufi) {
        if (wave < 8) {
            const int kv0 = kt * 64;
            const int mt = wave >> 1;
            const size_t row = (size_t)(b * S + kv0 + mt * 16 + l15);
#pragma unroll
            for (int i = 0; i < 3; ++i) {
                const int ks = (wave & 1) * 3 + i;
                const bf16* g = (ks < 4)
                    ? kvb + row * 4096 + h * 256 + ks * 32 + quad * 8
                    : cb  + row * 640  + 512 + (ks - 4) * 32 + quad * 8;
                load_lds16(g, &Ks[bufi][(mt * 6 + ks) * 512]);
            }
        }
    };
    // waves 8-15: V vd-block nt=w-8 (2 DMAs / tile) into the single buffer
    auto stage_v = [&](int kt) {
        if (wave >= 8) {
            const int kv0 = kt * 64;
            const int nt = wave - 8;
#pragma unroll
            for (int i = 0; i < 2; ++i) {
                const bf16* g = vt_head + (size_t)(nt * 16 + l15) * 2048
                                + kv0 + (i * 4 + quad) * 8;
                load_lds16(g, &Vs[nt * 1024 + i * 512]);
            }
        }
    };

    f32x4 o[8] = {};
    float m_i = -1e30f, l_i = 0.f;
    const float sm_scale = 0.08838834764831845f * 1.4426950408889634f;
    const int qmin_w = q0 + wave * 16;

    // prologue: K depth-2, V for first tile (chunk len always >= 4)
    stage_k(t0, 0);
    stage_v(t0);
    stage_k(t0 + 1, 1);

    int cur = 0;
    for (int kt = t0; kt < t1; ++kt, cur ^= 1) {
        const int kv0 = kt * 64;

        // K-waves: wait for K(kt) only (K(kt+1) stays in flight)
        if (wave < 8) {
            if (kt + 1 < t1) asm volatile("s_waitcnt vmcnt(3)" ::: "memory");
            else             asm volatile("s_waitcnt vmcnt(0)" ::: "memory");
        }
        __builtin_amdgcn_s_barrier();    // K(kt) visible to all waves
        __builtin_amdgcn_sched_barrier(0);

        // S^T = K * Q^T ; C-layout: row(quad*4+r)=kv, col(l15)=qrow
        f32x4 s[4];
        __builtin_amdgcn_s_setprio(1);
#pragma unroll
        for (int mt = 0; mt < 4; ++mt) {
            f32x4 a = {};
#pragma unroll
            for (int ks = 0; ks < 6; ++ks) {
                bf16x8 kf = *(const bf16x8*)&Ks[cur][(mt * 6 + ks) * 512 + lane * 8];
                a = __builtin_amdgcn_mfma_f32_16x16x32_bf16(kf, qf[ks], a, 0, 0, 0);
            }
            s[mt] = a;
        }
        __builtin_amdgcn_s_setprio(0);

        // online softmax (lane owns qrow=l15's 16 kv values); tree reduces
        if (kv0 + 63 > qmin_w) {   // diagonal or fully-masked tile
#pragma unroll
            for (int mt = 0; mt < 4; ++mt)
#pragma unroll
                for (int r = 0; r < 4; ++r) {
                    int kvi = kv0 + mt * 16 + quad * 4 + r;
                    s[mt][r] = (kvi <= qrow) ? s[mt][r] * sm_scale : -1e30f;
                }
        } else {
#pragma unroll
            for (int mt = 0; mt < 4; ++mt)
#pragma unroll
                for (int r = 0; r < 4; ++r)
                    s[mt][r] = s[mt][r] * sm_scale;
        }
        float mx4[4];
#pragma unroll
        for (int mt = 0; mt < 4; ++mt)
            mx4[mt] = fmaxf(fmaxf(s[mt][0], s[mt][1]),
                            fmaxf(s[mt][2], s[mt][3]));
        float mx = fmaxf(fmaxf(mx4[0], mx4[1]), fmaxf(mx4[2], mx4[3]));
        mx = fmaxf(mx, __shfl_xor(mx, 16, 64));
        mx = fmaxf(mx, __shfl_xor(mx, 32, 64));
        float m_new = fmaxf(m_i, mx);
        float su4[4];
        bf16x4 pf[4];
#pragma unroll
        for (int mt = 0; mt < 4; ++mt) {
            float e0 = exp2f(s[mt][0] - m_new);
            float e1 = exp2f(s[mt][1] - m_new);
            float e2 = exp2f(s[mt][2] - m_new);
            float e3 = exp2f(s[mt][3] - m_new);
            su4[mt] = (e0 + e1) + (e2 + e3);
            pf[mt][0] = (bf16)e0; pf[mt][1] = (bf16)e1;
            pf[mt][2] = (bf16)e2; pf[mt][3] = (bf16)e3;
        }
        float su = (su4[0] + su4[1]) + (su4[2] + su4[3]);
        su += __shfl_xor(su, 16, 64);
        su += __shfl_xor(su, 32, 64);
        // defer-rescale: if no lane's max grew, alpha == 1 exactly -> skip
        if (__all(mx <= m_i)) {
            l_i += su;
        } else {
            float alpha = exp2f(m_i - m_new);
            l_i = l_i * alpha + su;
            m_i = m_new;
            float alpha_r[4];
#pragma unroll
            for (int r = 0; r < 4; ++r)
                alpha_r[r] = __shfl(alpha, quad * 4 + r, 64);
#pragma unroll
            for (int nt = 0; nt < 8; ++nt)
#pragma unroll
                for (int r = 0; r < 4; ++r) o[nt][r] *= alpha_r[r];
        }

        // V-waves: V(kt) retired (their only outstanding DMAs)
        if (wave >= 8) asm volatile("s_waitcnt vmcnt(0)" ::: "memory");
        __builtin_amdgcn_s_barrier();    // V(kt) visible to all waves
        __builtin_amdgcn_sched_barrier(0);

        // O += P * V
        __builtin_amdgcn_s_setprio(1);
#pragma unroll
        for (int ktk = 0; ktk < 4; ++ktk) {
            s16x4 a = __builtin_bit_cast(s16x4, pf[ktk]);
            const int voff = ktk * 256 + (quad >> 1) * 128 + l15 * 8 + (quad & 1) * 4;
#pragma unroll
            for (int nt = 0; nt < 8; ++nt) {
                s16x4 bfv = __builtin_bit_cast(s16x4,
                    *(const bf16x4*)&Vs[nt * 1024 + voff]);
                o[nt] = __builtin_amdgcn_mfma_f32_16x16x16bf16_1k(a, bfv, o[nt], 0, 0, 0);
            }
        }
        __builtin_amdgcn_s_setprio(0);

        // all reads of Ks[cur] and Vs done -> safe to re-stage both
        __builtin_amdgcn_s_barrier();
        if (kt + 2 < t1) stage_k(kt + 2, cur);
        if (kt + 1 < t1) stage_v(kt + 1);
    }

    // epilogue
    if (np == 1) {   // direct: normalized to ob
        float l_r[4];
#pragma unroll
        for (int r = 0; r < 4; ++r) l_r[r] = __shfl(l_i, quad * 4 + r, 64);
        bf16* obase = ob + (size_t)(b * S + q0 + wave * 16) * 2048 + h * 128;
#pragma unroll
        for (int nt = 0; nt < 8; ++nt)
#pragma unroll
            for (int r = 0; r < 4; ++r)
                obase[(size_t)(quad * 4 + r) * 2048 + nt * 16 + l15] =
                    (bf16)(o[nt][r] / l_r[r]);
    } else {       // partial
        const int bh = b * 16 + h;
        if (quad == 0) {
            const int qlocal = wave * 16 + l15;   // 0..255
            float* mlp = part_ml + ((size_t)(bh * 8 + k) * 4 + c) * 512;
            mlp[qlocal] = m_i;
            mlp[256 + qlocal] = l_i;
        }
        if (c == np - 1) {   // last chunk: O~ into ob (merged in place later)
            bf16* obase = ob + (size_t)(b * S + q0 + wave * 16) * 2048 + h * 128;
#pragma unroll
            for (int nt = 0; nt < 8; ++nt)
#pragma unroll
                for (int r = 0; r < 4; ++r)
                    obase[(size_t)(quad * 4 + r) * 2048 + nt * 16 + l15] =
                        (bf16)o[nt][r];
        } else {             // stored partial
            bf16* pb = part_o + (size_t)(bh * 12 + pre_of[k] + c) * 32768
                       + (size_t)(wave * 16) * 128;
#pragma unroll
            for (int nt = 0; nt < 8; ++nt)
#pragma unroll
                for (int r = 0; r < 4; ++r)
                    pb[(quad * 4 + r) * 128 + nt * 16 + l15] = (bf16)o[nt][r];
        }
    }
}

// ---------------------------------------------------------------------------
// Merge np partials for q-pair k>=2:
//   ob = (sum_c O_c~ a_c) / (sum_c l_c a_c), last chunk's O~ already in ob.
// 256 rows x 128 cols per slot; np in {2,3,4}.
// ---------------------------------------------------------------------------
__global__ __launch_bounds__(256) void mla_merge(
        const bf16* __restrict__ part_o, const float* __restrict__ part_ml,
        bf16* __restrict__ ob) {
    const signed char np_of[8]  = {1,1,2,2,3,3,4,4};
    const signed char pre_of[8] = {0,0,0,1,2,4,6,9};
    const int k = 2 + blockIdx.x;              // 2..7
    const int h = blockIdx.y, b = blockIdx.z;
    const int bh = b * 16 + h;
    const int np = np_of[k];
    const int row = threadIdx.x;               // 0..255

    const float* mlb = part_ml + (size_t)(bh * 8 + k) * 4 * 512;
    const float m0 = mlb[row],            l0 = mlb[256 + row];
    const float m1 = mlb[512 + row],      l1 = mlb[512 + 256 + row];
    const float m2 = (np > 2) ? mlb[1024 + row] : -1e30f;
    const float l2 = (np > 2) ? mlb[1024 + 256 + row] : 0.f;
    const float m3 = (np > 3) ? mlb[1536 + row] : -1e30f;
    const float l3 = (np > 3) ? mlb[1536 + 256 + row] : 0.f;
    const float M = fmaxf(fmaxf(m0, m1), fmaxf(m2, m3));
    float a0 = exp2f(m0 - M), a1 = exp2f(m1 - M);
    float a2 = exp2f(m2 - M), a3 = exp2f(m3 - M);
    const float inv = 1.f / (l0 * a0 + l1 * a1 + l2 * a2 + l3 * a3);
    a0 *= inv; a1 *= inv; a2 *= inv; a3 *= inv;
    const float alast = (np == 2) ? a1 : (np == 3) ? a2 : a3;

    const bf16* p0 = part_o + (size_t)(bh * 12 + pre_of[k]) * 32768 + row * 128;
    const bf16* p1 = p0 + 32768;
    const bf16* p2 = p1 + 32768;
    bf16* po = ob + (size_t)(b * 2048 + k * 256 + row) * 2048 + h * 128;
#pragma unroll
    for (int i = 0; i < 16; ++i) {
        bf16x8 vb = *(const bf16x8*)(po + i * 8);
        bf16x8 v0 = *(const bf16x8*)(p0 + i * 8);
        float acc[8];
#pragma unroll
        for (int u = 0; u < 8; ++u)
            acc[u] = (float)vb[u] * alast + (float)v0[u] * a0;
        if (np > 2) {
            bf16x8 v1 = *(const bf16x8*)(p1 + i * 8);
#pragma unroll
            for (int u = 0; u < 8; ++u) acc[u] += (float)v1[u] * a1;
        }
        if (np > 3) {
            bf16x8 v2 = *(const bf16x8*)(p2 + i * 8);
#pragma unroll
            for (int u = 0; u < 8; ++u) acc[u] += (float)v2[u] * a2;
        }
        bf16x8 om;
#pragma unroll
        for (int u = 0; u < 8; ++u) om[u] = (bf16)acc[u];
        *(bf16x8*)(po + i * 8) = om;
    }
}

// ---------------------------------------------------------------------------
// launch
// ---------------------------------------------------------------------------
extern "C" void kernel_launch(void* const* d_in, const int* in_sizes, int n_in,
                              void* d_out, int out_size, void* d_ws, size_t ws_size,
                              hipStream_t stream) {
    const float* x    = (const float*)d_in[0];
    const float* wqd  = (const float*)d_in[3];
    const float* wqu  = (const float*)d_in[4];
    const float* wkvd = (const float*)d_in[5];
    const float* wkvu = (const float*)d_in[6];
    const float* wout = (const float*)d_in[7];
    float* out = (float*)d_out;
    char* ws = (char*)d_ws;

    bf16* xb    = (bf16*)(ws + 0);          // 4096x2048 ; reused as vtb
    bf16* vtb   = (bf16*)(ws + 0);          // [b][h][128][2048] (aliases xb)
    bf16* wqdT  = (bf16*)(ws + 16777216);   // 768x2048  (dead at attention)
    bf16* wkvdT = (bf16*)(ws + 19922944);   // 640x2048  (dead at attention)
    bf16* wquT  = (bf16*)(ws + 22544384);   // 3072x768  (dead at attention)
    bf16* wkvuT = (bf16*)(ws + 27262976);   // 4096x512  (dead at attention)
    float* part_ml = (float*)(ws + 16777216); // 1024 slots x 512 f32 = 2 MB (aliases dead weights)
    bf16* part_o  = (bf16*)out;             // 384 x 32768 bf16 = 24 MB (out dead until final GEMM)
    bf16* woutT = (bf16*)(ws + 31457280);   // 2048x2048
    bf16* qd    = (bf16*)(ws + 39845888);   // 4096x768
    bf16* qb    = (bf16*)(ws + 46137344);   // 4096x3072
    bf16* cb    = (bf16*)(ws + 71303168);   // 4096x640
    bf16* kvb   = (bf16*)(ws + 76546048);   // 4096x4096
    bf16* attnb = (bf16*)(ws + 110100480);  // 4096x2048

    dim3 tb(32, 8);
    cast_f32_bf16<<<8192, 256, 0, stream>>>(x, xb, 8388608);
    transpose_cast<<<dim3(24, 64),  tb, 0, stream>>>(wqd,  wqdT,  2048, 768,  768);
    transpose_cast<<<dim3(20, 64),  tb, 0, stream>>>(wkvd, wkvdT, 2048, 576,  640);
    transpose_cast<<<dim3(96, 24),  tb, 0, stream>>>(wqu,  wquT,  768,  3072, 3072);
    transpose_cast<<<dim3(128, 16), tb, 0, stream>>>(wkvu, wkvuT, 512,  4096, 4096);
    transpose_cast<<<dim3(64, 64),  tb, 0, stream>>>(wout, woutT, 2048, 2048, 2048);

    gemm_down<<<dim3(11, 32), 256, 0, stream>>>(xb, wqdT, qd, cb);   // last reader of xb
    gemm_bt<bf16><<<dim3(24, 32), 256, 0, stream>>>(qd, wquT,  qb,  768, 768, 768, 3072);
    gemm_bt<bf16><<<dim3(32, 32), 256, 0, stream>>>(cb, wkvuT, kvb, 512, 640, 512, 4096);

    transpose_v<<<dim3(64, 4, 32), tb, 0, stream>>>(kvb, vtb);

    mla_attention_split<<<dim3(20, 16, 2), 1024, 0, stream>>>(
        qb, kvb, cb, vtb, attnb, part_o, part_ml);
    mla_merge<<<dim3(6, 16, 2), 256, 0, stream>>>(part_o, part_ml, attnb);

    gemm_bt<float><<<dim3(16, 32), 256, 0, stream>>>(attnb, woutT, out, 2048, 2048, 2048, 2048);
}

// Round 7
// 460.697 us; speedup vs baseline: 1.0756x; 1.0756x over previous
//
#include <hip/hip_runtime.h>

typedef __bf16 bf16;
typedef bf16 bf16x8 __attribute__((ext_vector_type(8)));
typedef bf16 bf16x4 __attribute__((ext_vector_type(4)));
typedef float f32x4 __attribute__((ext_vector_type(4)));
typedef short s16x4 __attribute__((ext_vector_type(4)));

#define AS1 __attribute__((address_space(1)))
#define AS3 __attribute__((address_space(3)))

__device__ __forceinline__ void load_lds16(const void* g, void* l) {
    __builtin_amdgcn_global_load_lds((const AS1 unsigned int*)g,
                                     (AS3 unsigned int*)l, 16, 0, 0);
}

// ---------------------------------------------------------------------------
// Fused prep: cast x->bf16 + 5 weight transposes, one flat-grid dispatch.
// Ranges: [0,8192) cast; then transposes wqd(1536) wkvd(1280) wqu(2304)
// wkvu(2048) wout(4096). All 256-thread blocks.
// ---------------------------------------------------------------------------
__device__ __forceinline__ void tc_body(
        const float* __restrict__ in, bf16* __restrict__ out,
        int K, int N, int Np, int bx, int by, int tid,
        float (*tile)[33]) {
    const int tx = tid & 31, ty = tid >> 5;   // 32 x 8
#pragma unroll
    for (int i = 0; i < 4; ++i) {
        int k = by + ty + i * 8, n = bx + tx;
        float v = (k < K && n < N) ? in[(size_t)k * N + n] : 0.f;
        tile[ty + i * 8][tx] = v;
    }
    __syncthreads();
#pragma unroll
    for (int i = 0; i < 4; ++i) {
        int n = bx + ty + i * 8, k = by + tx;
        if (n < Np && k < K) out[(size_t)n * K + k] = (bf16)tile[tx][ty + i * 8];
    }
}

__global__ __launch_bounds__(256) void prep_fused(
        const float* __restrict__ x,    bf16* __restrict__ xb,
        const float* __restrict__ wqd,  bf16* __restrict__ wqdT,
        const float* __restrict__ wkvd, bf16* __restrict__ wkvdT,
        const float* __restrict__ wqu,  bf16* __restrict__ wquT,
        const float* __restrict__ wkvu, bf16* __restrict__ wkvuT,
        const float* __restrict__ wout, bf16* __restrict__ woutT) {
    __shared__ float tile[32][33];
    const int tid = threadIdx.x;
    int r = blockIdx.x;
    if (r < 8192) {           // cast: 8388608 floats, 4/thread
        int i = (r * 256 + tid) * 4;
        float4 v = *(const float4*)(x + i);
        bf16x4 o = { (bf16)v.x, (bf16)v.y, (bf16)v.z, (bf16)v.w };
        *(bf16x4*)(xb + i) = o;
        return;
    }
    r -= 8192;
    if (r < 1536) { tc_body(wqd,  wqdT,  2048, 768,  768,  (r % 24) * 32, (r / 24) * 32, tid, tile); return; }
    r -= 1536;
    if (r < 1280) { tc_body(wkvd, wkvdT, 2048, 576,  640,  (r % 20) * 32, (r / 20) * 32, tid, tile); return; }
    r -= 1280;
    if (r < 2304) { tc_body(wqu,  wquT,  768,  3072, 3072, (r % 96) * 32, (r / 96) * 32, tid, tile); return; }
    r -= 2304;
    if (r < 2048) { tc_body(wkvu, wkvuT, 512,  4096, 4096, (r % 128) * 32, (r / 128) * 32, tid, tile); return; }
    r -= 2048;
    tc_body(wout, woutT, 2048, 2048, 2048, (r % 64) * 32, (r / 64) * 32, tid, tile);
}

// ---------------------------------------------------------------------------
// transpose V slice of kvb -> vtb[(b*16+h)*128 + vd][kv]  (bf16 -> bf16)
// ---------------------------------------------------------------------------
__global__ __launch_bounds__(256) void transpose_v(
        const bf16* __restrict__ kvb, bf16* __restrict__ vtb) {
    __shared__ bf16 t[32][34];
    const int kv0 = blockIdx.x * 32;
    const int vd0 = blockIdx.y * 32;
    const int bh = blockIdx.z;                 // b*16 + h
    const int b = bh >> 4, h = bh & 15;
    const int tx = threadIdx.x, ty = threadIdx.y;  // 32 x 8
#pragma unroll
    for (int i = 0; i < 4; ++i)
        t[ty + i * 8][tx] = kvb[(size_t)(b * 2048 + kv0 + ty + i * 8) * 4096
                                + h * 256 + 128 + vd0 + tx];
    __syncthreads();
#pragma unroll
    for (int i = 0; i < 4; ++i)
        vtb[(size_t)(bh * 128 + vd0 + ty + i * 8) * 2048 + kv0 + tx] =
            t[tx][ty + i * 8];
}

// ---------------------------------------------------------------------------
// GEMM body: C[M][N] = A[M][K] * Bt[N][K]^T . 128x128 tile, BK=64, 4 waves.
// ---------------------------------------------------------------------------
template <typename OutT>
__device__ __forceinline__ void gemm_bt_body(
        const bf16* __restrict__ A, const bf16* __restrict__ Bt,
        OutT* __restrict__ C, int K, int lda, int ldb, int ldc,
        int m0, int n0, bf16* As, bf16* Bs) {
    const int tid = threadIdx.x;
    const int wave = tid >> 6, lane = tid & 63;
    const int l15 = lane & 15, quad = lane >> 4;
    const int wm = (wave >> 1) * 64, wn = (wave & 1) * 64;

    f32x4 acc[4][4] = {};

    for (int k0 = 0; k0 < K; k0 += 64) {
#pragma unroll
        for (int c = 0; c < 4; ++c) {
            int e = wave * 2048 + c * 512 + lane * 8;
            int r = e >> 6, col = e & 63;
            load_lds16(A + (size_t)(m0 + r) * lda + k0 + col,
                       &As[wave * 2048 + c * 512]);
            load_lds16(Bt + (size_t)(n0 + r) * ldb + k0 + col,
                       &Bs[wave * 2048 + c * 512]);
        }
        __syncthreads();
#pragma unroll
        for (int kk = 0; kk < 64; kk += 32) {
            bf16x8 af[4], bf[4];
#pragma unroll
            for (int i = 0; i < 4; ++i)
                af[i] = *(const bf16x8*)&As[(wm + i * 16 + l15) * 64 + kk + quad * 8];
#pragma unroll
            for (int j = 0; j < 4; ++j)
                bf[j] = *(const bf16x8*)&Bs[(wn + j * 16 + l15) * 64 + kk + quad * 8];
#pragma unroll
            for (int i = 0; i < 4; ++i)
#pragma unroll
                for (int j = 0; j < 4; ++j)
                    acc[i][j] = __builtin_amdgcn_mfma_f32_16x16x32_bf16(
                        af[i], bf[j], acc[i][j], 0, 0, 0);
        }
        __syncthreads();
    }
#pragma unroll
    for (int i = 0; i < 4; ++i)
#pragma unroll
        for (int j = 0; j < 4; ++j) {
            int row = m0 + wm + i * 16 + quad * 4;
            int col = n0 + wn + j * 16 + l15;
#pragma unroll
            for (int r = 0; r < 4; ++r)
                C[(size_t)(row + r) * ldc + col] = (OutT)acc[i][j][r];
        }
}

template <typename OutT>
__global__ __launch_bounds__(256) void gemm_bt(
        const bf16* __restrict__ A, const bf16* __restrict__ Bt,
        OutT* __restrict__ C, int K, int lda, int ldb, int ldc) {
    __shared__ __align__(16) bf16 As[128 * 64];
    __shared__ __align__(16) bf16 Bs[128 * 64];
    gemm_bt_body<OutT>(A, Bt, C, K, lda, ldb, ldc,
                       blockIdx.y * 128, blockIdx.x * 128, As, Bs);
}

// ---------------------------------------------------------------------------
// Merged up-proj GEMMs (both depend only on gemm_down outputs):
//   blockIdx.x <  24 : qb  = qd @ wquT^T   (K=768)
//   blockIdx.x >= 24 : kvb = cb @ wkvuT^T  (K=512)
// One dispatch -> tails overlap.
// ---------------------------------------------------------------------------
__global__ __launch_bounds__(256) void gemm_up(
        const bf16* __restrict__ qd, const bf16* __restrict__ wquT,
        bf16* __restrict__ qb,
        const bf16* __restrict__ cb, const bf16* __restrict__ wkvuT,
        bf16* __restrict__ kvb) {
    __shared__ __align__(16) bf16 As[128 * 64];
    __shared__ __align__(16) bf16 Bs[128 * 64];
    if (blockIdx.x < 24)
        gemm_bt_body<bf16>(qd, wquT, qb, 768, 768, 768, 3072,
                           blockIdx.y * 128, blockIdx.x * 128, As, Bs);
    else
        gemm_bt_body<bf16>(cb, wkvuT, kvb, 512, 640, 512, 4096,
                           blockIdx.y * 128, (blockIdx.x - 24) * 128, As, Bs);
}

// ---------------------------------------------------------------------------
// Fused down-proj GEMM: Bt rows [0,768)=w_q_down^T -> C1, [768,1408)=w_kv_down^T -> C2
// ---------------------------------------------------------------------------
__global__ __launch_bounds__(256) void gemm_down(
        const bf16* __restrict__ A, const bf16* __restrict__ Bt,
        bf16* __restrict__ C1, bf16* __restrict__ C2) {
    __shared__ __align__(16) bf16 As[128 * 64];
    __shared__ __align__(16) bf16 Bs[128 * 64];
    const int n0 = blockIdx.x * 128;
    if (n0 < 768)
        gemm_bt_body<bf16>(A, Bt, C1, 2048, 2048, 2048, 768,
                           blockIdx.y * 128, n0, As, Bs);
    else {
        // columns [768,1408) of the fused Bt -> C2 with its own ldc
        const int tid = threadIdx.x;
        const int wave = tid >> 6, lane = tid & 63;
        const int l15 = lane & 15, quad = lane >> 4;
        const int m0 = blockIdx.y * 128;
        const int wm = (wave >> 1) * 64, wn = (wave & 1) * 64;
        f32x4 acc[4][4] = {};
        for (int k0 = 0; k0 < 2048; k0 += 64) {
#pragma unroll
            for (int c = 0; c < 4; ++c) {
                int e = wave * 2048 + c * 512 + lane * 8;
                int r = e >> 6, col = e & 63;
                load_lds16(A + (size_t)(m0 + r) * 2048 + k0 + col,
                           &As[wave * 2048 + c * 512]);
                load_lds16(Bt + (size_t)(n0 + r) * 2048 + k0 + col,
                           &Bs[wave * 2048 + c * 512]);
            }
            __syncthreads();
#pragma unroll
            for (int kk = 0; kk < 64; kk += 32) {
                bf16x8 af[4], bf[4];
#pragma unroll
                for (int i = 0; i < 4; ++i)
                    af[i] = *(const bf16x8*)&As[(wm + i * 16 + l15) * 64 + kk + quad * 8];
#pragma unroll
                for (int j = 0; j < 4; ++j)
                    bf[j] = *(const bf16x8*)&Bs[(wn + j * 16 + l15) * 64 + kk + quad * 8];
#pragma unroll
                for (int i = 0; i < 4; ++i)
#pragma unroll
                    for (int j = 0; j < 4; ++j)
                        acc[i][j] = __builtin_amdgcn_mfma_f32_16x16x32_bf16(
                            af[i], bf[j], acc[i][j], 0, 0, 0);
            }
            __syncthreads();
        }
#pragma unroll
        for (int i = 0; i < 4; ++i)
#pragma unroll
            for (int j = 0; j < 4; ++j) {
                int row = m0 + wm + i * 16 + quad * 4;
                int col = n0 + wn + j * 16 + l15 - 768;
#pragma unroll
                for (int r = 0; r < 4; ++r)
                    C2[(size_t)(row + r) * 640 + col] = (bf16)acc[i][j][r];
            }
    }
}

// ---------------------------------------------------------------------------
// Flash attention (causal), SPLIT-K flash-decoding style.  [round-5 config:
// best measured 144us]
// 16 WAVES / 256 q-rows per block (wave owns 16 q-rows); kv tiles of 64.
// Per (b,h): q-pairs k=0..7, T=4k+4 tiles, np=ceil(T/8) chunks.
// Grid 20x16x2 = 640 blocks, heavy-first. K/V both double-buffered, 80KB.
// waves 0-7 stage K (3 DMAs/tile, vmcnt(3)); waves 8-15 stage V (2, vmcnt(2)).
// NOTE: residency is 1 block/CU regardless of LDS (total regs ~96-128/wave:
// reported 64 arch VGPR + accumulators on the unified file) -- r6 measured.
// __launch_bounds__(1024, 4): VGPR cap 128 (min-waves 8 forced spill in r4).
// ---------------------------------------------------------------------------
__global__ __launch_bounds__(1024, 4) void mla_attention_split(
        const bf16* __restrict__ qb, const bf16* __restrict__ kvb,
        const bf16* __restrict__ cb, const bf16* __restrict__ vtb,
        bf16* __restrict__ ob, bf16* __restrict__ part_o,
        float* __restrict__ part_ml) {
    constexpr int S = 2048;
    // chunk tables (heavy chunks first in dispatch order)
    const signed char k_of[20]  = {7,7,7,7, 6,6,6,6, 5,5,5, 4,4,4, 3,3, 2,2, 1, 0};
    const signed char c_of[20]  = {0,1,2,3, 0,1,2,3, 0,1,2, 0,1,2, 0,1, 0,1, 0, 0};
    const signed char np_of[8]  = {1,1,2,2,3,3,4,4};
    const signed char pre_of[8] = {0,0,0,1,2,4,6,9};   // exclusive prefix of (np-1)

    const int k  = k_of[blockIdx.x], c = c_of[blockIdx.x];
    const int np = np_of[k];
    const int h = blockIdx.y, b = blockIdx.z;
    const int T  = 4 * k + 4;
    const int t0 = (c * T) / np, t1 = ((c + 1) * T) / np;
    const int q0 = k * 256;

    const int tid = threadIdx.x, wave = tid >> 6, lane = tid & 63;
    const int l15 = lane & 15, quad = lane >> 4;

    __shared__ __align__(16) bf16 Ks[2][24 * 512];  // frag-major, 2 x 24 KB
    __shared__ __align__(16) bf16 Vs[2][8 * 1024];  // frag-major, 2 x 16 KB

    const int qrow = q0 + wave * 16 + l15;
    bf16x8 qf[6];
    {
        const bf16* qr = qb + (size_t)(b * S + qrow) * 3072 + h * 192;
#pragma unroll
        for (int ks = 0; ks < 6; ++ks)
            qf[ks] = *(const bf16x8*)(qr + ks * 32 + quad * 8);
    }

    const bf16* vt_head = vtb + (size_t)((b * 16 + h) * 128) * 2048;

    // stage kv tile kt into buffer bufi.
    // waves 0-7: K frag-blocks mt=w>>1, ks=(w&1)*3+i (3 DMAs)
    // waves 8-15: V vd-block nt=w-8 (2 DMAs)
    auto stage = [&](int kt, int bufi) {
        const int kv0 = kt * 64;
        if (wave < 8) {
            const int mt = wave >> 1;
            const size_t row = (size_t)(b * S + kv0 + mt * 16 + l15);
#pragma unroll
            for (int i = 0; i < 3; ++i) {
                const int ks = (wave & 1) * 3 + i;
                const bf16* g = (ks < 4)
                    ? kvb + row * 4096 + h * 256 + ks * 32 + quad * 8
                    : cb  + row * 640  + 512 + (ks - 4) * 32 + quad * 8;
                load_lds16(g, &Ks[bufi][(mt * 6 + ks) * 512]);
            }
        } else {
            const int nt = wave - 8;
#pragma unroll
            for (int i = 0; i < 2; ++i) {
                const bf16* g = vt_head + (size_t)(nt * 16 + l15) * 2048
                                + kv0 + (i * 4 + quad) * 8;
                load_lds16(g, &Vs[bufi][nt * 1024 + i * 512]);
            }
        }
    };

    f32x4 o[8] = {};
    float m_i = -1e30f, l_i = 0.f;
    const float sm_scale = 0.08838834764831845f * 1.4426950408889634f;
    const int qmin_w = q0 + wave * 16;

    // prologue: fill both buffers (depth-2 pipeline); chunk len always >= 4
    stage(t0, 0);
    stage(t0 + 1, 1);

    int cur = 0;
    for (int kt = t0; kt < t1; ++kt, cur ^= 1) {
        const int kv0 = kt * 64;

        // wait for THIS tile's DMAs only (FIFO; leave next tile in flight)
        if (kt + 1 < t1) {
            if (wave < 8) asm volatile("s_waitcnt vmcnt(3)" ::: "memory");
            else          asm volatile("s_waitcnt vmcnt(2)" ::: "memory");
        } else {
            asm volatile("s_waitcnt vmcnt(0)" ::: "memory");
        }
        __builtin_amdgcn_s_barrier();    // all waves' tile-kt DMAs visible
        __builtin_amdgcn_sched_barrier(0);

        // S^T = K * Q^T ; C-layout: row(quad*4+r)=kv, col(l15)=qrow
        f32x4 s[4];
        __builtin_amdgcn_s_setprio(1);
#pragma unroll
        for (int mt = 0; mt < 4; ++mt) {
            f32x4 a = {};
#pragma unroll
            for (int ks = 0; ks < 6; ++ks) {
                bf16x8 kf = *(const bf16x8*)&Ks[cur][(mt * 6 + ks) * 512 + lane * 8];
                a = __builtin_amdgcn_mfma_f32_16x16x32_bf16(kf, qf[ks], a, 0, 0, 0);
            }
            s[mt] = a;
        }
        __builtin_amdgcn_s_setprio(0);

        // online softmax (lane owns qrow=l15's 16 kv values); tree reduces
        if (kv0 + 63 > qmin_w) {   // diagonal or fully-masked tile
#pragma unroll
            for (int mt = 0; mt < 4; ++mt)
#pragma unroll
                for (int r = 0; r < 4; ++r) {
                    int kvi = kv0 + mt * 16 + quad * 4 + r;
                    s[mt][r] = (kvi <= qrow) ? s[mt][r] * sm_scale : -1e30f;
                }
        } else {
#pragma unroll
            for (int mt = 0; mt < 4; ++mt)
#pragma unroll
                for (int r = 0; r < 4; ++r)
                    s[mt][r] = s[mt][r] * sm_scale;
        }
        float mx4[4];
#pragma unroll
        for (int mt = 0; mt < 4; ++mt)
            mx4[mt] = fmaxf(fmaxf(s[mt][0], s[mt][1]),
                            fmaxf(s[mt][2], s[mt][3]));
        float mx = fmaxf(fmaxf(mx4[0], mx4[1]), fmaxf(mx4[2], mx4[3]));
        mx = fmaxf(mx, __shfl_xor(mx, 16, 64));
        mx = fmaxf(mx, __shfl_xor(mx, 32, 64));
        float m_new = fmaxf(m_i, mx);
        float su4[4];
        bf16x4 pf[4];
#pragma unroll
        for (int mt = 0; mt < 4; ++mt) {
            float e0 = exp2f(s[mt][0] - m_new);
            float e1 = exp2f(s[mt][1] - m_new);
            float e2 = exp2f(s[mt][2] - m_new);
            float e3 = exp2f(s[mt][3] - m_new);
            su4[mt] = (e0 + e1) + (e2 + e3);
            pf[mt][0] = (bf16)e0; pf[mt][1] = (bf16)e1;
            pf[mt][2] = (bf16)e2; pf[mt][3] = (bf16)e3;
        }
        float su = (su4[0] + su4[1]) + (su4[2] + su4[3]);
        su += __shfl_xor(su, 16, 64);
        su += __shfl_xor(su, 32, 64);
        // defer-rescale: if no lane's max grew, alpha == 1 exactly -> skip
        if (__all(mx <= m_i)) {
            l_i += su;
        } else {
            float alpha = exp2f(m_i - m_new);
            l_i = l_i * alpha + su;
            m_i = m_new;
            float alpha_r[4];
#pragma unroll
            for (int r = 0; r < 4; ++r)
                alpha_r[r] = __shfl(alpha, quad * 4 + r, 64);
#pragma unroll
            for (int nt = 0; nt < 8; ++nt)
#pragma unroll
                for (int r = 0; r < 4; ++r) o[nt][r] *= alpha_r[r];
        }

        // O += P * V
        __builtin_amdgcn_s_setprio(1);
#pragma unroll
        for (int ktk = 0; ktk < 4; ++ktk) {
            s16x4 a = __builtin_bit_cast(s16x4, pf[ktk]);
            const int voff = ktk * 256 + (quad >> 1) * 128 + l15 * 8 + (quad & 1) * 4;
#pragma unroll
            for (int nt = 0; nt < 8; ++nt) {
                s16x4 bfv = __builtin_bit_cast(s16x4,
                    *(const bf16x4*)&Vs[cur][nt * 1024 + voff]);
                o[nt] = __builtin_amdgcn_mfma_f32_16x16x16bf16_1k(a, bfv, o[nt], 0, 0, 0);
            }
        }
        __builtin_amdgcn_s_setprio(0);

        // all waves done reading buf[cur] -> safe to re-stage it
        __builtin_amdgcn_s_barrier();
        if (kt + 2 < t1) stage(kt + 2, cur);
    }

    // epilogue
    if (np == 1) {   // direct: normalized to ob
        float l_r[4];
#pragma unroll
        for (int r = 0; r < 4; ++r) l_r[r] = __shfl(l_i, quad * 4 + r, 64);
        bf16* obase = ob + (size_t)(b * S + q0 + wave * 16) * 2048 + h * 128;
#pragma unroll
        for (int nt = 0; nt < 8; ++nt)
#pragma unroll
            for (int r = 0; r < 4; ++r)
                obase[(size_t)(quad * 4 + r) * 2048 + nt * 16 + l15] =
                    (bf16)(o[nt][r] / l_r[r]);
    } else {       // partial
        const int bh = b * 16 + h;
        if (quad == 0) {
            const int qlocal = wave * 16 + l15;   // 0..255
            float* mlp = part_ml + ((size_t)(bh * 8 + k) * 4 + c) * 512;
            mlp[qlocal] = m_i;
            mlp[256 + qlocal] = l_i;
        }
        if (c == np - 1) {   // last chunk: O~ into ob (merged in place later)
            bf16* obase = ob + (size_t)(b * S + q0 + wave * 16) * 2048 + h * 128;
#pragma unroll
            for (int nt = 0; nt < 8; ++nt)
#pragma unroll
                for (int r = 0; r < 4; ++r)
                    obase[(size_t)(quad * 4 + r) * 2048 + nt * 16 + l15] =
                        (bf16)o[nt][r];
        } else {             // stored partial
            bf16* pb = part_o + (size_t)(bh * 12 + pre_of[k] + c) * 32768
                       + (size_t)(wave * 16) * 128;
#pragma unroll
            for (int nt = 0; nt < 8; ++nt)
#pragma unroll
                for (int r = 0; r < 4; ++r)
                    pb[(quad * 4 + r) * 128 + nt * 16 + l15] = (bf16)o[nt][r];
        }
    }
}

// ---------------------------------------------------------------------------
// Merge np partials for q-pair k>=2:
//   ob = (sum_c O_c~ a_c) / (sum_c l_c a_c), last chunk's O~ already in ob.
// 256 rows x 128 cols per slot; np in {2,3,4}.
// ---------------------------------------------------------------------------
__global__ __launch_bounds__(256) void mla_merge(
        const bf16* __restrict__ part_o, const float* __restrict__ part_ml,
        bf16* __restrict__ ob) {
    const signed char np_of[8]  = {1,1,2,2,3,3,4,4};
    const signed char pre_of[8] = {0,0,0,1,2,4,6,9};
    const int k = 2 + blockIdx.x;              // 2..7
    const int h = blockIdx.y, b = blockIdx.z;
    const int bh = b * 16 + h;
    const int np = np_of[k];
    const int row = threadIdx.x;               // 0..255

    const float* mlb = part_ml + (size_t)(bh * 8 + k) * 4 * 512;
    const float m0 = mlb[row],            l0 = mlb[256 + row];
    const float m1 = mlb[512 + row],      l1 = mlb[512 + 256 + row];
    const float m2 = (np > 2) ? mlb[1024 + row] : -1e30f;
    const float l2 = (np > 2) ? mlb[1024 + 256 + row] : 0.f;
    const float m3 = (np > 3) ? mlb[1536 + row] : -1e30f;
    const float l3 = (np > 3) ? mlb[1536 + 256 + row] : 0.f;
    const float M = fmaxf(fmaxf(m0, m1), fmaxf(m2, m3));
    float a0 = exp2f(m0 - M), a1 = exp2f(m1 - M);
    float a2 = exp2f(m2 - M), a3 = exp2f(m3 - M);
    const float inv = 1.f / (l0 * a0 + l1 * a1 + l2 * a2 + l3 * a3);
    a0 *= inv; a1 *= inv; a2 *= inv; a3 *= inv;
    const float alast = (np == 2) ? a1 : (np == 3) ? a2 : a3;

    const bf16* p0 = part_o + (size_t)(bh * 12 + pre_of[k]) * 32768 + row * 128;
    const bf16* p1 = p0 + 32768;
    const bf16* p2 = p1 + 32768;
    bf16* po = ob + (size_t)(b * 2048 + k * 256 + row) * 2048 + h * 128;
#pragma unroll
    for (int i = 0; i < 16; ++i) {
        bf16x8 vb = *(const bf16x8*)(po + i * 8);
        bf16x8 v0 = *(const bf16x8*)(p0 + i * 8);
        float acc[8];
#pragma unroll
        for (int u = 0; u < 8; ++u)
            acc[u] = (float)vb[u] * alast + (float)v0[u] * a0;
        if (np > 2) {
            bf16x8 v1 = *(const bf16x8*)(p1 + i * 8);
#pragma unroll
            for (int u = 0; u < 8; ++u) acc[u] += (float)v1[u] * a1;
        }
        if (np > 3) {
            bf16x8 v2 = *(const bf16x8*)(p2 + i * 8);
#pragma unroll
            for (int u = 0; u < 8; ++u) acc[u] += (float)v2[u] * a2;
        }
        bf16x8 om;
#pragma unroll
        for (int u = 0; u < 8; ++u) om[u] = (bf16)acc[u];
        *(bf16x8*)(po + i * 8) = om;
    }
}

// ---------------------------------------------------------------------------
// launch
// ---------------------------------------------------------------------------
extern "C" void kernel_launch(void* const* d_in, const int* in_sizes, int n_in,
                              void* d_out, int out_size, void* d_ws, size_t ws_size,
                              hipStream_t stream) {
    const float* x    = (const float*)d_in[0];
    const float* wqd  = (const float*)d_in[3];
    const float* wqu  = (const float*)d_in[4];
    const float* wkvd = (const float*)d_in[5];
    const float* wkvu = (const float*)d_in[6];
    const float* wout = (const float*)d_in[7];
    float* out = (float*)d_out;
    char* ws = (char*)d_ws;

    bf16* xb    = (bf16*)(ws + 0);          // 4096x2048 ; reused as vtb
    bf16* vtb   = (bf16*)(ws + 0);          // [b][h][128][2048] (aliases xb)
    bf16* wqdT  = (bf16*)(ws + 16777216);   // 768x2048  (dead at attention)
    bf16* wkvdT = (bf16*)(ws + 19922944);   // 640x2048  (dead at attention)
    bf16* wquT  = (bf16*)(ws + 22544384);   // 3072x768  (dead at attention)
    bf16* wkvuT = (bf16*)(ws + 27262976);   // 4096x512  (dead at attention)
    float* part_ml = (float*)(ws + 16777216); // 1024 slots x 512 f32 = 2 MB (aliases dead weights)
    bf16* part_o  = (bf16*)out;             // 384 x 32768 bf16 = 24 MB (out dead until final GEMM)
    bf16* woutT = (bf16*)(ws + 31457280);   // 2048x2048
    bf16* qd    = (bf16*)(ws + 39845888);   // 4096x768
    bf16* qb    = (bf16*)(ws + 46137344);   // 4096x3072
    bf16* cb    = (bf16*)(ws + 71303168);   // 4096x640
    bf16* kvb   = (bf16*)(ws + 76546048);   // 4096x4096
    bf16* attnb = (bf16*)(ws + 110100480);  // 4096x2048

    // one fused prep dispatch: cast + all 5 weight transposes
    prep_fused<<<19456, 256, 0, stream>>>(x, xb, wqd, wqdT, wkvd, wkvdT,
                                          wqu, wquT, wkvu, wkvuT, wout, woutT);

    gemm_down<<<dim3(11, 32), 256, 0, stream>>>(xb, wqdT, qd, cb);   // last reader of xb
    gemm_up<<<dim3(56, 32), 256, 0, stream>>>(qd, wquT, qb, cb, wkvuT, kvb);

    transpose_v<<<dim3(64, 4, 32), dim3(32, 8), 0, stream>>>(kvb, vtb);

    mla_attention_split<<<dim3(20, 16, 2), 1024, 0, stream>>>(
        qb, kvb, cb, vtb, attnb, part_o, part_ml);
    mla_merge<<<dim3(6, 16, 2), 256, 0, stream>>>(part_o, part_ml, attnb);

    gemm_bt<float><<<dim3(16, 32), 256, 0, stream>>>(attnb, woutT, out, 2048, 2048, 2048, 2048);
}

// Round 8
// 455.652 us; speedup vs baseline: 1.0875x; 1.0111x over previous
//
#include <hip/hip_runtime.h>

typedef __bf16 bf16;
typedef bf16 bf16x8 __attribute__((ext_vector_type(8)));
typedef bf16 bf16x4 __attribute__((ext_vector_type(4)));
typedef float f32x4 __attribute__((ext_vector_type(4)));
typedef short s16x4 __attribute__((ext_vector_type(4)));

#define AS1 __attribute__((address_space(1)))
#define AS3 __attribute__((address_space(3)))

__device__ __forceinline__ void load_lds16(const void* g, void* l) {
    __builtin_amdgcn_global_load_lds((const AS1 unsigned int*)g,
                                     (AS3 unsigned int*)l, 16, 0, 0);
}

// ---------------------------------------------------------------------------
// Fused prep: cast x->bf16 + 5 weight transposes, one flat-grid dispatch.
// ---------------------------------------------------------------------------
__device__ __forceinline__ void tc_body(
        const float* __restrict__ in, bf16* __restrict__ out,
        int K, int N, int Np, int bx, int by, int tid,
        float (*tile)[33]) {
    const int tx = tid & 31, ty = tid >> 5;   // 32 x 8
#pragma unroll
    for (int i = 0; i < 4; ++i) {
        int k = by + ty + i * 8, n = bx + tx;
        float v = (k < K && n < N) ? in[(size_t)k * N + n] : 0.f;
        tile[ty + i * 8][tx] = v;
    }
    __syncthreads();
#pragma unroll
    for (int i = 0; i < 4; ++i) {
        int n = bx + ty + i * 8, k = by + tx;
        if (n < Np && k < K) out[(size_t)n * K + k] = (bf16)tile[tx][ty + i * 8];
    }
}

__global__ __launch_bounds__(256) void prep_fused(
        const float* __restrict__ x,    bf16* __restrict__ xb,
        const float* __restrict__ wqd,  bf16* __restrict__ wqdT,
        const float* __restrict__ wkvd, bf16* __restrict__ wkvdT,
        const float* __restrict__ wqu,  bf16* __restrict__ wquT,
        const float* __restrict__ wkvu, bf16* __restrict__ wkvuT,
        const float* __restrict__ wout, bf16* __restrict__ woutT) {
    __shared__ float tile[32][33];
    const int tid = threadIdx.x;
    int r = blockIdx.x;
    if (r < 8192) {           // cast: 8388608 floats, 4/thread
        int i = (r * 256 + tid) * 4;
        float4 v = *(const float4*)(x + i);
        bf16x4 o = { (bf16)v.x, (bf16)v.y, (bf16)v.z, (bf16)v.w };
        *(bf16x4*)(xb + i) = o;
        return;
    }
    r -= 8192;
    if (r < 1536) { tc_body(wqd,  wqdT,  2048, 768,  768,  (r % 24) * 32, (r / 24) * 32, tid, tile); return; }
    r -= 1536;
    if (r < 1280) { tc_body(wkvd, wkvdT, 2048, 576,  640,  (r % 20) * 32, (r / 20) * 32, tid, tile); return; }
    r -= 1280;
    if (r < 2304) { tc_body(wqu,  wquT,  768,  3072, 3072, (r % 96) * 32, (r / 96) * 32, tid, tile); return; }
    r -= 2304;
    if (r < 2048) { tc_body(wkvu, wkvuT, 512,  4096, 4096, (r % 128) * 32, (r / 128) * 32, tid, tile); return; }
    r -= 2048;
    tc_body(wout, woutT, 2048, 2048, 2048, (r % 64) * 32, (r / 64) * 32, tid, tile);
}

// ---------------------------------------------------------------------------
// GEMM core: acc[4][4] = A[M][K] * Bt[N][K]^T tile (128x128, BK=64, 4 waves).
// ---------------------------------------------------------------------------
__device__ __forceinline__ void gemm_acc(
        const bf16* __restrict__ A, const bf16* __restrict__ Bt,
        int K, int lda, int ldb, int m0, int n0,
        bf16* As, bf16* Bs, f32x4 acc[4][4]) {
    const int tid = threadIdx.x;
    const int wave = tid >> 6, lane = tid & 63;
    const int l15 = lane & 15, quad = lane >> 4;
    const int wm = (wave >> 1) * 64, wn = (wave & 1) * 64;

    for (int k0 = 0; k0 < K; k0 += 64) {
#pragma unroll
        for (int c = 0; c < 4; ++c) {
            int e = wave * 2048 + c * 512 + lane * 8;
            int r = e >> 6, col = e & 63;
            load_lds16(A + (size_t)(m0 + r) * lda + k0 + col,
                       &As[wave * 2048 + c * 512]);
            load_lds16(Bt + (size_t)(n0 + r) * ldb + k0 + col,
                       &Bs[wave * 2048 + c * 512]);
        }
        __syncthreads();
#pragma unroll
        for (int kk = 0; kk < 64; kk += 32) {
            bf16x8 af[4], bf[4];
#pragma unroll
            for (int i = 0; i < 4; ++i)
                af[i] = *(const bf16x8*)&As[(wm + i * 16 + l15) * 64 + kk + quad * 8];
#pragma unroll
            for (int j = 0; j < 4; ++j)
                bf[j] = *(const bf16x8*)&Bs[(wn + j * 16 + l15) * 64 + kk + quad * 8];
#pragma unroll
            for (int i = 0; i < 4; ++i)
#pragma unroll
                for (int j = 0; j < 4; ++j)
                    acc[i][j] = __builtin_amdgcn_mfma_f32_16x16x32_bf16(
                        af[i], bf[j], acc[i][j], 0, 0, 0);
        }
        __syncthreads();
    }
}

template <typename OutT>
__device__ __forceinline__ void store_c(
        f32x4 acc[4][4], OutT* __restrict__ C, int ldc, int m0, int n0) {
    const int tid = threadIdx.x;
    const int wave = tid >> 6, lane = tid & 63;
    const int l15 = lane & 15, quad = lane >> 4;
    const int wm = (wave >> 1) * 64, wn = (wave & 1) * 64;
#pragma unroll
    for (int i = 0; i < 4; ++i)
#pragma unroll
        for (int j = 0; j < 4; ++j) {
            int row = m0 + wm + i * 16 + quad * 4;
            int col = n0 + wn + j * 16 + l15;
#pragma unroll
            for (int r = 0; r < 4; ++r)
                C[(size_t)(row + r) * ldc + col] = (OutT)acc[i][j][r];
        }
}

template <typename OutT>
__global__ __launch_bounds__(256) void gemm_bt(
        const bf16* __restrict__ A, const bf16* __restrict__ Bt,
        OutT* __restrict__ C, int K, int lda, int ldb, int ldc) {
    __shared__ __align__(16) bf16 As[128 * 64];
    __shared__ __align__(16) bf16 Bs[128 * 64];
    f32x4 acc[4][4] = {};
    gemm_acc(A, Bt, K, lda, ldb, blockIdx.y * 128, blockIdx.x * 128, As, Bs, acc);
    store_c<OutT>(acc, C, ldc, blockIdx.y * 128, blockIdx.x * 128);
}

// ---------------------------------------------------------------------------
// Merged up-proj GEMMs + FUSED V-transpose:
//   blockIdx.x <  24 : qb  = qd @ wquT^T   (K=768)
//   blockIdx.x >= 24 : kvb = cb @ wkvuT^T  (K=512)
//     - k_nope tiles ((n0&255)==0): write kvb rows (attention K staging)
//     - V tiles ((n0&255)==128): kvb write is DEAD -> transpose acc through
//       LDS and write vtb directly (replaces transpose_v kernel).
// ---------------------------------------------------------------------------
__global__ __launch_bounds__(256) void gemm_up(
        const bf16* __restrict__ qd, const bf16* __restrict__ wquT,
        bf16* __restrict__ qb,
        const bf16* __restrict__ cb, const bf16* __restrict__ wkvuT,
        bf16* __restrict__ kvb, bf16* __restrict__ vtb) {
    __shared__ __align__(16) bf16 shbuf[2 * 128 * 64];   // As|Bs, reused for transpose
    bf16* As = shbuf;
    bf16* Bs = shbuf + 128 * 64;
    f32x4 acc[4][4] = {};
    const int m0 = blockIdx.y * 128;
    if (blockIdx.x < 24) {
        const int n0 = blockIdx.x * 128;
        gemm_acc(qd, wquT, 768, 768, 768, m0, n0, As, Bs, acc);
        store_c<bf16>(acc, qb, 3072, m0, n0);
        return;
    }
    const int n0 = (blockIdx.x - 24) * 128;
    gemm_acc(cb, wkvuT, 512, 640, 512, m0, n0, As, Bs, acc);
    if ((n0 & 255) == 0) {           // k_nope tile -> kvb
        store_c<bf16>(acc, kvb, 4096, m0, n0);
        return;
    }
    // ---- V tile -> transpose to vtb[(b*16+h)*128 + vd][kv] ----
    const int tid = threadIdx.x;
    const int wave = tid >> 6, lane = tid & 63;
    const int l15 = lane & 15, quad = lane >> 4;
    const int wm = (wave >> 1) * 64, wn = (wave & 1) * 64;
    const int h = n0 >> 8;           // head
    const int bb = m0 >> 11;         // batch
    const int kvbase = m0 & 2047;
    bf16* vt = vtb + (size_t)((bb * 16 + h) * 128) * 2048;
    bf16* t = shbuf;                 // [64][136] bf16 = 17.4 KB
#pragma unroll
    for (int p = 0; p < 2; ++p) {    // vd halves [0,64) and [64,128)
        if ((wn >> 6) == p) {        // waves owning these cols write LDS
#pragma unroll
            for (int i = 0; i < 4; ++i)
#pragma unroll
                for (int j = 0; j < 4; ++j) {
                    bf16x4 v;
#pragma unroll
                    for (int r = 0; r < 4; ++r) v[r] = (bf16)acc[i][j][r];
                    const int colL = j * 16 + l15;            // vd within pass
                    const int row = wm + i * 16 + quad * 4;   // kv local
                    *(bf16x4*)&t[colL * 136 + row] = v;
                }
        }
        __syncthreads();
        {   // 256 threads read out 64 vd x 128 kv, coalesced to vtb
            const int vd = tid >> 2;
            const int kvo = (tid & 3) * 32;
#pragma unroll
            for (int u = 0; u < 4; ++u) {
                bf16x8 vv = *(const bf16x8*)&t[vd * 136 + kvo + u * 8];
                *(bf16x8*)&vt[(size_t)(p * 64 + vd) * 2048 + kvbase + kvo + u * 8] = vv;
            }
        }
        __syncthreads();
    }
}

// ---------------------------------------------------------------------------
// Fused down-proj GEMM: Bt rows [0,768)=w_q_down^T -> C1, [768,1408)=w_kv_down^T -> C2
// ---------------------------------------------------------------------------
__global__ __launch_bounds__(256) void gemm_down(
        const bf16* __restrict__ A, const bf16* __restrict__ Bt,
        bf16* __restrict__ C1, bf16* __restrict__ C2) {
    __shared__ __align__(16) bf16 As[128 * 64];
    __shared__ __align__(16) bf16 Bs[128 * 64];
    f32x4 acc[4][4] = {};
    const int n0 = blockIdx.x * 128, m0 = blockIdx.y * 128;
    gemm_acc(A, Bt, 2048, 2048, 2048, m0, n0, As, Bs, acc);
    if (n0 < 768) store_c<bf16>(acc, C1, 768, m0, n0);
    else          store_c<bf16>(acc, C2, 640, m0, n0 - 768);
}

// ---------------------------------------------------------------------------
// Flash attention (causal), SPLIT-K flash-decoding style.  [round-5/7 config]
// 16 WAVES / 256 q-rows per block; kv tiles of 64; 80KB LDS dbuf K+V.
// waves 0-7 stage K (3 DMAs/tile, vmcnt(3)); waves 8-15 stage V (2, vmcnt(2)).
// Residency: 1 block/CU (register file: 64 arch VGPR + acc on unified file).
// ---------------------------------------------------------------------------
__global__ __launch_bounds__(1024, 4) void mla_attention_split(
        const bf16* __restrict__ qb, const bf16* __restrict__ kvb,
        const bf16* __restrict__ cb, const bf16* __restrict__ vtb,
        bf16* __restrict__ ob, bf16* __restrict__ part_o,
        float* __restrict__ part_ml) {
    constexpr int S = 2048;
    const signed char k_of[20]  = {7,7,7,7, 6,6,6,6, 5,5,5, 4,4,4, 3,3, 2,2, 1, 0};
    const signed char c_of[20]  = {0,1,2,3, 0,1,2,3, 0,1,2, 0,1,2, 0,1, 0,1, 0, 0};
    const signed char np_of[8]  = {1,1,2,2,3,3,4,4};
    const signed char pre_of[8] = {0,0,0,1,2,4,6,9};

    const int k  = k_of[blockIdx.x], c = c_of[blockIdx.x];
    const int np = np_of[k];
    const int h = blockIdx.y, b = blockIdx.z;
    const int T  = 4 * k + 4;
    const int t0 = (c * T) / np, t1 = ((c + 1) * T) / np;
    const int q0 = k * 256;

    const int tid = threadIdx.x, wave = tid >> 6, lane = tid & 63;
    const int l15 = lane & 15, quad = lane >> 4;

    __shared__ __align__(16) bf16 Ks[2][24 * 512];
    __shared__ __align__(16) bf16 Vs[2][8 * 1024];

    const int qrow = q0 + wave * 16 + l15;
    bf16x8 qf[6];
    {
        const bf16* qr = qb + (size_t)(b * S + qrow) * 3072 + h * 192;
#pragma unroll
        for (int ks = 0; ks < 6; ++ks)
            qf[ks] = *(const bf16x8*)(qr + ks * 32 + quad * 8);
    }

    const bf16* vt_head = vtb + (size_t)((b * 16 + h) * 128) * 2048;

    auto stage = [&](int kt, int bufi) {
        const int kv0 = kt * 64;
        if (wave < 8) {
            const int mt = wave >> 1;
            const size_t row = (size_t)(b * S + kv0 + mt * 16 + l15);
#pragma unroll
            for (int i = 0; i < 3; ++i) {
                const int ks = (wave & 1) * 3 + i;
                const bf16* g = (ks < 4)
                    ? kvb + row * 4096 + h * 256 + ks * 32 + quad * 8
                    : cb  + row * 640  + 512 + (ks - 4) * 32 + quad * 8;
                load_lds16(g, &Ks[bufi][(mt * 6 + ks) * 512]);
            }
        } else {
            const int nt = wave - 8;
#pragma unroll
            for (int i = 0; i < 2; ++i) {
                const bf16* g = vt_head + (size_t)(nt * 16 + l15) * 2048
                                + kv0 + (i * 4 + quad) * 8;
                load_lds16(g, &Vs[bufi][nt * 1024 + i * 512]);
            }
        }
    };

    f32x4 o[8] = {};
    float m_i = -1e30f, l_i = 0.f;
    const float sm_scale = 0.08838834764831845f * 1.4426950408889634f;
    const int qmin_w = q0 + wave * 16;

    stage(t0, 0);
    stage(t0 + 1, 1);

    int cur = 0;
    for (int kt = t0; kt < t1; ++kt, cur ^= 1) {
        const int kv0 = kt * 64;

        if (kt + 1 < t1) {
            if (wave < 8) asm volatile("s_waitcnt vmcnt(3)" ::: "memory");
            else          asm volatile("s_waitcnt vmcnt(2)" ::: "memory");
        } else {
            asm volatile("s_waitcnt vmcnt(0)" ::: "memory");
        }
        __builtin_amdgcn_s_barrier();
        __builtin_amdgcn_sched_barrier(0);

        f32x4 s[4];
        __builtin_amdgcn_s_setprio(1);
#pragma unroll
        for (int mt = 0; mt < 4; ++mt) {
            f32x4 a = {};
#pragma unroll
            for (int ks = 0; ks < 6; ++ks) {
                bf16x8 kf = *(const bf16x8*)&Ks[cur][(mt * 6 + ks) * 512 + lane * 8];
                a = __builtin_amdgcn_mfma_f32_16x16x32_bf16(kf, qf[ks], a, 0, 0, 0);
            }
            s[mt] = a;
        }
        __builtin_amdgcn_s_setprio(0);

        if (kv0 + 63 > qmin_w) {
#pragma unroll
            for (int mt = 0; mt < 4; ++mt)
#pragma unroll
                for (int r = 0; r < 4; ++r) {
                    int kvi = kv0 + mt * 16 + quad * 4 + r;
                    s[mt][r] = (kvi <= qrow) ? s[mt][r] * sm_scale : -1e30f;
                }
        } else {
#pragma unroll
            for (int mt = 0; mt < 4; ++mt)
#pragma unroll
                for (int r = 0; r < 4; ++r)
                    s[mt][r] = s[mt][r] * sm_scale;
        }
        float mx4[4];
#pragma unroll
        for (int mt = 0; mt < 4; ++mt)
            mx4[mt] = fmaxf(fmaxf(s[mt][0], s[mt][1]),
                            fmaxf(s[mt][2], s[mt][3]));
        float mx = fmaxf(fmaxf(mx4[0], mx4[1]), fmaxf(mx4[2], mx4[3]));
        mx = fmaxf(mx, __shfl_xor(mx, 16, 64));
        mx = fmaxf(mx, __shfl_xor(mx, 32, 64));
        float m_new = fmaxf(m_i, mx);
        float su4[4];
        bf16x4 pf[4];
#pragma unroll
        for (int mt = 0; mt < 4; ++mt) {
            float e0 = exp2f(s[mt][0] - m_new);
            float e1 = exp2f(s[mt][1] - m_new);
            float e2 = exp2f(s[mt][2] - m_new);
            float e3 = exp2f(s[mt][3] - m_new);
            su4[mt] = (e0 + e1) + (e2 + e3);
            pf[mt][0] = (bf16)e0; pf[mt][1] = (bf16)e1;
            pf[mt][2] = (bf16)e2; pf[mt][3] = (bf16)e3;
        }
        float su = (su4[0] + su4[1]) + (su4[2] + su4[3]);
        su += __shfl_xor(su, 16, 64);
        su += __shfl_xor(su, 32, 64);
        if (__all(mx <= m_i)) {
            l_i += su;
        } else {
            float alpha = exp2f(m_i - m_new);
            l_i = l_i * alpha + su;
            m_i = m_new;
            float alpha_r[4];
#pragma unroll
            for (int r = 0; r < 4; ++r)
                alpha_r[r] = __shfl(alpha, quad * 4 + r, 64);
#pragma unroll
            for (int nt = 0; nt < 8; ++nt)
#pragma unroll
                for (int r = 0; r < 4; ++r) o[nt][r] *= alpha_r[r];
        }

        __builtin_amdgcn_s_setprio(1);
#pragma unroll
        for (int ktk = 0; ktk < 4; ++ktk) {
            s16x4 a = __builtin_bit_cast(s16x4, pf[ktk]);
            const int voff = ktk * 256 + (quad >> 1) * 128 + l15 * 8 + (quad & 1) * 4;
#pragma unroll
            for (int nt = 0; nt < 8; ++nt) {
                s16x4 bfv = __builtin_bit_cast(s16x4,
                    *(const bf16x4*)&Vs[cur][nt * 1024 + voff]);
                o[nt] = __builtin_amdgcn_mfma_f32_16x16x16bf16_1k(a, bfv, o[nt], 0, 0, 0);
            }
        }
        __builtin_amdgcn_s_setprio(0);

        __builtin_amdgcn_s_barrier();
        if (kt + 2 < t1) stage(kt + 2, cur);
    }

    // epilogue
    if (np == 1) {
        float l_r[4];
#pragma unroll
        for (int r = 0; r < 4; ++r) l_r[r] = __shfl(l_i, quad * 4 + r, 64);
        bf16* obase = ob + (size_t)(b * S + q0 + wave * 16) * 2048 + h * 128;
#pragma unroll
        for (int nt = 0; nt < 8; ++nt)
#pragma unroll
            for (int r = 0; r < 4; ++r)
                obase[(size_t)(quad * 4 + r) * 2048 + nt * 16 + l15] =
                    (bf16)(o[nt][r] / l_r[r]);
    } else {
        const int bh = b * 16 + h;
        if (quad == 0) {
            const int qlocal = wave * 16 + l15;
            float* mlp = part_ml + ((size_t)(bh * 8 + k) * 4 + c) * 512;
            mlp[qlocal] = m_i;
            mlp[256 + qlocal] = l_i;
        }
        if (c == np - 1) {
            bf16* obase = ob + (size_t)(b * S + q0 + wave * 16) * 2048 + h * 128;
#pragma unroll
            for (int nt = 0; nt < 8; ++nt)
#pragma unroll
                for (int r = 0; r < 4; ++r)
                    obase[(size_t)(quad * 4 + r) * 2048 + nt * 16 + l15] =
                        (bf16)o[nt][r];
        } else {
            bf16* pb = part_o + (size_t)(bh * 12 + pre_of[k] + c) * 32768
                       + (size_t)(wave * 16) * 128;
#pragma unroll
            for (int nt = 0; nt < 8; ++nt)
#pragma unroll
                for (int r = 0; r < 4; ++r)
                    pb[(quad * 4 + r) * 128 + nt * 16 + l15] = (bf16)o[nt][r];
        }
    }
}

// ---------------------------------------------------------------------------
// Merge np partials for q-pair k>=2.
// ---------------------------------------------------------------------------
__global__ __launch_bounds__(256) void mla_merge(
        const bf16* __restrict__ part_o, const float* __restrict__ part_ml,
        bf16* __restrict__ ob) {
    const signed char np_of[8]  = {1,1,2,2,3,3,4,4};
    const signed char pre_of[8] = {0,0,0,1,2,4,6,9};
    const int k = 2 + blockIdx.x;              // 2..7
    const int h = blockIdx.y, b = blockIdx.z;
    const int bh = b * 16 + h;
    const int np = np_of[k];
    const int row = threadIdx.x;               // 0..255

    const float* mlb = part_ml + (size_t)(bh * 8 + k) * 4 * 512;
    const float m0 = mlb[row],            l0 = mlb[256 + row];
    const float m1 = mlb[512 + row],      l1 = mlb[512 + 256 + row];
    const float m2 = (np > 2) ? mlb[1024 + row] : -1e30f;
    const float l2 = (np > 2) ? mlb[1024 + 256 + row] : 0.f;
    const float m3 = (np > 3) ? mlb[1536 + row] : -1e30f;
    const float l3 = (np > 3) ? mlb[1536 + 256 + row] : 0.f;
    const float M = fmaxf(fmaxf(m0, m1), fmaxf(m2, m3));
    float a0 = exp2f(m0 - M), a1 = exp2f(m1 - M);
    float a2 = exp2f(m2 - M), a3 = exp2f(m3 - M);
    const float inv = 1.f / (l0 * a0 + l1 * a1 + l2 * a2 + l3 * a3);
    a0 *= inv; a1 *= inv; a2 *= inv; a3 *= inv;
    const float alast = (np == 2) ? a1 : (np == 3) ? a2 : a3;

    const bf16* p0 = part_o + (size_t)(bh * 12 + pre_of[k]) * 32768 + row * 128;
    const bf16* p1 = p0 + 32768;
    const bf16* p2 = p1 + 32768;
    bf16* po = ob + (size_t)(b * 2048 + k * 256 + row) * 2048 + h * 128;
#pragma unroll
    for (int i = 0; i < 16; ++i) {
        bf16x8 vb = *(const bf16x8*)(po + i * 8);
        bf16x8 v0 = *(const bf16x8*)(p0 + i * 8);
        float acc[8];
#pragma unroll
        for (int u = 0; u < 8; ++u)
            acc[u] = (float)vb[u] * alast + (float)v0[u] * a0;
        if (np > 2) {
            bf16x8 v1 = *(const bf16x8*)(p1 + i * 8);
#pragma unroll
            for (int u = 0; u < 8; ++u) acc[u] += (float)v1[u] * a1;
        }
        if (np > 3) {
            bf16x8 v2 = *(const bf16x8*)(p2 + i * 8);
#pragma unroll
            for (int u = 0; u < 8; ++u) acc[u] += (float)v2[u] * a2;
        }
        bf16x8 om;
#pragma unroll
        for (int u = 0; u < 8; ++u) om[u] = (bf16)acc[u];
        *(bf16x8*)(po + i * 8) = om;
    }
}

// ---------------------------------------------------------------------------
// launch
// ---------------------------------------------------------------------------
extern "C" void kernel_launch(void* const* d_in, const int* in_sizes, int n_in,
                              void* d_out, int out_size, void* d_ws, size_t ws_size,
                              hipStream_t stream) {
    const float* x    = (const float*)d_in[0];
    const float* wqd  = (const float*)d_in[3];
    const float* wqu  = (const float*)d_in[4];
    const float* wkvd = (const float*)d_in[5];
    const float* wkvu = (const float*)d_in[6];
    const float* wout = (const float*)d_in[7];
    float* out = (float*)d_out;
    char* ws = (char*)d_ws;

    bf16* xb    = (bf16*)(ws + 0);          // 4096x2048 ; reused as vtb
    bf16* vtb   = (bf16*)(ws + 0);          // aliases xb; xb dead after gemm_down
    bf16* wqdT  = (bf16*)(ws + 16777216);   // 768x2048  (dead at attention)
    bf16* wkvdT = (bf16*)(ws + 19922944);   // 640x2048  (dead at attention)
    bf16* wquT  = (bf16*)(ws + 22544384);   // 3072x768  (dead at attention)
    bf16* wkvuT = (bf16*)(ws + 27262976);   // 4096x512  (dead at attention)
    float* part_ml = (float*)(ws + 16777216); // 2 MB (aliases dead weights)
    bf16* part_o  = (bf16*)out;             // 24 MB (out dead until final GEMM)
    bf16* woutT = (bf16*)(ws + 31457280);   // 2048x2048
    bf16* qd    = (bf16*)(ws + 39845888);   // 4096x768
    bf16* qb    = (bf16*)(ws + 46137344);   // 4096x3072
    bf16* cb    = (bf16*)(ws + 71303168);   // 4096x640
    bf16* kvb   = (bf16*)(ws + 76546048);   // 4096x4096 (only k_nope halves written)
    bf16* attnb = (bf16*)(ws + 110100480);  // 4096x2048

    prep_fused<<<19456, 256, 0, stream>>>(x, xb, wqd, wqdT, wkvd, wkvdT,
                                          wqu, wquT, wkvu, wkvuT, wout, woutT);

    gemm_down<<<dim3(11, 32), 256, 0, stream>>>(xb, wqdT, qd, cb);   // last reader of xb
    // up-proj GEMMs with fused V-transpose (writes vtb directly; no transpose_v)
    gemm_up<<<dim3(56, 32), 256, 0, stream>>>(qd, wquT, qb, cb, wkvuT, kvb, vtb);

    mla_attention_split<<<dim3(20, 16, 2), 1024, 0, stream>>>(
        qb, kvb, cb, vtb, attnb, part_o, part_ml);
    mla_merge<<<dim3(6, 16, 2), 256, 0, stream>>>(part_o, part_ml, attnb);

    gemm_bt<float><<<dim3(16, 32), 256, 0, stream>>>(attnb, woutT, out, 2048, 2048, 2048, 2048);
}

// Round 9
// 441.955 us; speedup vs baseline: 1.1212x; 1.0310x over previous
//
#include <hip/hip_runtime.h>

typedef __bf16 bf16;
typedef bf16 bf16x8 __attribute__((ext_vector_type(8)));
typedef bf16 bf16x4 __attribute__((ext_vector_type(4)));
typedef float f32x4 __attribute__((ext_vector_type(4)));
typedef short s16x4 __attribute__((ext_vector_type(4)));

#define AS1 __attribute__((address_space(1)))
#define AS3 __attribute__((address_space(3)))

__device__ __forceinline__ void load_lds16(const void* g, void* l) {
    __builtin_amdgcn_global_load_lds((const AS1 unsigned int*)g,
                                     (AS3 unsigned int*)l, 16, 0, 0);
}

// ---------------------------------------------------------------------------
// Fused prep: cast x->bf16 + 5 weight transposes, one flat-grid dispatch.
// ---------------------------------------------------------------------------
__device__ __forceinline__ void tc_body(
        const float* __restrict__ in, bf16* __restrict__ out,
        int K, int N, int Np, int bx, int by, int tid,
        float (*tile)[33]) {
    const int tx = tid & 31, ty = tid >> 5;   // 32 x 8
#pragma unroll
    for (int i = 0; i < 4; ++i) {
        int k = by + ty + i * 8, n = bx + tx;
        float v = (k < K && n < N) ? in[(size_t)k * N + n] : 0.f;
        tile[ty + i * 8][tx] = v;
    }
    __syncthreads();
#pragma unroll
    for (int i = 0; i < 4; ++i) {
        int n = bx + ty + i * 8, k = by + tx;
        if (n < Np && k < K) out[(size_t)n * K + k] = (bf16)tile[tx][ty + i * 8];
    }
}

__global__ __launch_bounds__(256) void prep_fused(
        const float* __restrict__ x,    bf16* __restrict__ xb,
        const float* __restrict__ wqd,  bf16* __restrict__ wqdT,
        const float* __restrict__ wkvd, bf16* __restrict__ wkvdT,
        const float* __restrict__ wqu,  bf16* __restrict__ wquT,
        const float* __restrict__ wkvu, bf16* __restrict__ wkvuT,
        const float* __restrict__ wout, bf16* __restrict__ woutT) {
    __shared__ float tile[32][33];
    const int tid = threadIdx.x;
    int r = blockIdx.x;
    if (r < 8192) {           // cast: 8388608 floats, 4/thread
        int i = (r * 256 + tid) * 4;
        float4 v = *(const float4*)(x + i);
        bf16x4 o = { (bf16)v.x, (bf16)v.y, (bf16)v.z, (bf16)v.w };
        *(bf16x4*)(xb + i) = o;
        return;
    }
    r -= 8192;
    if (r < 1536) { tc_body(wqd,  wqdT,  2048, 768,  768,  (r % 24) * 32, (r / 24) * 32, tid, tile); return; }
    r -= 1536;
    if (r < 1280) { tc_body(wkvd, wkvdT, 2048, 576,  640,  (r % 20) * 32, (r / 20) * 32, tid, tile); return; }
    r -= 1280;
    if (r < 2304) { tc_body(wqu,  wquT,  768,  3072, 3072, (r % 96) * 32, (r / 96) * 32, tid, tile); return; }
    r -= 2304;
    if (r < 2048) { tc_body(wkvu, wkvuT, 512,  4096, 4096, (r % 128) * 32, (r / 128) * 32, tid, tile); return; }
    r -= 2048;
    tc_body(wout, woutT, 2048, 2048, 2048, (r % 64) * 32, (r / 64) * 32, tid, tile);
}

// ---------------------------------------------------------------------------
// GEMM core: acc[4][4] = A[M][K] * Bt[N][K]^T tile (128x128, BK=64, 4 waves).
// ---------------------------------------------------------------------------
__device__ __forceinline__ void gemm_acc(
        const bf16* __restrict__ A, const bf16* __restrict__ Bt,
        int K, int lda, int ldb, int m0, int n0,
        bf16* As, bf16* Bs, f32x4 acc[4][4]) {
    const int tid = threadIdx.x;
    const int wave = tid >> 6, lane = tid & 63;
    const int l15 = lane & 15, quad = lane >> 4;
    const int wm = (wave >> 1) * 64, wn = (wave & 1) * 64;

    for (int k0 = 0; k0 < K; k0 += 64) {
#pragma unroll
        for (int c = 0; c < 4; ++c) {
            int e = wave * 2048 + c * 512 + lane * 8;
            int r = e >> 6, col = e & 63;
            load_lds16(A + (size_t)(m0 + r) * lda + k0 + col,
                       &As[wave * 2048 + c * 512]);
            load_lds16(Bt + (size_t)(n0 + r) * ldb + k0 + col,
                       &Bs[wave * 2048 + c * 512]);
        }
        __syncthreads();
#pragma unroll
        for (int kk = 0; kk < 64; kk += 32) {
            bf16x8 af[4], bf[4];
#pragma unroll
            for (int i = 0; i < 4; ++i)
                af[i] = *(const bf16x8*)&As[(wm + i * 16 + l15) * 64 + kk + quad * 8];
#pragma unroll
            for (int j = 0; j < 4; ++j)
                bf[j] = *(const bf16x8*)&Bs[(wn + j * 16 + l15) * 64 + kk + quad * 8];
#pragma unroll
            for (int i = 0; i < 4; ++i)
#pragma unroll
                for (int j = 0; j < 4; ++j)
                    acc[i][j] = __builtin_amdgcn_mfma_f32_16x16x32_bf16(
                        af[i], bf[j], acc[i][j], 0, 0, 0);
        }
        __syncthreads();
    }
}

template <typename OutT>
__device__ __forceinline__ void store_c(
        f32x4 acc[4][4], OutT* __restrict__ C, int ldc, int m0, int n0) {
    const int tid = threadIdx.x;
    const int wave = tid >> 6, lane = tid & 63;
    const int l15 = lane & 15, quad = lane >> 4;
    const int wm = (wave >> 1) * 64, wn = (wave & 1) * 64;
#pragma unroll
    for (int i = 0; i < 4; ++i)
#pragma unroll
        for (int j = 0; j < 4; ++j) {
            int row = m0 + wm + i * 16 + quad * 4;
            int col = n0 + wn + j * 16 + l15;
#pragma unroll
            for (int r = 0; r < 4; ++r)
                C[(size_t)(row + r) * ldc + col] = (OutT)acc[i][j][r];
        }
}

template <typename OutT>
__global__ __launch_bounds__(256) void gemm_bt(
        const bf16* __restrict__ A, const bf16* __restrict__ Bt,
        OutT* __restrict__ C, int K, int lda, int ldb, int ldc) {
    __shared__ __align__(16) bf16 As[128 * 64];
    __shared__ __align__(16) bf16 Bs[128 * 64];
    f32x4 acc[4][4] = {};
    gemm_acc(A, Bt, K, lda, ldb, blockIdx.y * 128, blockIdx.x * 128, As, Bs, acc);
    store_c<OutT>(acc, C, ldc, blockIdx.y * 128, blockIdx.x * 128);
}

// ---------------------------------------------------------------------------
// Fused down-proj GEMM: Bt rows [0,768)=w_q_down^T -> C1, [768,1408)=w_kv_down^T -> C2
// ---------------------------------------------------------------------------
__global__ __launch_bounds__(256) void gemm_down(
        const bf16* __restrict__ A, const bf16* __restrict__ Bt,
        bf16* __restrict__ C1, bf16* __restrict__ C2) {
    __shared__ __align__(16) bf16 As[128 * 64];
    __shared__ __align__(16) bf16 Bs[128 * 64];
    f32x4 acc[4][4] = {};
    const int n0 = blockIdx.x * 128, m0 = blockIdx.y * 128;
    gemm_acc(A, Bt, 2048, 2048, 2048, m0, n0, As, Bs, acc);
    if (n0 < 768) store_c<bf16>(acc, C1, 768, m0, n0);
    else          store_c<bf16>(acc, C2, 640, m0, n0 - 768);
}

// ---------------------------------------------------------------------------
// 256x256-tile 8-phase GEMM for the up-projections (learn_hip m201 template,
// plain HIP): 512 threads = 8 waves (2M x 4N), BK=64, 128 KB LDS dbuf,
// per-phase {ds_read quadrant || (p0: stage next tile) -> barrier ->
// lgkmcnt(0) -> setprio+16 MFMA -> (p3: vmcnt(0), ~3 phases flight) ->
// barrier}. LDS XOR-swizzle (T2, rule #21): linear gload_lds dest +
// pre-swizzled GLOBAL col (col ^= (row&7)*8) + same XOR on ds_read.
//   blockIdx.x <  12 : qb  = qd @ wquT^T   (K=768, 12 K-tiles)
//   blockIdx.x >= 12 : kvb/vtb = cb @ wkvuT^T (K=512, 8 K-tiles);
//     cols [0,128) of head -> kvb; cols [128,256) -> V, transposed via LDS
//     to vtb (fused transpose_v).
// Summation order per output element identical to the 128^2 kernel ->
// bitwise-same results.
// ---------------------------------------------------------------------------
__global__ __launch_bounds__(512, 2) void gemm_up256(
        const bf16* __restrict__ qd, const bf16* __restrict__ wquT,
        bf16* __restrict__ qb,
        const bf16* __restrict__ cb, const bf16* __restrict__ wkvuT,
        bf16* __restrict__ kvb, bf16* __restrict__ vtb) {
    __shared__ __align__(16) bf16 sh[65536];   // 128 KB: A[2][16384] | B[2][16384]
    const int tid = threadIdx.x;
    const int wave = tid >> 6, lane = tid & 63;
    const int l15 = lane & 15, quad = lane >> 4;
    const int wr = wave >> 2, wc = wave & 3;     // 2M x 4N wave grid
    const int m0 = blockIdx.y * 256;
    const bool is_q = blockIdx.x < 12;
    const int n0 = is_q ? blockIdx.x * 256 : (blockIdx.x - 12) * 256;
    const bf16* Ag  = is_q ? qd : cb;
    const bf16* Btg = is_q ? wquT : wkvuT;
    const int lda = is_q ? 768 : 640;
    const int ldb = is_q ? 768 : 512;
    const int NT  = is_q ? 12 : 8;

    // staging: 4 gloads/thread per matrix per K-tile; linear LDS dest
    // (wave-uniform base + lane*16), global col pre-swizzled.
    const int gcol = (((tid & 7) ^ ((tid >> 3) & 7)) * 8);
    auto stage = [&](int kt, int bufi) {
        const int k0 = kt * 64;
#pragma unroll
        for (int c = 0; c < 4; ++c) {
            const int row = c * 64 + (tid >> 3);
            const int ldsb = bufi * 16384 + c * 4096 + wave * 512;  // wave-uniform
            load_lds16(Ag  + (size_t)(m0 + row) * lda + k0 + gcol, &sh[ldsb]);
            load_lds16(Btg + (size_t)(n0 + row) * ldb + k0 + gcol, &sh[32768 + ldsb]);
        }
    };

    const int sw = (l15 & 7) * 8;   // read-side swizzle (row&7 == l15&7)
    f32x4 acc[8][4] = {};

    stage(0, 0);
    asm volatile("s_waitcnt vmcnt(0)" ::: "memory");
    __builtin_amdgcn_s_barrier();
    __builtin_amdgcn_sched_barrier(0);

    for (int kt = 0; kt < NT; ++kt) {
        const int bufi = kt & 1;
        const bf16* As_ = &sh[bufi * 16384];
        const bf16* Bs_ = &sh[32768 + bufi * 16384];
        bf16x8 bfr[4][2];
#pragma unroll
        for (int p = 0; p < 4; ++p) {
            bf16x8 afr[2][2];
#pragma unroll
            for (int ii = 0; ii < 2; ++ii) {
                const int arow = (wr * 128 + (p * 2 + ii) * 16 + l15) * 64;
#pragma unroll
                for (int kki = 0; kki < 2; ++kki)
                    afr[ii][kki] = *(const bf16x8*)&As_[arow + ((kki * 32 + quad * 8) ^ sw)];
            }
            if (p == 0) {
#pragma unroll
                for (int j = 0; j < 4; ++j) {
                    const int brow = (wc * 64 + j * 16 + l15) * 64;
#pragma unroll
                    for (int kki = 0; kki < 2; ++kki)
                        bfr[j][kki] = *(const bf16x8*)&Bs_[brow + ((kki * 32 + quad * 8) ^ sw)];
                }
                if (kt + 1 < NT) stage(kt + 1, bufi ^ 1);   // all 8 gloads early
            }
            __builtin_amdgcn_s_barrier();                    // phase-lock waves
            asm volatile("s_waitcnt lgkmcnt(0)" ::: "memory");
            __builtin_amdgcn_sched_barrier(0);
            __builtin_amdgcn_s_setprio(1);
#pragma unroll
            for (int ii = 0; ii < 2; ++ii)
#pragma unroll
                for (int j = 0; j < 4; ++j)
#pragma unroll
                    for (int kki = 0; kki < 2; ++kki)
                        acc[p * 2 + ii][j] = __builtin_amdgcn_mfma_f32_16x16x32_bf16(
                            afr[ii][kki], bfr[j][kki], acc[p * 2 + ii][j], 0, 0, 0);
            __builtin_amdgcn_s_setprio(0);
            if (p == 3) asm volatile("s_waitcnt vmcnt(0)" ::: "memory");
            __builtin_amdgcn_s_barrier();                    // phase end; LDS safe
            __builtin_amdgcn_sched_barrier(0);
        }
    }

    // ---- epilogue ----
    if (is_q) {
#pragma unroll
        for (int i = 0; i < 8; ++i)
#pragma unroll
            for (int j = 0; j < 4; ++j) {
                const int row = m0 + wr * 128 + i * 16 + quad * 4;
                const int col = n0 + wc * 64 + j * 16 + l15;
#pragma unroll
                for (int r = 0; r < 4; ++r)
                    qb[(size_t)(row + r) * 3072 + col] = (bf16)acc[i][j][r];
            }
        return;
    }
    const int h = n0 >> 8;
    const int bb = m0 >> 11, kvbase = m0 & 2047;
    bf16* t = sh;                       // [128][264] transpose buffer (67.6 KB)
    if (wc < 2) {                       // k_nope cols [0,128) -> kvb
#pragma unroll
        for (int i = 0; i < 8; ++i)
#pragma unroll
            for (int j = 0; j < 4; ++j) {
                const int row = m0 + wr * 128 + i * 16 + quad * 4;
                const int col = h * 256 + wc * 64 + j * 16 + l15;
#pragma unroll
                for (int r = 0; r < 4; ++r)
                    kvb[(size_t)(row + r) * 4096 + col] = (bf16)acc[i][j][r];
            }
    } else {                            // V cols [128,256): transpose into LDS
#pragma unroll
        for (int i = 0; i < 8; ++i)
#pragma unroll
            for (int j = 0; j < 4; ++j) {
                const int vd = (wc - 2) * 64 + j * 16 + l15;
                const int kv = wr * 128 + i * 16 + quad * 4;
                bf16x4 v;
#pragma unroll
                for (int r = 0; r < 4; ++r) v[r] = (bf16)acc[i][j][r];
                *(bf16x4*)&t[vd * 264 + kv] = v;
            }
    }
    __syncthreads();
    {   // cooperative readout: 512 threads, vd = tid>>2, 64-kv span each
        bf16* vt = vtb + (size_t)((bb * 16 + h) * 128) * 2048;
        const int vd = tid >> 2;
        const int kv4 = (tid & 3) * 64;
#pragma unroll
        for (int u = 0; u < 8; ++u) {
            bf16x8 vv = *(const bf16x8*)&t[vd * 264 + kv4 + u * 8];
            *(bf16x8*)&vt[(size_t)vd * 2048 + kvbase + kv4 + u * 8] = vv;
        }
    }
}

// ---------------------------------------------------------------------------
// Flash attention (causal), SPLIT-K flash-decoding style.  [round-5/7 config]
// 16 WAVES / 256 q-rows per block; kv tiles of 64; 80KB LDS dbuf K+V.
// waves 0-7 stage K (3 DMAs/tile, vmcnt(3)); waves 8-15 stage V (2, vmcnt(2)).
// Residency: 1 block/CU (register file: 64 arch VGPR + acc on unified file).
// ---------------------------------------------------------------------------
__global__ __launch_bounds__(1024, 4) void mla_attention_split(
        const bf16* __restrict__ qb, const bf16* __restrict__ kvb,
        const bf16* __restrict__ cb, const bf16* __restrict__ vtb,
        bf16* __restrict__ ob, bf16* __restrict__ part_o,
        float* __restrict__ part_ml) {
    constexpr int S = 2048;
    const signed char k_of[20]  = {7,7,7,7, 6,6,6,6, 5,5,5, 4,4,4, 3,3, 2,2, 1, 0};
    const signed char c_of[20]  = {0,1,2,3, 0,1,2,3, 0,1,2, 0,1,2, 0,1, 0,1, 0, 0};
    const signed char np_of[8]  = {1,1,2,2,3,3,4,4};
    const signed char pre_of[8] = {0,0,0,1,2,4,6,9};

    const int k  = k_of[blockIdx.x], c = c_of[blockIdx.x];
    const int np = np_of[k];
    const int h = blockIdx.y, b = blockIdx.z;
    const int T  = 4 * k + 4;
    const int t0 = (c * T) / np, t1 = ((c + 1) * T) / np;
    const int q0 = k * 256;

    const int tid = threadIdx.x, wave = tid >> 6, lane = tid & 63;
    const int l15 = lane & 15, quad = lane >> 4;

    __shared__ __align__(16) bf16 Ks[2][24 * 512];
    __shared__ __align__(16) bf16 Vs[2][8 * 1024];

    const int qrow = q0 + wave * 16 + l15;
    bf16x8 qf[6];
    {
        const bf16* qr = qb + (size_t)(b * S + qrow) * 3072 + h * 192;
#pragma unroll
        for (int ks = 0; ks < 6; ++ks)
            qf[ks] = *(const bf16x8*)(qr + ks * 32 + quad * 8);
    }

    const bf16* vt_head = vtb + (size_t)((b * 16 + h) * 128) * 2048;

    auto stage = [&](int kt, int bufi) {
        const int kv0 = kt * 64;
        if (wave < 8) {
            const int mt = wave >> 1;
            const size_t row = (size_t)(b * S + kv0 + mt * 16 + l15);
#pragma unroll
            for (int i = 0; i < 3; ++i) {
                const int ks = (wave & 1) * 3 + i;
                const bf16* g = (ks < 4)
                    ? kvb + row * 4096 + h * 256 + ks * 32 + quad * 8
                    : cb  + row * 640  + 512 + (ks - 4) * 32 + quad * 8;
                load_lds16(g, &Ks[bufi][(mt * 6 + ks) * 512]);
            }
        } else {
            const int nt = wave - 8;
#pragma unroll
            for (int i = 0; i < 2; ++i) {
                const bf16* g = vt_head + (size_t)(nt * 16 + l15) * 2048
                                + kv0 + (i * 4 + quad) * 8;
                load_lds16(g, &Vs[bufi][nt * 1024 + i * 512]);
            }
        }
    };

    f32x4 o[8] = {};
    float m_i = -1e30f, l_i = 0.f;
    const float sm_scale = 0.08838834764831845f * 1.4426950408889634f;
    const int qmin_w = q0 + wave * 16;

    stage(t0, 0);
    stage(t0 + 1, 1);

    int cur = 0;
    for (int kt = t0; kt < t1; ++kt, cur ^= 1) {
        const int kv0 = kt * 64;

        if (kt + 1 < t1) {
            if (wave < 8) asm volatile("s_waitcnt vmcnt(3)" ::: "memory");
            else          asm volatile("s_waitcnt vmcnt(2)" ::: "memory");
        } else {
            asm volatile("s_waitcnt vmcnt(0)" ::: "memory");
        }
        __builtin_amdgcn_s_barrier();
        __builtin_amdgcn_sched_barrier(0);

        f32x4 s[4];
        __builtin_amdgcn_s_setprio(1);
#pragma unroll
        for (int mt = 0; mt < 4; ++mt) {
            f32x4 a = {};
#pragma unroll
            for (int ks = 0; ks < 6; ++ks) {
                bf16x8 kf = *(const bf16x8*)&Ks[cur][(mt * 6 + ks) * 512 + lane * 8];
                a = __builtin_amdgcn_mfma_f32_16x16x32_bf16(kf, qf[ks], a, 0, 0, 0);
            }
            s[mt] = a;
        }
        __builtin_amdgcn_s_setprio(0);

        if (kv0 + 63 > qmin_w) {
#pragma unroll
            for (int mt = 0; mt < 4; ++mt)
#pragma unroll
                for (int r = 0; r < 4; ++r) {
                    int kvi = kv0 + mt * 16 + quad * 4 + r;
                    s[mt][r] = (kvi <= qrow) ? s[mt][r] * sm_scale : -1e30f;
                }
        } else {
#pragma unroll
            for (int mt = 0; mt < 4; ++mt)
#pragma unroll
                for (int r = 0; r < 4; ++r)
                    s[mt][r] = s[mt][r] * sm_scale;
        }
        float mx4[4];
#pragma unroll
        for (int mt = 0; mt < 4; ++mt)
            mx4[mt] = fmaxf(fmaxf(s[mt][0], s[mt][1]),
                            fmaxf(s[mt][2], s[mt][3]));
        float mx = fmaxf(fmaxf(mx4[0], mx4[1]), fmaxf(mx4[2], mx4[3]));
        mx = fmaxf(mx, __shfl_xor(mx, 16, 64));
        mx = fmaxf(mx, __shfl_xor(mx, 32, 64));
        float m_new = fmaxf(m_i, mx);
        float su4[4];
        bf16x4 pf[4];
#pragma unroll
        for (int mt = 0; mt < 4; ++mt) {
            float e0 = exp2f(s[mt][0] - m_new);
            float e1 = exp2f(s[mt][1] - m_new);
            float e2 = exp2f(s[mt][2] - m_new);
            float e3 = exp2f(s[mt][3] - m_new);
            su4[mt] = (e0 + e1) + (e2 + e3);
            pf[mt][0] = (bf16)e0; pf[mt][1] = (bf16)e1;
            pf[mt][2] = (bf16)e2; pf[mt][3] = (bf16)e3;
        }
        float su = (su4[0] + su4[1]) + (su4[2] + su4[3]);
        su += __shfl_xor(su, 16, 64);
        su += __shfl_xor(su, 32, 64);
        if (__all(mx <= m_i)) {
            l_i += su;
        } else {
            float alpha = exp2f(m_i - m_new);
            l_i = l_i * alpha + su;
            m_i = m_new;
            float alpha_r[4];
#pragma unroll
            for (int r = 0; r < 4; ++r)
                alpha_r[r] = __shfl(alpha, quad * 4 + r, 64);
#pragma unroll
            for (int nt = 0; nt < 8; ++nt)
#pragma unroll
                for (int r = 0; r < 4; ++r) o[nt][r] *= alpha_r[r];
        }

        __builtin_amdgcn_s_setprio(1);
#pragma unroll
        for (int ktk = 0; ktk < 4; ++ktk) {
            s16x4 a = __builtin_bit_cast(s16x4, pf[ktk]);
            const int voff = ktk * 256 + (quad >> 1) * 128 + l15 * 8 + (quad & 1) * 4;
#pragma unroll
            for (int nt = 0; nt < 8; ++nt) {
                s16x4 bfv = __builtin_bit_cast(s16x4,
                    *(const bf16x4*)&Vs[cur][nt * 1024 + voff]);
                o[nt] = __builtin_amdgcn_mfma_f32_16x16x16bf16_1k(a, bfv, o[nt], 0, 0, 0);
            }
        }
        __builtin_amdgcn_s_setprio(0);

        __builtin_amdgcn_s_barrier();
        if (kt + 2 < t1) stage(kt + 2, cur);
    }

    // epilogue
    if (np == 1) {
        float l_r[4];
#pragma unroll
        for (int r = 0; r < 4; ++r) l_r[r] = __shfl(l_i, quad * 4 + r, 64);
        bf16* obase = ob + (size_t)(b * S + q0 + wave * 16) * 2048 + h * 128;
#pragma unroll
        for (int nt = 0; nt < 8; ++nt)
#pragma unroll
            for (int r = 0; r < 4; ++r)
                obase[(size_t)(quad * 4 + r) * 2048 + nt * 16 + l15] =
                    (bf16)(o[nt][r] / l_r[r]);
    } else {
        const int bh = b * 16 + h;
        if (quad == 0) {
            const int qlocal = wave * 16 + l15;
            float* mlp = part_ml + ((size_t)(bh * 8 + k) * 4 + c) * 512;
            mlp[qlocal] = m_i;
            mlp[256 + qlocal] = l_i;
        }
        if (c == np - 1) {
            bf16* obase = ob + (size_t)(b * S + q0 + wave * 16) * 2048 + h * 128;
#pragma unroll
            for (int nt = 0; nt < 8; ++nt)
#pragma unroll
                for (int r = 0; r < 4; ++r)
                    obase[(size_t)(quad * 4 + r) * 2048 + nt * 16 + l15] =
                        (bf16)o[nt][r];
        } else {
            bf16* pb = part_o + (size_t)(bh * 12 + pre_of[k] + c) * 32768
                       + (size_t)(wave * 16) * 128;
#pragma unroll
            for (int nt = 0; nt < 8; ++nt)
#pragma unroll
                for (int r = 0; r < 4; ++r)
                    pb[(quad * 4 + r) * 128 + nt * 16 + l15] = (bf16)o[nt][r];
        }
    }
}

// ---------------------------------------------------------------------------
// Merge np partials for q-pair k>=2.
// ---------------------------------------------------------------------------
__global__ __launch_bounds__(256) void mla_merge(
        const bf16* __restrict__ part_o, const float* __restrict__ part_ml,
        bf16* __restrict__ ob) {
    const signed char np_of[8]  = {1,1,2,2,3,3,4,4};
    const signed char pre_of[8] = {0,0,0,1,2,4,6,9};
    const int k = 2 + blockIdx.x;              // 2..7
    const int h = blockIdx.y, b = blockIdx.z;
    const int bh = b * 16 + h;
    const int np = np_of[k];
    const int row = threadIdx.x;               // 0..255

    const float* mlb = part_ml + (size_t)(bh * 8 + k) * 4 * 512;
    const float m0 = mlb[row],            l0 = mlb[256 + row];
    const float m1 = mlb[512 + row],      l1 = mlb[512 + 256 + row];
    const float m2 = (np > 2) ? mlb[1024 + row] : -1e30f;
    const float l2 = (np > 2) ? mlb[1024 + 256 + row] : 0.f;
    const float m3 = (np > 3) ? mlb[1536 + row] : -1e30f;
    const float l3 = (np > 3) ? mlb[1536 + 256 + row] : 0.f;
    const float M = fmaxf(fmaxf(m0, m1), fmaxf(m2, m3));
    float a0 = exp2f(m0 - M), a1 = exp2f(m1 - M);
    float a2 = exp2f(m2 - M), a3 = exp2f(m3 - M);
    const float inv = 1.f / (l0 * a0 + l1 * a1 + l2 * a2 + l3 * a3);
    a0 *= inv; a1 *= inv; a2 *= inv; a3 *= inv;
    const float alast = (np == 2) ? a1 : (np == 3) ? a2 : a3;

    const bf16* p0 = part_o + (size_t)(bh * 12 + pre_of[k]) * 32768 + row * 128;
    const bf16* p1 = p0 + 32768;
    const bf16* p2 = p1 + 32768;
    bf16* po = ob + (size_t)(b * 2048 + k * 256 + row) * 2048 + h * 128;
#pragma unroll
    for (int i = 0; i < 16; ++i) {
        bf16x8 vb = *(const bf16x8*)(po + i * 8);
        bf16x8 v0 = *(const bf16x8*)(p0 + i * 8);
        float acc[8];
#pragma unroll
        for (int u = 0; u < 8; ++u)
            acc[u] = (float)vb[u] * alast + (float)v0[u] * a0;
        if (np > 2) {
            bf16x8 v1 = *(const bf16x8*)(p1 + i * 8);
#pragma unroll
            for (int u = 0; u < 8; ++u) acc[u] += (float)v1[u] * a1;
        }
        if (np > 3) {
            bf16x8 v2 = *(const bf16x8*)(p2 + i * 8);
#pragma unroll
            for (int u = 0; u < 8; ++u) acc[u] += (float)v2[u] * a2;
        }
        bf16x8 om;
#pragma unroll
        for (int u = 0; u < 8; ++u) om[u] = (bf16)acc[u];
        *(bf16x8*)(po + i * 8) = om;
    }
}

// ---------------------------------------------------------------------------
// launch
// ---------------------------------------------------------------------------
extern "C" void kernel_launch(void* const* d_in, const int* in_sizes, int n_in,
                              void* d_out, int out_size, void* d_ws, size_t ws_size,
                              hipStream_t stream) {
    const float* x    = (const float*)d_in[0];
    const float* wqd  = (const float*)d_in[3];
    const float* wqu  = (const float*)d_in[4];
    const float* wkvd = (const float*)d_in[5];
    const float* wkvu = (const float*)d_in[6];
    const float* wout = (const float*)d_in[7];
    float* out = (float*)d_out;
    char* ws = (char*)d_ws;

    bf16* xb    = (bf16*)(ws + 0);          // 4096x2048 ; reused as vtb
    bf16* vtb   = (bf16*)(ws + 0);          // aliases xb; xb dead after gemm_down
    bf16* wqdT  = (bf16*)(ws + 16777216);   // 768x2048  (dead at attention)
    bf16* wkvdT = (bf16*)(ws + 19922944);   // 640x2048  (dead at attention)
    bf16* wquT  = (bf16*)(ws + 22544384);   // 3072x768  (dead at attention)
    bf16* wkvuT = (bf16*)(ws + 27262976);   // 4096x512  (dead at attention)
    float* part_ml = (float*)(ws + 16777216); // 2 MB (aliases dead weights)
    bf16* part_o  = (bf16*)out;             // 24 MB (out dead until final GEMM)
    bf16* woutT = (bf16*)(ws + 31457280);   // 2048x2048
    bf16* qd    = (bf16*)(ws + 39845888);   // 4096x768
    bf16* qb    = (bf16*)(ws + 46137344);   // 4096x3072
    bf16* cb    = (bf16*)(ws + 71303168);   // 4096x640
    bf16* kvb   = (bf16*)(ws + 76546048);   // 4096x4096 (only k_nope halves written)
    bf16* attnb = (bf16*)(ws + 110100480);  // 4096x2048

    prep_fused<<<19456, 256, 0, stream>>>(x, xb, wqd, wqdT, wkvd, wkvdT,
                                          wqu, wquT, wkvu, wkvuT, wout, woutT);

    gemm_down<<<dim3(11, 32), 256, 0, stream>>>(xb, wqdT, qd, cb);   // last reader of xb
    // 256^2 8-phase up-proj GEMMs with fused V-transpose
    gemm_up256<<<dim3(28, 16), 512, 0, stream>>>(qd, wquT, qb, cb, wkvuT, kvb, vtb);

    mla_attention_split<<<dim3(20, 16, 2), 1024, 0, stream>>>(
        qb, kvb, cb, vtb, attnb, part_o, part_ml);
    mla_merge<<<dim3(6, 16, 2), 256, 0, stream>>>(part_o, part_ml, attnb);

    gemm_bt<float><<<dim3(16, 32), 256, 0, stream>>>(attnb, woutT, out, 2048, 2048, 2048, 2048);
}

// Round 10
// 434.849 us; speedup vs baseline: 1.1395x; 1.0163x over previous
//
#include <hip/hip_runtime.h>

typedef __bf16 bf16;
typedef bf16 bf16x8 __attribute__((ext_vector_type(8)));
typedef bf16 bf16x4 __attribute__((ext_vector_type(4)));
typedef float f32x4 __attribute__((ext_vector_type(4)));
typedef short s16x4 __attribute__((ext_vector_type(4)));

#define AS1 __attribute__((address_space(1)))
#define AS3 __attribute__((address_space(3)))

__device__ __forceinline__ void load_lds16(const void* g, void* l) {
    __builtin_amdgcn_global_load_lds((const AS1 unsigned int*)g,
                                     (AS3 unsigned int*)l, 16, 0, 0);
}

// ---------------------------------------------------------------------------
// Fused prep: cast x->bf16 + 5 weight transposes, one flat-grid dispatch.
// ---------------------------------------------------------------------------
__device__ __forceinline__ void tc_body(
        const float* __restrict__ in, bf16* __restrict__ out,
        int K, int N, int Np, int bx, int by, int tid,
        float (*tile)[33]) {
    const int tx = tid & 31, ty = tid >> 5;   // 32 x 8
#pragma unroll
    for (int i = 0; i < 4; ++i) {
        int k = by + ty + i * 8, n = bx + tx;
        float v = (k < K && n < N) ? in[(size_t)k * N + n] : 0.f;
        tile[ty + i * 8][tx] = v;
    }
    __syncthreads();
#pragma unroll
    for (int i = 0; i < 4; ++i) {
        int n = bx + ty + i * 8, k = by + tx;
        if (n < Np && k < K) out[(size_t)n * K + k] = (bf16)tile[tx][ty + i * 8];
    }
}

__global__ __launch_bounds__(256) void prep_fused(
        const float* __restrict__ x,    bf16* __restrict__ xb,
        const float* __restrict__ wqd,  bf16* __restrict__ wqdT,
        const float* __restrict__ wkvd, bf16* __restrict__ wkvdT,
        const float* __restrict__ wqu,  bf16* __restrict__ wquT,
        const float* __restrict__ wkvu, bf16* __restrict__ wkvuT,
        const float* __restrict__ wout, bf16* __restrict__ woutT) {
    __shared__ float tile[32][33];
    const int tid = threadIdx.x;
    int r = blockIdx.x;
    if (r < 8192) {           // cast: 8388608 floats, 4/thread
        int i = (r * 256 + tid) * 4;
        float4 v = *(const float4*)(x + i);
        bf16x4 o = { (bf16)v.x, (bf16)v.y, (bf16)v.z, (bf16)v.w };
        *(bf16x4*)(xb + i) = o;
        return;
    }
    r -= 8192;
    if (r < 1536) { tc_body(wqd,  wqdT,  2048, 768,  768,  (r % 24) * 32, (r / 24) * 32, tid, tile); return; }
    r -= 1536;
    if (r < 1280) { tc_body(wkvd, wkvdT, 2048, 576,  640,  (r % 20) * 32, (r / 20) * 32, tid, tile); return; }
    r -= 1280;
    if (r < 2304) { tc_body(wqu,  wquT,  768,  3072, 3072, (r % 96) * 32, (r / 96) * 32, tid, tile); return; }
    r -= 2304;
    if (r < 2048) { tc_body(wkvu, wkvuT, 512,  4096, 4096, (r % 128) * 32, (r / 128) * 32, tid, tile); return; }
    r -= 2048;
    tc_body(wout, woutT, 2048, 2048, 2048, (r % 64) * 32, (r / 64) * 32, tid, tile);
}

// ---------------------------------------------------------------------------
// GEMM core: acc[4][4] = A[M][K] * Bt[N][K]^T tile (128x128, BK=64, 4 waves).
// ---------------------------------------------------------------------------
__device__ __forceinline__ void gemm_acc(
        const bf16* __restrict__ A, const bf16* __restrict__ Bt,
        int K, int lda, int ldb, int m0, int n0,
        bf16* As, bf16* Bs, f32x4 acc[4][4]) {
    const int tid = threadIdx.x;
    const int wave = tid >> 6, lane = tid & 63;
    const int l15 = lane & 15, quad = lane >> 4;
    const int wm = (wave >> 1) * 64, wn = (wave & 1) * 64;

    for (int k0 = 0; k0 < K; k0 += 64) {
#pragma unroll
        for (int c = 0; c < 4; ++c) {
            int e = wave * 2048 + c * 512 + lane * 8;
            int r = e >> 6, col = e & 63;
            load_lds16(A + (size_t)(m0 + r) * lda + k0 + col,
                       &As[wave * 2048 + c * 512]);
            load_lds16(Bt + (size_t)(n0 + r) * ldb + k0 + col,
                       &Bs[wave * 2048 + c * 512]);
        }
        __syncthreads();
#pragma unroll
        for (int kk = 0; kk < 64; kk += 32) {
            bf16x8 af[4], bf[4];
#pragma unroll
            for (int i = 0; i < 4; ++i)
                af[i] = *(const bf16x8*)&As[(wm + i * 16 + l15) * 64 + kk + quad * 8];
#pragma unroll
            for (int j = 0; j < 4; ++j)
                bf[j] = *(const bf16x8*)&Bs[(wn + j * 16 + l15) * 64 + kk + quad * 8];
#pragma unroll
            for (int i = 0; i < 4; ++i)
#pragma unroll
                for (int j = 0; j < 4; ++j)
                    acc[i][j] = __builtin_amdgcn_mfma_f32_16x16x32_bf16(
                        af[i], bf[j], acc[i][j], 0, 0, 0);
        }
        __syncthreads();
    }
}

template <typename OutT>
__device__ __forceinline__ void store_c(
        f32x4 acc[4][4], OutT* __restrict__ C, int ldc, int m0, int n0) {
    const int tid = threadIdx.x;
    const int wave = tid >> 6, lane = tid & 63;
    const int l15 = lane & 15, quad = lane >> 4;
    const int wm = (wave >> 1) * 64, wn = (wave & 1) * 64;
#pragma unroll
    for (int i = 0; i < 4; ++i)
#pragma unroll
        for (int j = 0; j < 4; ++j) {
            int row = m0 + wm + i * 16 + quad * 4;
            int col = n0 + wn + j * 16 + l15;
#pragma unroll
            for (int r = 0; r < 4; ++r)
                C[(size_t)(row + r) * ldc + col] = (OutT)acc[i][j][r];
        }
}

// ---------------------------------------------------------------------------
// Fused down-proj GEMM: Bt rows [0,768)=w_q_down^T -> C1, [768,1408)=w_kv_down^T -> C2
// ---------------------------------------------------------------------------
__global__ __launch_bounds__(256) void gemm_down(
        const bf16* __restrict__ A, const bf16* __restrict__ Bt,
        bf16* __restrict__ C1, bf16* __restrict__ C2) {
    __shared__ __align__(16) bf16 As[128 * 64];
    __shared__ __align__(16) bf16 Bs[128 * 64];
    f32x4 acc[4][4] = {};
    const int n0 = blockIdx.x * 128, m0 = blockIdx.y * 128;
    gemm_acc(A, Bt, 2048, 2048, 2048, m0, n0, As, Bs, acc);
    if (n0 < 768) store_c<bf16>(acc, C1, 768, m0, n0);
    else          store_c<bf16>(acc, C2, 640, m0, n0 - 768);
}

// ---------------------------------------------------------------------------
// 256x256-tile 8-phase GEMM for the up-projections (m201 template).
//   blockIdx.x <  12 : qb  = qd @ wquT^T   (K=768, 12 K-tiles)
//   blockIdx.x >= 12 : kvb/vtb = cb @ wkvuT^T (K=512, 8 K-tiles);
//     cols [0,128) of head -> kvb; cols [128,256) -> V -> vtb (fused T).
// ---------------------------------------------------------------------------
__global__ __launch_bounds__(512, 2) void gemm_up256(
        const bf16* __restrict__ qd, const bf16* __restrict__ wquT,
        bf16* __restrict__ qb,
        const bf16* __restrict__ cb, const bf16* __restrict__ wkvuT,
        bf16* __restrict__ kvb, bf16* __restrict__ vtb) {
    __shared__ __align__(16) bf16 sh[65536];   // 128 KB: A[2][16384] | B[2][16384]
    const int tid = threadIdx.x;
    const int wave = tid >> 6, lane = tid & 63;
    const int l15 = lane & 15, quad = lane >> 4;
    const int wr = wave >> 2, wc = wave & 3;     // 2M x 4N wave grid
    const int m0 = blockIdx.y * 256;
    const bool is_q = blockIdx.x < 12;
    const int n0 = is_q ? blockIdx.x * 256 : (blockIdx.x - 12) * 256;
    const bf16* Ag  = is_q ? qd : cb;
    const bf16* Btg = is_q ? wquT : wkvuT;
    const int lda = is_q ? 768 : 640;
    const int ldb = is_q ? 768 : 512;
    const int NT  = is_q ? 12 : 8;

    const int gcol = (((tid & 7) ^ ((tid >> 3) & 7)) * 8);
    auto stage = [&](int kt, int bufi) {
        const int k0 = kt * 64;
#pragma unroll
        for (int c = 0; c < 4; ++c) {
            const int row = c * 64 + (tid >> 3);
            const int ldsb = bufi * 16384 + c * 4096 + wave * 512;  // wave-uniform
            load_lds16(Ag  + (size_t)(m0 + row) * lda + k0 + gcol, &sh[ldsb]);
            load_lds16(Btg + (size_t)(n0 + row) * ldb + k0 + gcol, &sh[32768 + ldsb]);
        }
    };

    const int sw = (l15 & 7) * 8;   // read-side swizzle (row&7 == l15&7)
    f32x4 acc[8][4] = {};

    stage(0, 0);
    asm volatile("s_waitcnt vmcnt(0)" ::: "memory");
    __builtin_amdgcn_s_barrier();
    __builtin_amdgcn_sched_barrier(0);

    for (int kt = 0; kt < NT; ++kt) {
        const int bufi = kt & 1;
        const bf16* As_ = &sh[bufi * 16384];
        const bf16* Bs_ = &sh[32768 + bufi * 16384];
        bf16x8 bfr[4][2];
#pragma unroll
        for (int p = 0; p < 4; ++p) {
            bf16x8 afr[2][2];
#pragma unroll
            for (int ii = 0; ii < 2; ++ii) {
                const int arow = (wr * 128 + (p * 2 + ii) * 16 + l15) * 64;
#pragma unroll
                for (int kki = 0; kki < 2; ++kki)
                    afr[ii][kki] = *(const bf16x8*)&As_[arow + ((kki * 32 + quad * 8) ^ sw)];
            }
            if (p == 0) {
#pragma unroll
                for (int j = 0; j < 4; ++j) {
                    const int brow = (wc * 64 + j * 16 + l15) * 64;
#pragma unroll
                    for (int kki = 0; kki < 2; ++kki)
                        bfr[j][kki] = *(const bf16x8*)&Bs_[brow + ((kki * 32 + quad * 8) ^ sw)];
                }
                if (kt + 1 < NT) stage(kt + 1, bufi ^ 1);   // all 8 gloads early
            }
            __builtin_amdgcn_s_barrier();                    // phase-lock waves
            asm volatile("s_waitcnt lgkmcnt(0)" ::: "memory");
            __builtin_amdgcn_sched_barrier(0);
            __builtin_amdgcn_s_setprio(1);
#pragma unroll
            for (int ii = 0; ii < 2; ++ii)
#pragma unroll
                for (int j = 0; j < 4; ++j)
#pragma unroll
                    for (int kki = 0; kki < 2; ++kki)
                        acc[p * 2 + ii][j] = __builtin_amdgcn_mfma_f32_16x16x32_bf16(
                            afr[ii][kki], bfr[j][kki], acc[p * 2 + ii][j], 0, 0, 0);
            __builtin_amdgcn_s_setprio(0);
            if (p == 3) asm volatile("s_waitcnt vmcnt(0)" ::: "memory");
            __builtin_amdgcn_s_barrier();                    // phase end; LDS safe
            __builtin_amdgcn_sched_barrier(0);
        }
    }

    // ---- epilogue ----
    if (is_q) {
#pragma unroll
        for (int i = 0; i < 8; ++i)
#pragma unroll
            for (int j = 0; j < 4; ++j) {
                const int row = m0 + wr * 128 + i * 16 + quad * 4;
                const int col = n0 + wc * 64 + j * 16 + l15;
#pragma unroll
                for (int r = 0; r < 4; ++r)
                    qb[(size_t)(row + r) * 3072 + col] = (bf16)acc[i][j][r];
            }
        return;
    }
    const int h = n0 >> 8;
    const int bb = m0 >> 11, kvbase = m0 & 2047;
    bf16* t = sh;                       // [128][264] transpose buffer (67.6 KB)
    if (wc < 2) {                       // k_nope cols [0,128) -> kvb
#pragma unroll
        for (int i = 0; i < 8; ++i)
#pragma unroll
            for (int j = 0; j < 4; ++j) {
                const int row = m0 + wr * 128 + i * 16 + quad * 4;
                const int col = h * 256 + wc * 64 + j * 16 + l15;
#pragma unroll
                for (int r = 0; r < 4; ++r)
                    kvb[(size_t)(row + r) * 4096 + col] = (bf16)acc[i][j][r];
            }
    } else {                            // V cols [128,256): transpose into LDS
#pragma unroll
        for (int i = 0; i < 8; ++i)
#pragma unroll
            for (int j = 0; j < 4; ++j) {
                const int vd = (wc - 2) * 64 + j * 16 + l15;
                const int kv = wr * 128 + i * 16 + quad * 4;
                bf16x4 v;
#pragma unroll
                for (int r = 0; r < 4; ++r) v[r] = (bf16)acc[i][j][r];
                *(bf16x4*)&t[vd * 264 + kv] = v;
            }
    }
    __syncthreads();
    {   // cooperative readout: 512 threads, vd = tid>>2, 64-kv span each
        bf16* vt = vtb + (size_t)((bb * 16 + h) * 128) * 2048;
        const int vd = tid >> 2;
        const int kv4 = (tid & 3) * 64;
#pragma unroll
        for (int u = 0; u < 8; ++u) {
            bf16x8 vv = *(const bf16x8*)&t[vd * 264 + kv4 + u * 8];
            *(bf16x8*)&vt[(size_t)vd * 2048 + kvbase + kv4 + u * 8] = vv;
        }
    }
}

// ---------------------------------------------------------------------------
// 256x128-tile 8-phase GEMM for the output projection:
//   out[4096][2048] = attnb[4096][2048] @ woutT[2048][2048]^T, f32 out.
// Grid 16x16 = 256 blocks = exactly 1/CU (full machine fill, 32 K-tiles).
// 8 waves as 4M x 2N (64x64 output each, acc[4][4]); per phase: 1 A
// row-block ds_read + 8 MFMA; B frags + 6-gload stage at p0; vmcnt(0)
// only at p3. LDS 96 KB dbuf. Same both-sides XOR swizzle as gemm_up256;
// same K-summation order as the 128^2 kernel.
// ---------------------------------------------------------------------------
__global__ __launch_bounds__(512, 2) void gemm_out256(
        const bf16* __restrict__ A, const bf16* __restrict__ Bt,
        float* __restrict__ C) {
    __shared__ __align__(16) bf16 sh[49152];   // 96 KB: A[2][16384] | B[2][8192]
    const int tid = threadIdx.x;
    const int wave = tid >> 6, lane = tid & 63;
    const int l15 = lane & 15, quad = lane >> 4;
    const int wr = wave >> 1, wc = wave & 1;     // 4M x 2N wave grid
    const int m0 = blockIdx.y * 256, n0 = blockIdx.x * 128;
    const int NT = 32;                           // K = 2048

    const int gcol = (((tid & 7) ^ ((tid >> 3) & 7)) * 8);
    auto stage = [&](int kt, int bufi) {
        const int k0 = kt * 64;
#pragma unroll
        for (int c = 0; c < 4; ++c) {            // A: 256 rows
            const int row = c * 64 + (tid >> 3);
            load_lds16(A + (size_t)(m0 + row) * 2048 + k0 + gcol,
                       &sh[bufi * 16384 + c * 4096 + wave * 512]);
        }
#pragma unroll
        for (int c = 0; c < 2; ++c) {            // B: 128 rows
            const int row = c * 64 + (tid >> 3);
            load_lds16(Bt + (size_t)(n0 + row) * 2048 + k0 + gcol,
                       &sh[32768 + bufi * 8192 + c * 4096 + wave * 512]);
        }
    };

    const int sw = (l15 & 7) * 8;
    f32x4 acc[4][4] = {};

    stage(0, 0);
    asm volatile("s_waitcnt vmcnt(0)" ::: "memory");
    __builtin_amdgcn_s_barrier();
    __builtin_amdgcn_sched_barrier(0);

    for (int kt = 0; kt < NT; ++kt) {
        const int bufi = kt & 1;
        const bf16* As_ = &sh[bufi * 16384];
        const bf16* Bs_ = &sh[32768 + bufi * 8192];
        bf16x8 bfr[4][2];
#pragma unroll
        for (int p = 0; p < 4; ++p) {
            bf16x8 afr[2];
            {
                const int arow = (wr * 64 + p * 16 + l15) * 64;
#pragma unroll
                for (int kki = 0; kki < 2; ++kki)
                    afr[kki] = *(const bf16x8*)&As_[arow + ((kki * 32 + quad * 8) ^ sw)];
            }
            if (p == 0) {
#pragma unroll
                for (int j = 0; j < 4; ++j) {
                    const int brow = (wc * 64 + j * 16 + l15) * 64;
#pragma unroll
                    for (int kki = 0; kki < 2; ++kki)
                        bfr[j][kki] = *(const bf16x8*)&Bs_[brow + ((kki * 32 + quad * 8) ^ sw)];
                }
                if (kt + 1 < NT) stage(kt + 1, bufi ^ 1);
            }
            __builtin_amdgcn_s_barrier();
            asm volatile("s_waitcnt lgkmcnt(0)" ::: "memory");
            __builtin_amdgcn_sched_barrier(0);
            __builtin_amdgcn_s_setprio(1);
#pragma unroll
            for (int j = 0; j < 4; ++j)
#pragma unroll
                for (int kki = 0; kki < 2; ++kki)
                    acc[p][j] = __builtin_amdgcn_mfma_f32_16x16x32_bf16(
                        afr[kki], bfr[j][kki], acc[p][j], 0, 0, 0);
            __builtin_amdgcn_s_setprio(0);
            if (p == 3) asm volatile("s_waitcnt vmcnt(0)" ::: "memory");
            __builtin_amdgcn_s_barrier();
            __builtin_amdgcn_sched_barrier(0);
        }
    }

    // epilogue: f32 store
#pragma unroll
    for (int i = 0; i < 4; ++i)
#pragma unroll
        for (int j = 0; j < 4; ++j) {
            const int row = m0 + wr * 64 + i * 16 + quad * 4;
            const int col = n0 + wc * 64 + j * 16 + l15;
#pragma unroll
            for (int r = 0; r < 4; ++r)
                C[(size_t)(row + r) * 2048 + col] = acc[i][j][r];
        }
}

// ---------------------------------------------------------------------------
// Flash attention (causal), SPLIT-K flash-decoding style.  [round-5/7 config]
// 16 WAVES / 256 q-rows per block; kv tiles of 64; 80KB LDS dbuf K+V.
// waves 0-7 stage K (3 DMAs/tile, vmcnt(3)); waves 8-15 stage V (2, vmcnt(2)).
// Residency: 1 block/CU (register file: 64 arch VGPR + acc on unified file).
// ---------------------------------------------------------------------------
__global__ __launch_bounds__(1024, 4) void mla_attention_split(
        const bf16* __restrict__ qb, const bf16* __restrict__ kvb,
        const bf16* __restrict__ cb, const bf16* __restrict__ vtb,
        bf16* __restrict__ ob, bf16* __restrict__ part_o,
        float* __restrict__ part_ml) {
    constexpr int S = 2048;
    const signed char k_of[20]  = {7,7,7,7, 6,6,6,6, 5,5,5, 4,4,4, 3,3, 2,2, 1, 0};
    const signed char c_of[20]  = {0,1,2,3, 0,1,2,3, 0,1,2, 0,1,2, 0,1, 0,1, 0, 0};
    const signed char np_of[8]  = {1,1,2,2,3,3,4,4};
    const signed char pre_of[8] = {0,0,0,1,2,4,6,9};

    const int k  = k_of[blockIdx.x], c = c_of[blockIdx.x];
    const int np = np_of[k];
    const int h = blockIdx.y, b = blockIdx.z;
    const int T  = 4 * k + 4;
    const int t0 = (c * T) / np, t1 = ((c + 1) * T) / np;
    const int q0 = k * 256;

    const int tid = threadIdx.x, wave = tid >> 6, lane = tid & 63;
    const int l15 = lane & 15, quad = lane >> 4;

    __shared__ __align__(16) bf16 Ks[2][24 * 512];
    __shared__ __align__(16) bf16 Vs[2][8 * 1024];

    const int qrow = q0 + wave * 16 + l15;
    bf16x8 qf[6];
    {
        const bf16* qr = qb + (size_t)(b * S + qrow) * 3072 + h * 192;
#pragma unroll
        for (int ks = 0; ks < 6; ++ks)
            qf[ks] = *(const bf16x8*)(qr + ks * 32 + quad * 8);
    }

    const bf16* vt_head = vtb + (size_t)((b * 16 + h) * 128) * 2048;

    auto stage = [&](int kt, int bufi) {
        const int kv0 = kt * 64;
        if (wave < 8) {
            const int mt = wave >> 1;
            const size_t row = (size_t)(b * S + kv0 + mt * 16 + l15);
#pragma unroll
            for (int i = 0; i < 3; ++i) {
                const int ks = (wave & 1) * 3 + i;
                const bf16* g = (ks < 4)
                    ? kvb + row * 4096 + h * 256 + ks * 32 + quad * 8
                    : cb  + row * 640  + 512 + (ks - 4) * 32 + quad * 8;
                load_lds16(g, &Ks[bufi][(mt * 6 + ks) * 512]);
            }
        } else {
            const int nt = wave - 8;
#pragma unroll
            for (int i = 0; i < 2; ++i) {
                const bf16* g = vt_head + (size_t)(nt * 16 + l15) * 2048
                                + kv0 + (i * 4 + quad) * 8;
                load_lds16(g, &Vs[bufi][nt * 1024 + i * 512]);
            }
        }
    };

    f32x4 o[8] = {};
    float m_i = -1e30f, l_i = 0.f;
    const float sm_scale = 0.08838834764831845f * 1.4426950408889634f;
    const int qmin_w = q0 + wave * 16;

    stage(t0, 0);
    stage(t0 + 1, 1);

    int cur = 0;
    for (int kt = t0; kt < t1; ++kt, cur ^= 1) {
        const int kv0 = kt * 64;

        if (kt + 1 < t1) {
            if (wave < 8) asm volatile("s_waitcnt vmcnt(3)" ::: "memory");
            else          asm volatile("s_waitcnt vmcnt(2)" ::: "memory");
        } else {
            asm volatile("s_waitcnt vmcnt(0)" ::: "memory");
        }
        __builtin_amdgcn_s_barrier();
        __builtin_amdgcn_sched_barrier(0);

        f32x4 s[4];
        __builtin_amdgcn_s_setprio(1);
#pragma unroll
        for (int mt = 0; mt < 4; ++mt) {
            f32x4 a = {};
#pragma unroll
            for (int ks = 0; ks < 6; ++ks) {
                bf16x8 kf = *(const bf16x8*)&Ks[cur][(mt * 6 + ks) * 512 + lane * 8];
                a = __builtin_amdgcn_mfma_f32_16x16x32_bf16(kf, qf[ks], a, 0, 0, 0);
            }
            s[mt] = a;
        }
        __builtin_amdgcn_s_setprio(0);

        if (kv0 + 63 > qmin_w) {
#pragma unroll
            for (int mt = 0; mt < 4; ++mt)
#pragma unroll
                for (int r = 0; r < 4; ++r) {
                    int kvi = kv0 + mt * 16 + quad * 4 + r;
                    s[mt][r] = (kvi <= qrow) ? s[mt][r] * sm_scale : -1e30f;
                }
        } else {
#pragma unroll
            for (int mt = 0; mt < 4; ++mt)
#pragma unroll
                for (int r = 0; r < 4; ++r)
                    s[mt][r] = s[mt][r] * sm_scale;
        }
        float mx4[4];
#pragma unroll
        for (int mt = 0; mt < 4; ++mt)
            mx4[mt] = fmaxf(fmaxf(s[mt][0], s[mt][1]),
                            fmaxf(s[mt][2], s[mt][3]));
        float mx = fmaxf(fmaxf(mx4[0], mx4[1]), fmaxf(mx4[2], mx4[3]));
        mx = fmaxf(mx, __shfl_xor(mx, 16, 64));
        mx = fmaxf(mx, __shfl_xor(mx, 32, 64));
        float m_new = fmaxf(m_i, mx);
        float su4[4];
        bf16x4 pf[4];
#pragma unroll
        for (int mt = 0; mt < 4; ++mt) {
            float e0 = exp2f(s[mt][0] - m_new);
            float e1 = exp2f(s[mt][1] - m_new);
            float e2 = exp2f(s[mt][2] - m_new);
            float e3 = exp2f(s[mt][3] - m_new);
            su4[mt] = (e0 + e1) + (e2 + e3);
            pf[mt][0] = (bf16)e0; pf[mt][1] = (bf16)e1;
            pf[mt][2] = (bf16)e2; pf[mt][3] = (bf16)e3;
        }
        float su = (su4[0] + su4[1]) + (su4[2] + su4[3]);
        su += __shfl_xor(su, 16, 64);
        su += __shfl_xor(su, 32, 64);
        if (__all(mx <= m_i)) {
            l_i += su;
        } else {
            float alpha = exp2f(m_i - m_new);
            l_i = l_i * alpha + su;
            m_i = m_new;
            float alpha_r[4];
#pragma unroll
            for (int r = 0; r < 4; ++r)
                alpha_r[r] = __shfl(alpha, quad * 4 + r, 64);
#pragma unroll
            for (int nt = 0; nt < 8; ++nt)
#pragma unroll
                for (int r = 0; r < 4; ++r) o[nt][r] *= alpha_r[r];
        }

        __builtin_amdgcn_s_setprio(1);
#pragma unroll
        for (int ktk = 0; ktk < 4; ++ktk) {
            s16x4 a = __builtin_bit_cast(s16x4, pf[ktk]);
            const int voff = ktk * 256 + (quad >> 1) * 128 + l15 * 8 + (quad & 1) * 4;
#pragma unroll
            for (int nt = 0; nt < 8; ++nt) {
                s16x4 bfv = __builtin_bit_cast(s16x4,
                    *(const bf16x4*)&Vs[cur][nt * 1024 + voff]);
                o[nt] = __builtin_amdgcn_mfma_f32_16x16x16bf16_1k(a, bfv, o[nt], 0, 0, 0);
            }
        }
        __builtin_amdgcn_s_setprio(0);

        __builtin_amdgcn_s_barrier();
        if (kt + 2 < t1) stage(kt + 2, cur);
    }

    // epilogue
    if (np == 1) {
        float l_r[4];
#pragma unroll
        for (int r = 0; r < 4; ++r) l_r[r] = __shfl(l_i, quad * 4 + r, 64);
        bf16* obase = ob + (size_t)(b * S + q0 + wave * 16) * 2048 + h * 128;
#pragma unroll
        for (int nt = 0; nt < 8; ++nt)
#pragma unroll
            for (int r = 0; r < 4; ++r)
                obase[(size_t)(quad * 4 + r) * 2048 + nt * 16 + l15] =
                    (bf16)(o[nt][r] / l_r[r]);
    } else {
        const int bh = b * 16 + h;
        if (quad == 0) {
            const int qlocal = wave * 16 + l15;
            float* mlp = part_ml + ((size_t)(bh * 8 + k) * 4 + c) * 512;
            mlp[qlocal] = m_i;
            mlp[256 + qlocal] = l_i;
        }
        if (c == np - 1) {
            bf16* obase = ob + (size_t)(b * S + q0 + wave * 16) * 2048 + h * 128;
#pragma unroll
            for (int nt = 0; nt < 8; ++nt)
#pragma unroll
                for (int r = 0; r < 4; ++r)
                    obase[(size_t)(quad * 4 + r) * 2048 + nt * 16 + l15] =
                        (bf16)o[nt][r];
        } else {
            bf16* pb = part_o + (size_t)(bh * 12 + pre_of[k] + c) * 32768
                       + (size_t)(wave * 16) * 128;
#pragma unroll
            for (int nt = 0; nt < 8; ++nt)
#pragma unroll
                for (int r = 0; r < 4; ++r)
                    pb[(quad * 4 + r) * 128 + nt * 16 + l15] = (bf16)o[nt][r];
        }
    }
}

// ---------------------------------------------------------------------------
// Merge np partials for q-pair k>=2.
// ---------------------------------------------------------------------------
__global__ __launch_bounds__(256) void mla_merge(
        const bf16* __restrict__ part_o, const float* __restrict__ part_ml,
        bf16* __restrict__ ob) {
    const signed char np_of[8]  = {1,1,2,2,3,3,4,4};
    const signed char pre_of[8] = {0,0,0,1,2,4,6,9};
    const int k = 2 + blockIdx.x;              // 2..7
    const int h = blockIdx.y, b = blockIdx.z;
    const int bh = b * 16 + h;
    const int np = np_of[k];
    const int row = threadIdx.x;               // 0..255

    const float* mlb = part_ml + (size_t)(bh * 8 + k) * 4 * 512;
    const float m0 = mlb[row],            l0 = mlb[256 + row];
    const float m1 = mlb[512 + row],      l1 = mlb[512 + 256 + row];
    const float m2 = (np > 2) ? mlb[1024 + row] : -1e30f;
    const float l2 = (np > 2) ? mlb[1024 + 256 + row] : 0.f;
    const float m3 = (np > 3) ? mlb[1536 + row] : -1e30f;
    const float l3 = (np > 3) ? mlb[1536 + 256 + row] : 0.f;
    const float M = fmaxf(fmaxf(m0, m1), fmaxf(m2, m3));
    float a0 = exp2f(m0 - M), a1 = exp2f(m1 - M);
    float a2 = exp2f(m2 - M), a3 = exp2f(m3 - M);
    const float inv = 1.f / (l0 * a0 + l1 * a1 + l2 * a2 + l3 * a3);
    a0 *= inv; a1 *= inv; a2 *= inv; a3 *= inv;
    const float alast = (np == 2) ? a1 : (np == 3) ? a2 : a3;

    const bf16* p0 = part_o + (size_t)(bh * 12 + pre_of[k]) * 32768 + row * 128;
    const bf16* p1 = p0 + 32768;
    const bf16* p2 = p1 + 32768;
    bf16* po = ob + (size_t)(b * 2048 + k * 256 + row) * 2048 + h * 128;
#pragma unroll
    for (int i = 0; i < 16; ++i) {
        bf16x8 vb = *(const bf16x8*)(po + i * 8);
        bf16x8 v0 = *(const bf16x8*)(p0 + i * 8);
        float acc[8];
#pragma unroll
        for (int u = 0; u < 8; ++u)
            acc[u] = (float)vb[u] * alast + (float)v0[u] * a0;
        if (np > 2) {
            bf16x8 v1 = *(const bf16x8*)(p1 + i * 8);
#pragma unroll
            for (int u = 0; u < 8; ++u) acc[u] += (float)v1[u] * a1;
        }
        if (np > 3) {
            bf16x8 v2 = *(const bf16x8*)(p2 + i * 8);
#pragma unroll
            for (int u = 0; u < 8; ++u) acc[u] += (float)v2[u] * a2;
        }
        bf16x8 om;
#pragma unroll
        for (int u = 0; u < 8; ++u) om[u] = (bf16)acc[u];
        *(bf16x8*)(po + i * 8) = om;
    }
}

// ---------------------------------------------------------------------------
// launch
// ---------------------------------------------------------------------------
extern "C" void kernel_launch(void* const* d_in, const int* in_sizes, int n_in,
                              void* d_out, int out_size, void* d_ws, size_t ws_size,
                              hipStream_t stream) {
    const float* x    = (const float*)d_in[0];
    const float* wqd  = (const float*)d_in[3];
    const float* wqu  = (const float*)d_in[4];
    const float* wkvd = (const float*)d_in[5];
    const float* wkvu = (const float*)d_in[6];
    const float* wout = (const float*)d_in[7];
    float* out = (float*)d_out;
    char* ws = (char*)d_ws;

    bf16* xb    = (bf16*)(ws + 0);          // 4096x2048 ; reused as vtb
    bf16* vtb   = (bf16*)(ws + 0);          // aliases xb; xb dead after gemm_down
    bf16* wqdT  = (bf16*)(ws + 16777216);   // 768x2048  (dead at attention)
    bf16* wkvdT = (bf16*)(ws + 19922944);   // 640x2048  (dead at attention)
    bf16* wquT  = (bf16*)(ws + 22544384);   // 3072x768  (dead at attention)
    bf16* wkvuT = (bf16*)(ws + 27262976);   // 4096x512  (dead at attention)
    float* part_ml = (float*)(ws + 16777216); // 2 MB (aliases dead weights)
    bf16* part_o  = (bf16*)out;             // 24 MB (out dead until final GEMM)
    bf16* woutT = (bf16*)(ws + 31457280);   // 2048x2048
    bf16* qd    = (bf16*)(ws + 39845888);   // 4096x768
    bf16* qb    = (bf16*)(ws + 46137344);   // 4096x3072
    bf16* cb    = (bf16*)(ws + 71303168);   // 4096x640
    bf16* kvb   = (bf16*)(ws + 76546048);   // 4096x4096 (only k_nope halves written)
    bf16* attnb = (bf16*)(ws + 110100480);  // 4096x2048

    prep_fused<<<19456, 256, 0, stream>>>(x, xb, wqd, wqdT, wkvd, wkvdT,
                                          wqu, wquT, wkvu, wkvuT, wout, woutT);

    gemm_down<<<dim3(11, 32), 256, 0, stream>>>(xb, wqdT, qd, cb);   // last reader of xb
    // 256^2 8-phase up-proj GEMMs with fused V-transpose
    gemm_up256<<<dim3(28, 16), 512, 0, stream>>>(qd, wquT, qb, cb, wkvuT, kvb, vtb);

    mla_attention_split<<<dim3(20, 16, 2), 1024, 0, stream>>>(
        qb, kvb, cb, vtb, attnb, part_o, part_ml);
    mla_merge<<<dim3(6, 16, 2), 256, 0, stream>>>(part_o, part_ml, attnb);

    // 256x128-tile 8-phase output GEMM (256 blocks = full machine fill)
    gemm_out256<<<dim3(16, 16), 512, 0, stream>>>(attnb, woutT, out);
}

// Round 11
// 422.967 us; speedup vs baseline: 1.1715x; 1.0281x over previous
//
#include <hip/hip_runtime.h>

typedef __bf16 bf16;
typedef bf16 bf16x8 __attribute__((ext_vector_type(8)));
typedef bf16 bf16x4 __attribute__((ext_vector_type(4)));
typedef float f32x4 __attribute__((ext_vector_type(4)));
typedef short s16x4 __attribute__((ext_vector_type(4)));

#define AS1 __attribute__((address_space(1)))
#define AS3 __attribute__((address_space(3)))

__device__ __forceinline__ void load_lds16(const void* g, void* l) {
    __builtin_amdgcn_global_load_lds((const AS1 unsigned int*)g,
                                     (AS3 unsigned int*)l, 16, 0, 0);
}

// ---------------------------------------------------------------------------
// Fused prep: cast x->bf16 + 5 weight transposes, one flat-grid dispatch.
// ---------------------------------------------------------------------------
__device__ __forceinline__ void tc_body(
        const float* __restrict__ in, bf16* __restrict__ out,
        int K, int N, int Np, int bx, int by, int tid,
        float (*tile)[33]) {
    const int tx = tid & 31, ty = tid >> 5;   // 32 x 8
#pragma unroll
    for (int i = 0; i < 4; ++i) {
        int k = by + ty + i * 8, n = bx + tx;
        float v = (k < K && n < N) ? in[(size_t)k * N + n] : 0.f;
        tile[ty + i * 8][tx] = v;
    }
    __syncthreads();
#pragma unroll
    for (int i = 0; i < 4; ++i) {
        int n = bx + ty + i * 8, k = by + tx;
        if (n < Np && k < K) out[(size_t)n * K + k] = (bf16)tile[tx][ty + i * 8];
    }
}

__global__ __launch_bounds__(256) void prep_fused(
        const float* __restrict__ x,    bf16* __restrict__ xb,
        const float* __restrict__ wqd,  bf16* __restrict__ wqdT,
        const float* __restrict__ wkvd, bf16* __restrict__ wkvdT,
        const float* __restrict__ wqu,  bf16* __restrict__ wquT,
        const float* __restrict__ wkvu, bf16* __restrict__ wkvuT,
        const float* __restrict__ wout, bf16* __restrict__ woutT) {
    __shared__ float tile[32][33];
    const int tid = threadIdx.x;
    int r = blockIdx.x;
    if (r < 8192) {           // cast: 8388608 floats, 4/thread
        int i = (r * 256 + tid) * 4;
        float4 v = *(const float4*)(x + i);
        bf16x4 o = { (bf16)v.x, (bf16)v.y, (bf16)v.z, (bf16)v.w };
        *(bf16x4*)(xb + i) = o;
        return;
    }
    r -= 8192;
    if (r < 1536) { tc_body(wqd,  wqdT,  2048, 768,  768,  (r % 24) * 32, (r / 24) * 32, tid, tile); return; }
    r -= 1536;
    if (r < 1280) { tc_body(wkvd, wkvdT, 2048, 576,  640,  (r % 20) * 32, (r / 20) * 32, tid, tile); return; }
    r -= 1280;
    if (r < 2304) { tc_body(wqu,  wquT,  768,  3072, 3072, (r % 96) * 32, (r / 96) * 32, tid, tile); return; }
    r -= 2304;
    if (r < 2048) { tc_body(wkvu, wkvuT, 512,  4096, 4096, (r % 128) * 32, (r / 128) * 32, tid, tile); return; }
    r -= 2048;
    tc_body(wout, woutT, 2048, 2048, 2048, (r % 64) * 32, (r / 64) * 32, tid, tile);
}

// ---------------------------------------------------------------------------
// 256x256-tile 8-phase GEMM for the up-projections (m201 template).
//   blockIdx.x <  12 : qb  = qd @ wquT^T   (K=768, 12 K-tiles)
//   blockIdx.x >= 12 : kvb/vtb = cb @ wkvuT^T (K=512, 8 K-tiles);
//     cols [0,128) of head -> kvb; cols [128,256) -> V -> vtb (fused T).
// ---------------------------------------------------------------------------
__global__ __launch_bounds__(512, 2) void gemm_up256(
        const bf16* __restrict__ qd, const bf16* __restrict__ wquT,
        bf16* __restrict__ qb,
        const bf16* __restrict__ cb, const bf16* __restrict__ wkvuT,
        bf16* __restrict__ kvb, bf16* __restrict__ vtb) {
    __shared__ __align__(16) bf16 sh[65536];   // 128 KB: A[2][16384] | B[2][16384]
    const int tid = threadIdx.x;
    const int wave = tid >> 6, lane = tid & 63;
    const int l15 = lane & 15, quad = lane >> 4;
    const int wr = wave >> 2, wc = wave & 3;     // 2M x 4N wave grid
    const int m0 = blockIdx.y * 256;
    const bool is_q = blockIdx.x < 12;
    const int n0 = is_q ? blockIdx.x * 256 : (blockIdx.x - 12) * 256;
    const bf16* Ag  = is_q ? qd : cb;
    const bf16* Btg = is_q ? wquT : wkvuT;
    const int lda = is_q ? 768 : 640;
    const int ldb = is_q ? 768 : 512;
    const int NT  = is_q ? 12 : 8;

    const int gcol = (((tid & 7) ^ ((tid >> 3) & 7)) * 8);
    auto stage = [&](int kt, int bufi) {
        const int k0 = kt * 64;
#pragma unroll
        for (int c = 0; c < 4; ++c) {
            const int row = c * 64 + (tid >> 3);
            const int ldsb = bufi * 16384 + c * 4096 + wave * 512;  // wave-uniform
            load_lds16(Ag  + (size_t)(m0 + row) * lda + k0 + gcol, &sh[ldsb]);
            load_lds16(Btg + (size_t)(n0 + row) * ldb + k0 + gcol, &sh[32768 + ldsb]);
        }
    };

    const int sw = (l15 & 7) * 8;   // read-side swizzle (row&7 == l15&7)
    f32x4 acc[8][4] = {};

    stage(0, 0);
    asm volatile("s_waitcnt vmcnt(0)" ::: "memory");
    __builtin_amdgcn_s_barrier();
    __builtin_amdgcn_sched_barrier(0);

    for (int kt = 0; kt < NT; ++kt) {
        const int bufi = kt & 1;
        const bf16* As_ = &sh[bufi * 16384];
        const bf16* Bs_ = &sh[32768 + bufi * 16384];
        bf16x8 bfr[4][2];
#pragma unroll
        for (int p = 0; p < 4; ++p) {
            bf16x8 afr[2][2];
#pragma unroll
            for (int ii = 0; ii < 2; ++ii) {
                const int arow = (wr * 128 + (p * 2 + ii) * 16 + l15) * 64;
#pragma unroll
                for (int kki = 0; kki < 2; ++kki)
                    afr[ii][kki] = *(const bf16x8*)&As_[arow + ((kki * 32 + quad * 8) ^ sw)];
            }
            if (p == 0) {
#pragma unroll
                for (int j = 0; j < 4; ++j) {
                    const int brow = (wc * 64 + j * 16 + l15) * 64;
#pragma unroll
                    for (int kki = 0; kki < 2; ++kki)
                        bfr[j][kki] = *(const bf16x8*)&Bs_[brow + ((kki * 32 + quad * 8) ^ sw)];
                }
                if (kt + 1 < NT) stage(kt + 1, bufi ^ 1);   // all 8 gloads early
            }
            __builtin_amdgcn_s_barrier();                    // phase-lock waves
            asm volatile("s_waitcnt lgkmcnt(0)" ::: "memory");
            __builtin_amdgcn_sched_barrier(0);
            __builtin_amdgcn_s_setprio(1);
#pragma unroll
            for (int ii = 0; ii < 2; ++ii)
#pragma unroll
                for (int j = 0; j < 4; ++j)
#pragma unroll
                    for (int kki = 0; kki < 2; ++kki)
                        acc[p * 2 + ii][j] = __builtin_amdgcn_mfma_f32_16x16x32_bf16(
                            afr[ii][kki], bfr[j][kki], acc[p * 2 + ii][j], 0, 0, 0);
            __builtin_amdgcn_s_setprio(0);
            if (p == 3) asm volatile("s_waitcnt vmcnt(0)" ::: "memory");
            __builtin_amdgcn_s_barrier();                    // phase end; LDS safe
            __builtin_amdgcn_sched_barrier(0);
        }
    }

    // ---- epilogue ----
    if (is_q) {
#pragma unroll
        for (int i = 0; i < 8; ++i)
#pragma unroll
            for (int j = 0; j < 4; ++j) {
                const int row = m0 + wr * 128 + i * 16 + quad * 4;
                const int col = n0 + wc * 64 + j * 16 + l15;
#pragma unroll
                for (int r = 0; r < 4; ++r)
                    qb[(size_t)(row + r) * 3072 + col] = (bf16)acc[i][j][r];
            }
        return;
    }
    const int h = n0 >> 8;
    const int bb = m0 >> 11, kvbase = m0 & 2047;
    bf16* t = sh;                       // [128][264] transpose buffer (67.6 KB)
    if (wc < 2) {                       // k_nope cols [0,128) -> kvb
#pragma unroll
        for (int i = 0; i < 8; ++i)
#pragma unroll
            for (int j = 0; j < 4; ++j) {
                const int row = m0 + wr * 128 + i * 16 + quad * 4;
                const int col = h * 256 + wc * 64 + j * 16 + l15;
#pragma unroll
                for (int r = 0; r < 4; ++r)
                    kvb[(size_t)(row + r) * 4096 + col] = (bf16)acc[i][j][r];
            }
    } else {                            // V cols [128,256): transpose into LDS
#pragma unroll
        for (int i = 0; i < 8; ++i)
#pragma unroll
            for (int j = 0; j < 4; ++j) {
                const int vd = (wc - 2) * 64 + j * 16 + l15;
                const int kv = wr * 128 + i * 16 + quad * 4;
                bf16x4 v;
#pragma unroll
                for (int r = 0; r < 4; ++r) v[r] = (bf16)acc[i][j][r];
                *(bf16x4*)&t[vd * 264 + kv] = v;
            }
    }
    __syncthreads();
    {   // cooperative readout: 512 threads, vd = tid>>2, 64-kv span each
        bf16* vt = vtb + (size_t)((bb * 16 + h) * 128) * 2048;
        const int vd = tid >> 2;
        const int kv4 = (tid & 3) * 64;
#pragma unroll
        for (int u = 0; u < 8; ++u) {
            bf16x8 vv = *(const bf16x8*)&t[vd * 264 + kv4 + u * 8];
            *(bf16x8*)&vt[(size_t)vd * 2048 + kvbase + kv4 + u * 8] = vv;
        }
    }
}

// ---------------------------------------------------------------------------
// 256x128-tile 8-phase GEMM body (template shared by gemm_out256 and
// gemm_down256): A 256 rows, Bt 128 rows, BK=64, 8 waves as 4M x 2N,
// acc[4][4]/wave. LDS 96 KB dbuf; both-sides XOR swizzle; vmcnt(0) at p3.
// Same K-summation order as the old 128^2 kernel -> numerically identical.
// ---------------------------------------------------------------------------
__device__ __forceinline__ void gemm256x128_acc(
        const bf16* __restrict__ A, const bf16* __restrict__ Bt,
        int lda, int ldb, int NT, int m0, int n0,
        bf16* sh, f32x4 acc[4][4]) {
    const int tid = threadIdx.x;
    const int wave = tid >> 6, lane = tid & 63;
    const int l15 = lane & 15, quad = lane >> 4;
    const int wr = wave >> 1, wc = wave & 1;     // 4M x 2N wave grid

    const int gcol = (((tid & 7) ^ ((tid >> 3) & 7)) * 8);
    auto stage = [&](int kt, int bufi) {
        const int k0 = kt * 64;
#pragma unroll
        for (int c = 0; c < 4; ++c) {            // A: 256 rows
            const int row = c * 64 + (tid >> 3);
            load_lds16(A + (size_t)(m0 + row) * lda + k0 + gcol,
                       &sh[bufi * 16384 + c * 4096 + wave * 512]);
        }
#pragma unroll
        for (int c = 0; c < 2; ++c) {            // B: 128 rows
            const int row = c * 64 + (tid >> 3);
            load_lds16(Bt + (size_t)(n0 + row) * ldb + k0 + gcol,
                       &sh[32768 + bufi * 8192 + c * 4096 + wave * 512]);
        }
    };

    const int sw = (l15 & 7) * 8;

    stage(0, 0);
    asm volatile("s_waitcnt vmcnt(0)" ::: "memory");
    __builtin_amdgcn_s_barrier();
    __builtin_amdgcn_sched_barrier(0);

    for (int kt = 0; kt < NT; ++kt) {
        const int bufi = kt & 1;
        const bf16* As_ = &sh[bufi * 16384];
        const bf16* Bs_ = &sh[32768 + bufi * 8192];
        bf16x8 bfr[4][2];
#pragma unroll
        for (int p = 0; p < 4; ++p) {
            bf16x8 afr[2];
            {
                const int arow = (wr * 64 + p * 16 + l15) * 64;
#pragma unroll
                for (int kki = 0; kki < 2; ++kki)
                    afr[kki] = *(const bf16x8*)&As_[arow + ((kki * 32 + quad * 8) ^ sw)];
            }
            if (p == 0) {
#pragma unroll
                for (int j = 0; j < 4; ++j) {
                    const int brow = (wc * 64 + j * 16 + l15) * 64;
#pragma unroll
                    for (int kki = 0; kki < 2; ++kki)
                        bfr[j][kki] = *(const bf16x8*)&Bs_[brow + ((kki * 32 + quad * 8) ^ sw)];
                }
                if (kt + 1 < NT) stage(kt + 1, bufi ^ 1);
            }
            __builtin_amdgcn_s_barrier();
            asm volatile("s_waitcnt lgkmcnt(0)" ::: "memory");
            __builtin_amdgcn_sched_barrier(0);
            __builtin_amdgcn_s_setprio(1);
#pragma unroll
            for (int j = 0; j < 4; ++j)
#pragma unroll
                for (int kki = 0; kki < 2; ++kki)
                    acc[p][j] = __builtin_amdgcn_mfma_f32_16x16x32_bf16(
                        afr[kki], bfr[j][kki], acc[p][j], 0, 0, 0);
            __builtin_amdgcn_s_setprio(0);
            if (p == 3) asm volatile("s_waitcnt vmcnt(0)" ::: "memory");
            __builtin_amdgcn_s_barrier();
            __builtin_amdgcn_sched_barrier(0);
        }
    }
}

// out[4096][2048] = attnb @ woutT^T, f32. Grid 16x16 = 256 blocks (1/CU).
__global__ __launch_bounds__(512, 2) void gemm_out256(
        const bf16* __restrict__ A, const bf16* __restrict__ Bt,
        float* __restrict__ C) {
    __shared__ __align__(16) bf16 sh[49152];   // 96 KB
    const int m0 = blockIdx.y * 256, n0 = blockIdx.x * 128;
    f32x4 acc[4][4] = {};
    gemm256x128_acc(A, Bt, 2048, 2048, 32, m0, n0, sh, acc);
    const int tid = threadIdx.x;
    const int wave = tid >> 6, lane = tid & 63;
    const int l15 = lane & 15, quad = lane >> 4;
    const int wr = wave >> 1, wc = wave & 1;
#pragma unroll
    for (int i = 0; i < 4; ++i)
#pragma unroll
        for (int j = 0; j < 4; ++j) {
            const int row = m0 + wr * 64 + i * 16 + quad * 4;
            const int col = n0 + wc * 64 + j * 16 + l15;
#pragma unroll
            for (int r = 0; r < 4; ++r)
                C[(size_t)(row + r) * 2048 + col] = acc[i][j][r];
        }
}

// Fused down-proj: xb @ [wqdT;wkvdT]^T (contiguous [1408][2048] Bt).
// Grid 11x16 = 176 blocks; cols [0,768) -> qd (ldc 768), [768,1408) -> cb
// (ldc 640). 768 = 6*128 so each block lands wholly in one output.
__global__ __launch_bounds__(512, 2) void gemm_down256(
        const bf16* __restrict__ A, const bf16* __restrict__ Bt,
        bf16* __restrict__ C1, bf16* __restrict__ C2) {
    __shared__ __align__(16) bf16 sh[49152];   // 96 KB
    const int m0 = blockIdx.y * 256, n0 = blockIdx.x * 128;
    f32x4 acc[4][4] = {};
    gemm256x128_acc(A, Bt, 2048, 2048, 32, m0, n0, sh, acc);
    bf16* Cp; int ldc, coff;
    if (n0 < 768) { Cp = C1; ldc = 768; coff = 0; }
    else          { Cp = C2; ldc = 640; coff = 768; }
    const int tid = threadIdx.x;
    const int wave = tid >> 6, lane = tid & 63;
    const int l15 = lane & 15, quad = lane >> 4;
    const int wr = wave >> 1, wc = wave & 1;
#pragma unroll
    for (int i = 0; i < 4; ++i)
#pragma unroll
        for (int j = 0; j < 4; ++j) {
            const int row = m0 + wr * 64 + i * 16 + quad * 4;
            const int col = n0 + wc * 64 + j * 16 + l15 - coff;
#pragma unroll
            for (int r = 0; r < 4; ++r)
                Cp[(size_t)(row + r) * ldc + col] = (bf16)acc[i][j][r];
        }
}

// ---------------------------------------------------------------------------
// Flash attention (causal), SPLIT-K flash-decoding style.  [round-5/7 config]
// 16 WAVES / 256 q-rows per block; kv tiles of 64; 80KB LDS dbuf K+V.
// waves 0-7 stage K (3 DMAs/tile, vmcnt(3)); waves 8-15 stage V (2, vmcnt(2)).
// Residency: 1 block/CU (register file: 64 arch VGPR + acc on unified file).
// ---------------------------------------------------------------------------
__global__ __launch_bounds__(1024, 4) void mla_attention_split(
        const bf16* __restrict__ qb, const bf16* __restrict__ kvb,
        const bf16* __restrict__ cb, const bf16* __restrict__ vtb,
        bf16* __restrict__ ob, bf16* __restrict__ part_o,
        float* __restrict__ part_ml) {
    constexpr int S = 2048;
    const signed char k_of[20]  = {7,7,7,7, 6,6,6,6, 5,5,5, 4,4,4, 3,3, 2,2, 1, 0};
    const signed char c_of[20]  = {0,1,2,3, 0,1,2,3, 0,1,2, 0,1,2, 0,1, 0,1, 0, 0};
    const signed char np_of[8]  = {1,1,2,2,3,3,4,4};
    const signed char pre_of[8] = {0,0,0,1,2,4,6,9};

    const int k  = k_of[blockIdx.x], c = c_of[blockIdx.x];
    const int np = np_of[k];
    const int h = blockIdx.y, b = blockIdx.z;
    const int T  = 4 * k + 4;
    const int t0 = (c * T) / np, t1 = ((c + 1) * T) / np;
    const int q0 = k * 256;

    const int tid = threadIdx.x, wave = tid >> 6, lane = tid & 63;
    const int l15 = lane & 15, quad = lane >> 4;

    __shared__ __align__(16) bf16 Ks[2][24 * 512];
    __shared__ __align__(16) bf16 Vs[2][8 * 1024];

    const int qrow = q0 + wave * 16 + l15;
    bf16x8 qf[6];
    {
        const bf16* qr = qb + (size_t)(b * S + qrow) * 3072 + h * 192;
#pragma unroll
        for (int ks = 0; ks < 6; ++ks)
            qf[ks] = *(const bf16x8*)(qr + ks * 32 + quad * 8);
    }

    const bf16* vt_head = vtb + (size_t)((b * 16 + h) * 128) * 2048;

    auto stage = [&](int kt, int bufi) {
        const int kv0 = kt * 64;
        if (wave < 8) {
            const int mt = wave >> 1;
            const size_t row = (size_t)(b * S + kv0 + mt * 16 + l15);
#pragma unroll
            for (int i = 0; i < 3; ++i) {
                const int ks = (wave & 1) * 3 + i;
                const bf16* g = (ks < 4)
                    ? kvb + row * 4096 + h * 256 + ks * 32 + quad * 8
                    : cb  + row * 640  + 512 + (ks - 4) * 32 + quad * 8;
                load_lds16(g, &Ks[bufi][(mt * 6 + ks) * 512]);
            }
        } else {
            const int nt = wave - 8;
#pragma unroll
            for (int i = 0; i < 2; ++i) {
                const bf16* g = vt_head + (size_t)(nt * 16 + l15) * 2048
                                + kv0 + (i * 4 + quad) * 8;
                load_lds16(g, &Vs[bufi][nt * 1024 + i * 512]);
            }
        }
    };

    f32x4 o[8] = {};
    float m_i = -1e30f, l_i = 0.f;
    const float sm_scale = 0.08838834764831845f * 1.4426950408889634f;
    const int qmin_w = q0 + wave * 16;

    stage(t0, 0);
    stage(t0 + 1, 1);

    int cur = 0;
    for (int kt = t0; kt < t1; ++kt, cur ^= 1) {
        const int kv0 = kt * 64;

        if (kt + 1 < t1) {
            if (wave < 8) asm volatile("s_waitcnt vmcnt(3)" ::: "memory");
            else          asm volatile("s_waitcnt vmcnt(2)" ::: "memory");
        } else {
            asm volatile("s_waitcnt vmcnt(0)" ::: "memory");
        }
        __builtin_amdgcn_s_barrier();
        __builtin_amdgcn_sched_barrier(0);

        f32x4 s[4];
        __builtin_amdgcn_s_setprio(1);
#pragma unroll
        for (int mt = 0; mt < 4; ++mt) {
            f32x4 a = {};
#pragma unroll
            for (int ks = 0; ks < 6; ++ks) {
                bf16x8 kf = *(const bf16x8*)&Ks[cur][(mt * 6 + ks) * 512 + lane * 8];
                a = __builtin_amdgcn_mfma_f32_16x16x32_bf16(kf, qf[ks], a, 0, 0, 0);
            }
            s[mt] = a;
        }
        __builtin_amdgcn_s_setprio(0);

        if (kv0 + 63 > qmin_w) {
#pragma unroll
            for (int mt = 0; mt < 4; ++mt)
#pragma unroll
                for (int r = 0; r < 4; ++r) {
                    int kvi = kv0 + mt * 16 + quad * 4 + r;
                    s[mt][r] = (kvi <= qrow) ? s[mt][r] * sm_scale : -1e30f;
                }
        } else {
#pragma unroll
            for (int mt = 0; mt < 4; ++mt)
#pragma unroll
                for (int r = 0; r < 4; ++r)
                    s[mt][r] = s[mt][r] * sm_scale;
        }
        float mx4[4];
#pragma unroll
        for (int mt = 0; mt < 4; ++mt)
            mx4[mt] = fmaxf(fmaxf(s[mt][0], s[mt][1]),
                            fmaxf(s[mt][2], s[mt][3]));
        float mx = fmaxf(fmaxf(mx4[0], mx4[1]), fmaxf(mx4[2], mx4[3]));
        mx = fmaxf(mx, __shfl_xor(mx, 16, 64));
        mx = fmaxf(mx, __shfl_xor(mx, 32, 64));
        float m_new = fmaxf(m_i, mx);
        float su4[4];
        bf16x4 pf[4];
#pragma unroll
        for (int mt = 0; mt < 4; ++mt) {
            float e0 = exp2f(s[mt][0] - m_new);
            float e1 = exp2f(s[mt][1] - m_new);
            float e2 = exp2f(s[mt][2] - m_new);
            float e3 = exp2f(s[mt][3] - m_new);
            su4[mt] = (e0 + e1) + (e2 + e3);
            pf[mt][0] = (bf16)e0; pf[mt][1] = (bf16)e1;
            pf[mt][2] = (bf16)e2; pf[mt][3] = (bf16)e3;
        }
        float su = (su4[0] + su4[1]) + (su4[2] + su4[3]);
        su += __shfl_xor(su, 16, 64);
        su += __shfl_xor(su, 32, 64);
        if (__all(mx <= m_i)) {
            l_i += su;
        } else {
            float alpha = exp2f(m_i - m_new);
            l_i = l_i * alpha + su;
            m_i = m_new;
            float alpha_r[4];
#pragma unroll
            for (int r = 0; r < 4; ++r)
                alpha_r[r] = __shfl(alpha, quad * 4 + r, 64);
#pragma unroll
            for (int nt = 0; nt < 8; ++nt)
#pragma unroll
                for (int r = 0; r < 4; ++r) o[nt][r] *= alpha_r[r];
        }

        __builtin_amdgcn_s_setprio(1);
#pragma unroll
        for (int ktk = 0; ktk < 4; ++ktk) {
            s16x4 a = __builtin_bit_cast(s16x4, pf[ktk]);
            const int voff = ktk * 256 + (quad >> 1) * 128 + l15 * 8 + (quad & 1) * 4;
#pragma unroll
            for (int nt = 0; nt < 8; ++nt) {
                s16x4 bfv = __builtin_bit_cast(s16x4,
                    *(const bf16x4*)&Vs[cur][nt * 1024 + voff]);
                o[nt] = __builtin_amdgcn_mfma_f32_16x16x16bf16_1k(a, bfv, o[nt], 0, 0, 0);
            }
        }
        __builtin_amdgcn_s_setprio(0);

        __builtin_amdgcn_s_barrier();
        if (kt + 2 < t1) stage(kt + 2, cur);
    }

    // epilogue
    if (np == 1) {
        float l_r[4];
#pragma unroll
        for (int r = 0; r < 4; ++r) l_r[r] = __shfl(l_i, quad * 4 + r, 64);
        bf16* obase = ob + (size_t)(b * S + q0 + wave * 16) * 2048 + h * 128;
#pragma unroll
        for (int nt = 0; nt < 8; ++nt)
#pragma unroll
            for (int r = 0; r < 4; ++r)
                obase[(size_t)(quad * 4 + r) * 2048 + nt * 16 + l15] =
                    (bf16)(o[nt][r] / l_r[r]);
    } else {
        const int bh = b * 16 + h;
        if (quad == 0) {
            const int qlocal = wave * 16 + l15;
            float* mlp = part_ml + ((size_t)(bh * 8 + k) * 4 + c) * 512;
            mlp[qlocal] = m_i;
            mlp[256 + qlocal] = l_i;
        }
        if (c == np - 1) {
            bf16* obase = ob + (size_t)(b * S + q0 + wave * 16) * 2048 + h * 128;
#pragma unroll
            for (int nt = 0; nt < 8; ++nt)
#pragma unroll
                for (int r = 0; r < 4; ++r)
                    obase[(size_t)(quad * 4 + r) * 2048 + nt * 16 + l15] =
                        (bf16)o[nt][r];
        } else {
            bf16* pb = part_o + (size_t)(bh * 12 + pre_of[k] + c) * 32768
                       + (size_t)(wave * 16) * 128;
#pragma unroll
            for (int nt = 0; nt < 8; ++nt)
#pragma unroll
                for (int r = 0; r < 4; ++r)
                    pb[(quad * 4 + r) * 128 + nt * 16 + l15] = (bf16)o[nt][r];
        }
    }
}

// ---------------------------------------------------------------------------
// Merge np partials for q-pair k>=2.
// ---------------------------------------------------------------------------
__global__ __launch_bounds__(256) void mla_merge(
        const bf16* __restrict__ part_o, const float* __restrict__ part_ml,
        bf16* __restrict__ ob) {
    const signed char np_of[8]  = {1,1,2,2,3,3,4,4};
    const signed char pre_of[8] = {0,0,0,1,2,4,6,9};
    const int k = 2 + blockIdx.x;              // 2..7
    const int h = blockIdx.y, b = blockIdx.z;
    const int bh = b * 16 + h;
    const int np = np_of[k];
    const int row = threadIdx.x;               // 0..255

    const float* mlb = part_ml + (size_t)(bh * 8 + k) * 4 * 512;
    const float m0 = mlb[row],            l0 = mlb[256 + row];
    const float m1 = mlb[512 + row],      l1 = mlb[512 + 256 + row];
    const float m2 = (np > 2) ? mlb[1024 + row] : -1e30f;
    const float l2 = (np > 2) ? mlb[1024 + 256 + row] : 0.f;
    const float m3 = (np > 3) ? mlb[1536 + row] : -1e30f;
    const float l3 = (np > 3) ? mlb[1536 + 256 + row] : 0.f;
    const float M = fmaxf(fmaxf(m0, m1), fmaxf(m2, m3));
    float a0 = exp2f(m0 - M), a1 = exp2f(m1 - M);
    float a2 = exp2f(m2 - M), a3 = exp2f(m3 - M);
    const float inv = 1.f / (l0 * a0 + l1 * a1 + l2 * a2 + l3 * a3);
    a0 *= inv; a1 *= inv; a2 *= inv; a3 *= inv;
    const float alast = (np == 2) ? a1 : (np == 3) ? a2 : a3;

    const bf16* p0 = part_o + (size_t)(bh * 12 + pre_of[k]) * 32768 + row * 128;
    const bf16* p1 = p0 + 32768;
    const bf16* p2 = p1 + 32768;
    bf16* po = ob + (size_t)(b * 2048 + k * 256 + row) * 2048 + h * 128;
#pragma unroll
    for (int i = 0; i < 16; ++i) {
        bf16x8 vb = *(const bf16x8*)(po + i * 8);
        bf16x8 v0 = *(const bf16x8*)(p0 + i * 8);
        float acc[8];
#pragma unroll
        for (int u = 0; u < 8; ++u)
            acc[u] = (float)vb[u] * alast + (float)v0[u] * a0;
        if (np > 2) {
            bf16x8 v1 = *(const bf16x8*)(p1 + i * 8);
#pragma unroll
            for (int u = 0; u < 8; ++u) acc[u] += (float)v1[u] * a1;
        }
        if (np > 3) {
            bf16x8 v2 = *(const bf16x8*)(p2 + i * 8);
#pragma unroll
            for (int u = 0; u < 8; ++u) acc[u] += (float)v2[u] * a2;
        }
        bf16x8 om;
#pragma unroll
        for (int u = 0; u < 8; ++u) om[u] = (bf16)acc[u];
        *(bf16x8*)(po + i * 8) = om;
    }
}

// ---------------------------------------------------------------------------
// launch
// ---------------------------------------------------------------------------
extern "C" void kernel_launch(void* const* d_in, const int* in_sizes, int n_in,
                              void* d_out, int out_size, void* d_ws, size_t ws_size,
                              hipStream_t stream) {
    const float* x    = (const float*)d_in[0];
    const float* wqd  = (const float*)d_in[3];
    const float* wqu  = (const float*)d_in[4];
    const float* wkvd = (const float*)d_in[5];
    const float* wkvu = (const float*)d_in[6];
    const float* wout = (const float*)d_in[7];
    float* out = (float*)d_out;
    char* ws = (char*)d_ws;

    bf16* xb    = (bf16*)(ws + 0);          // 4096x2048 ; reused as vtb
    bf16* vtb   = (bf16*)(ws + 0);          // aliases xb; xb dead after gemm_down
    bf16* wqdT  = (bf16*)(ws + 16777216);   // 768x2048  (dead at attention)
    bf16* wkvdT = (bf16*)(ws + 19922944);   // 640x2048  (dead at attention)
    bf16* wquT  = (bf16*)(ws + 22544384);   // 3072x768  (dead at attention)
    bf16* wkvuT = (bf16*)(ws + 27262976);   // 4096x512  (dead at attention)
    float* part_ml = (float*)(ws + 16777216); // 2 MB (aliases dead weights)
    bf16* part_o  = (bf16*)out;             // 24 MB (out dead until final GEMM)
    bf16* woutT = (bf16*)(ws + 31457280);   // 2048x2048
    bf16* qd    = (bf16*)(ws + 39845888);   // 4096x768
    bf16* qb    = (bf16*)(ws + 46137344);   // 4096x3072
    bf16* cb    = (bf16*)(ws + 71303168);   // 4096x640
    bf16* kvb   = (bf16*)(ws + 76546048);   // 4096x4096 (only k_nope halves written)
    bf16* attnb = (bf16*)(ws + 110100480);  // 4096x2048

    prep_fused<<<19456, 256, 0, stream>>>(x, xb, wqd, wqdT, wkvd, wkvdT,
                                          wqu, wquT, wkvu, wkvuT, wout, woutT);

    // 256x128-tile 8-phase down-proj (wqdT/wkvdT contiguous -> one Bt)
    gemm_down256<<<dim3(11, 16), 512, 0, stream>>>(xb, wqdT, qd, cb);
    // 256^2 8-phase up-proj GEMMs with fused V-transpose
    gemm_up256<<<dim3(28, 16), 512, 0, stream>>>(qd, wquT, qb, cb, wkvuT, kvb, vtb);

    mla_attention_split<<<dim3(20, 16, 2), 1024, 0, stream>>>(
        qb, kvb, cb, vtb, attnb, part_o, part_ml);
    mla_merge<<<dim3(6, 16, 2), 256, 0, stream>>>(part_o, part_ml, attnb);

    // 256x128-tile 8-phase output GEMM (256 blocks = full machine fill)
    gemm_out256<<<dim3(16, 16), 512, 0, stream>>>(attnb, woutT, out);
}

// Round 12
// 422.056 us; speedup vs baseline: 1.1741x; 1.0022x over previous
//
#include <hip/hip_runtime.h>

typedef __bf16 bf16;
typedef bf16 bf16x8 __attribute__((ext_vector_type(8)));
typedef bf16 bf16x4 __attribute__((ext_vector_type(4)));
typedef float f32x4 __attribute__((ext_vector_type(4)));
typedef short s16x4 __attribute__((ext_vector_type(4)));

#define AS1 __attribute__((address_space(1)))
#define AS3 __attribute__((address_space(3)))

__device__ __forceinline__ void load_lds16(const void* g, void* l) {
    __builtin_amdgcn_global_load_lds((const AS1 unsigned int*)g,
                                     (AS3 unsigned int*)l, 16, 0, 0);
}

// ---------------------------------------------------------------------------
// Fused prep: cast x->bf16 + 5 weight transposes, one flat-grid dispatch.
// ---------------------------------------------------------------------------
__device__ __forceinline__ void tc_body(
        const float* __restrict__ in, bf16* __restrict__ out,
        int K, int N, int Np, int bx, int by, int tid,
        float (*tile)[33]) {
    const int tx = tid & 31, ty = tid >> 5;   // 32 x 8
#pragma unroll
    for (int i = 0; i < 4; ++i) {
        int k = by + ty + i * 8, n = bx + tx;
        float v = (k < K && n < N) ? in[(size_t)k * N + n] : 0.f;
        tile[ty + i * 8][tx] = v;
    }
    __syncthreads();
#pragma unroll
    for (int i = 0; i < 4; ++i) {
        int n = bx + ty + i * 8, k = by + tx;
        if (n < Np && k < K) out[(size_t)n * K + k] = (bf16)tile[tx][ty + i * 8];
    }
}

__global__ __launch_bounds__(256) void prep_fused(
        const float* __restrict__ x,    bf16* __restrict__ xb,
        const float* __restrict__ wqd,  bf16* __restrict__ wqdT,
        const float* __restrict__ wkvd, bf16* __restrict__ wkvdT,
        const float* __restrict__ wqu,  bf16* __restrict__ wquT,
        const float* __restrict__ wkvu, bf16* __restrict__ wkvuT,
        const float* __restrict__ wout, bf16* __restrict__ woutT) {
    __shared__ float tile[32][33];
    const int tid = threadIdx.x;
    int r = blockIdx.x;
    if (r < 8192) {           // cast: 8388608 floats, 4/thread
        int i = (r * 256 + tid) * 4;
        float4 v = *(const float4*)(x + i);
        bf16x4 o = { (bf16)v.x, (bf16)v.y, (bf16)v.z, (bf16)v.w };
        *(bf16x4*)(xb + i) = o;
        return;
    }
    r -= 8192;
    if (r < 1536) { tc_body(wqd,  wqdT,  2048, 768,  768,  (r % 24) * 32, (r / 24) * 32, tid, tile); return; }
    r -= 1536;
    if (r < 1280) { tc_body(wkvd, wkvdT, 2048, 576,  640,  (r % 20) * 32, (r / 20) * 32, tid, tile); return; }
    r -= 1280;
    if (r < 2304) { tc_body(wqu,  wquT,  768,  3072, 3072, (r % 96) * 32, (r / 96) * 32, tid, tile); return; }
    r -= 2304;
    if (r < 2048) { tc_body(wkvu, wkvuT, 512,  4096, 4096, (r % 128) * 32, (r / 128) * 32, tid, tile); return; }
    r -= 2048;
    tc_body(wout, woutT, 2048, 2048, 2048, (r % 64) * 32, (r / 64) * 32, tid, tile);
}

// ---------------------------------------------------------------------------
// 256x256-tile 8-phase GEMM for the up-projections (m201 template).
//   blockIdx.x <  12 : qb  = qd @ wquT^T   (K=768, 12 K-tiles)
//   blockIdx.x >= 12 : kvb/vtb = cb @ wkvuT^T (K=512, 8 K-tiles);
//     cols [0,128) of head -> kvb; cols [128,256) -> V -> vtb (fused T).
// 2-buffer (LDS cap: 3x(A+B) = 192 KB > 160).
// ---------------------------------------------------------------------------
__global__ __launch_bounds__(512, 2) void gemm_up256(
        const bf16* __restrict__ qd, const bf16* __restrict__ wquT,
        bf16* __restrict__ qb,
        const bf16* __restrict__ cb, const bf16* __restrict__ wkvuT,
        bf16* __restrict__ kvb, bf16* __restrict__ vtb) {
    __shared__ __align__(16) bf16 sh[65536];   // 128 KB: A[2][16384] | B[2][16384]
    const int tid = threadIdx.x;
    const int wave = tid >> 6, lane = tid & 63;
    const int l15 = lane & 15, quad = lane >> 4;
    const int wr = wave >> 2, wc = wave & 3;     // 2M x 4N wave grid
    const int m0 = blockIdx.y * 256;
    const bool is_q = blockIdx.x < 12;
    const int n0 = is_q ? blockIdx.x * 256 : (blockIdx.x - 12) * 256;
    const bf16* Ag  = is_q ? qd : cb;
    const bf16* Btg = is_q ? wquT : wkvuT;
    const int lda = is_q ? 768 : 640;
    const int ldb = is_q ? 768 : 512;
    const int NT  = is_q ? 12 : 8;

    const int gcol = (((tid & 7) ^ ((tid >> 3) & 7)) * 8);
    auto stage = [&](int kt, int bufi) {
        const int k0 = kt * 64;
#pragma unroll
        for (int c = 0; c < 4; ++c) {
            const int row = c * 64 + (tid >> 3);
            const int ldsb = bufi * 16384 + c * 4096 + wave * 512;  // wave-uniform
            load_lds16(Ag  + (size_t)(m0 + row) * lda + k0 + gcol, &sh[ldsb]);
            load_lds16(Btg + (size_t)(n0 + row) * ldb + k0 + gcol, &sh[32768 + ldsb]);
        }
    };

    const int sw = (l15 & 7) * 8;   // read-side swizzle (row&7 == l15&7)
    f32x4 acc[8][4] = {};

    stage(0, 0);
    asm volatile("s_waitcnt vmcnt(0)" ::: "memory");
    __builtin_amdgcn_s_barrier();
    __builtin_amdgcn_sched_barrier(0);

    for (int kt = 0; kt < NT; ++kt) {
        const int bufi = kt & 1;
        const bf16* As_ = &sh[bufi * 16384];
        const bf16* Bs_ = &sh[32768 + bufi * 16384];
        bf16x8 bfr[4][2];
#pragma unroll
        for (int p = 0; p < 4; ++p) {
            bf16x8 afr[2][2];
#pragma unroll
            for (int ii = 0; ii < 2; ++ii) {
                const int arow = (wr * 128 + (p * 2 + ii) * 16 + l15) * 64;
#pragma unroll
                for (int kki = 0; kki < 2; ++kki)
                    afr[ii][kki] = *(const bf16x8*)&As_[arow + ((kki * 32 + quad * 8) ^ sw)];
            }
            if (p == 0) {
#pragma unroll
                for (int j = 0; j < 4; ++j) {
                    const int brow = (wc * 64 + j * 16 + l15) * 64;
#pragma unroll
                    for (int kki = 0; kki < 2; ++kki)
                        bfr[j][kki] = *(const bf16x8*)&Bs_[brow + ((kki * 32 + quad * 8) ^ sw)];
                }
                if (kt + 1 < NT) stage(kt + 1, bufi ^ 1);   // all 8 gloads early
            }
            __builtin_amdgcn_s_barrier();                    // phase-lock waves
            asm volatile("s_waitcnt lgkmcnt(0)" ::: "memory");
            __builtin_amdgcn_sched_barrier(0);
            __builtin_amdgcn_s_setprio(1);
#pragma unroll
            for (int ii = 0; ii < 2; ++ii)
#pragma unroll
                for (int j = 0; j < 4; ++j)
#pragma unroll
                    for (int kki = 0; kki < 2; ++kki)
                        acc[p * 2 + ii][j] = __builtin_amdgcn_mfma_f32_16x16x32_bf16(
                            afr[ii][kki], bfr[j][kki], acc[p * 2 + ii][j], 0, 0, 0);
            __builtin_amdgcn_s_setprio(0);
            if (p == 3) asm volatile("s_waitcnt vmcnt(0)" ::: "memory");
            __builtin_amdgcn_s_barrier();                    // phase end; LDS safe
            __builtin_amdgcn_sched_barrier(0);
        }
    }

    // ---- epilogue ----
    if (is_q) {
#pragma unroll
        for (int i = 0; i < 8; ++i)
#pragma unroll
            for (int j = 0; j < 4; ++j) {
                const int row = m0 + wr * 128 + i * 16 + quad * 4;
                const int col = n0 + wc * 64 + j * 16 + l15;
#pragma unroll
                for (int r = 0; r < 4; ++r)
                    qb[(size_t)(row + r) * 3072 + col] = (bf16)acc[i][j][r];
            }
        return;
    }
    const int h = n0 >> 8;
    const int bb = m0 >> 11, kvbase = m0 & 2047;
    bf16* t = sh;                       // [128][264] transpose buffer (67.6 KB)
    if (wc < 2) {                       // k_nope cols [0,128) -> kvb
#pragma unroll
        for (int i = 0; i < 8; ++i)
#pragma unroll
            for (int j = 0; j < 4; ++j) {
                const int row = m0 + wr * 128 + i * 16 + quad * 4;
                const int col = h * 256 + wc * 64 + j * 16 + l15;
#pragma unroll
                for (int r = 0; r < 4; ++r)
                    kvb[(size_t)(row + r) * 4096 + col] = (bf16)acc[i][j][r];
            }
    } else {                            // V cols [128,256): transpose into LDS
#pragma unroll
        for (int i = 0; i < 8; ++i)
#pragma unroll
            for (int j = 0; j < 4; ++j) {
                const int vd = (wc - 2) * 64 + j * 16 + l15;
                const int kv = wr * 128 + i * 16 + quad * 4;
                bf16x4 v;
#pragma unroll
                for (int r = 0; r < 4; ++r) v[r] = (bf16)acc[i][j][r];
                *(bf16x4*)&t[vd * 264 + kv] = v;
            }
    }
    __syncthreads();
    {   // cooperative readout: 512 threads, vd = tid>>2, 64-kv span each
        bf16* vt = vtb + (size_t)((bb * 16 + h) * 128) * 2048;
        const int vd = tid >> 2;
        const int kv4 = (tid & 3) * 64;
#pragma unroll
        for (int u = 0; u < 8; ++u) {
            bf16x8 vv = *(const bf16x8*)&t[vd * 264 + kv4 + u * 8];
            *(bf16x8*)&vt[(size_t)vd * 2048 + kvbase + kv4 + u * 8] = vv;
        }
    }
}

// ---------------------------------------------------------------------------
// 256x128-tile 8-phase GEMM body (gemm_out256 / gemm_down256):
// A 256 rows, Bt 128 rows, BK=64, 8 waves as 4M x 2N, acc[4][4]/wave.
// TRIPLE-buffered LDS (144 KB) + COUNTED vmcnt (T4, m218): per tile kt,
// p0 stages kt+2; p3 waits vmcnt(6) -- retires kt+1's 6 loads (FIFO-older),
// leaves kt+2's in flight. A tile's loads fly ~1.75 K-tiles (vs 0.75 with
// 2 buffers + drain-0). buf[(kt+2)%3] was last read in tile kt-1 (complete).
// Per-wave vmcnt + barrier makes all waves' loads visible before next tile.
// Same K-summation order as before -> numerically identical.
// ---------------------------------------------------------------------------
__device__ __forceinline__ void gemm256x128_acc(
        const bf16* __restrict__ A, const bf16* __restrict__ Bt,
        int lda, int ldb, int NT, int m0, int n0,
        bf16* sh, f32x4 acc[4][4]) {
    const int tid = threadIdx.x;
    const int wave = tid >> 6, lane = tid & 63;
    const int l15 = lane & 15, quad = lane >> 4;
    const int wr = wave >> 1, wc = wave & 1;     // 4M x 2N wave grid

    const int gcol = (((tid & 7) ^ ((tid >> 3) & 7)) * 8);
    // LDS layout (bf16 elems): A bufs at {0,16384,32768}; B bufs at
    // 49152 + {0,8192,16384}. Total 73728 elems = 144 KB.
    auto stage = [&](int kt, int bufi) {
        const int k0 = kt * 64;
#pragma unroll
        for (int c = 0; c < 4; ++c) {            // A: 256 rows
            const int row = c * 64 + (tid >> 3);
            load_lds16(A + (size_t)(m0 + row) * lda + k0 + gcol,
                       &sh[bufi * 16384 + c * 4096 + wave * 512]);
        }
#pragma unroll
        for (int c = 0; c < 2; ++c) {            // B: 128 rows
            const int row = c * 64 + (tid >> 3);
            load_lds16(Bt + (size_t)(n0 + row) * ldb + k0 + gcol,
                       &sh[49152 + bufi * 8192 + c * 4096 + wave * 512]);
        }
    };

    const int sw = (l15 & 7) * 8;

    // prologue: 2 tiles in flight; retire tile 0's (leave tile 1's flying)
    stage(0, 0);
    stage(1, 1);
    asm volatile("s_waitcnt vmcnt(6)" ::: "memory");
    __builtin_amdgcn_s_barrier();
    __builtin_amdgcn_sched_barrier(0);

    for (int kt = 0; kt < NT; ++kt) {
        const int bufi = kt % 3;
        const bf16* As_ = &sh[bufi * 16384];
        const bf16* Bs_ = &sh[49152 + bufi * 8192];
        bf16x8 bfr[4][2];
#pragma unroll
        for (int p = 0; p < 4; ++p) {
            bf16x8 afr[2];
            {
                const int arow = (wr * 64 + p * 16 + l15) * 64;
#pragma unroll
                for (int kki = 0; kki < 2; ++kki)
                    afr[kki] = *(const bf16x8*)&As_[arow + ((kki * 32 + quad * 8) ^ sw)];
            }
            if (p == 0) {
#pragma unroll
                for (int j = 0; j < 4; ++j) {
                    const int brow = (wc * 64 + j * 16 + l15) * 64;
#pragma unroll
                    for (int kki = 0; kki < 2; ++kki)
                        bfr[j][kki] = *(const bf16x8*)&Bs_[brow + ((kki * 32 + quad * 8) ^ sw)];
                }
                if (kt + 2 < NT) stage(kt + 2, (kt + 2) % 3);
            }
            __builtin_amdgcn_s_barrier();
            asm volatile("s_waitcnt lgkmcnt(0)" ::: "memory");
            __builtin_amdgcn_sched_barrier(0);
            __builtin_amdgcn_s_setprio(1);
#pragma unroll
            for (int j = 0; j < 4; ++j)
#pragma unroll
                for (int kki = 0; kki < 2; ++kki)
                    acc[p][j] = __builtin_amdgcn_mfma_f32_16x16x32_bf16(
                        afr[kki], bfr[j][kki], acc[p][j], 0, 0, 0);
            __builtin_amdgcn_s_setprio(0);
            if (p == 3) {
                // retire kt+1's loads; leave kt+2's (if staged) in flight
                if (kt + 2 < NT)
                    asm volatile("s_waitcnt vmcnt(6)" ::: "memory");
                else
                    asm volatile("s_waitcnt vmcnt(0)" ::: "memory");
            }
            __builtin_amdgcn_s_barrier();
            __builtin_amdgcn_sched_barrier(0);
        }
    }
}

// out[4096][2048] = attnb @ woutT^T, f32. Grid 16x16 = 256 blocks (1/CU).
__global__ __launch_bounds__(512, 2) void gemm_out256(
        const bf16* __restrict__ A, const bf16* __restrict__ Bt,
        float* __restrict__ C) {
    __shared__ __align__(16) bf16 sh[73728];   // 144 KB (3-buffer)
    const int m0 = blockIdx.y * 256, n0 = blockIdx.x * 128;
    f32x4 acc[4][4] = {};
    gemm256x128_acc(A, Bt, 2048, 2048, 32, m0, n0, sh, acc);
    const int tid = threadIdx.x;
    const int wave = tid >> 6, lane = tid & 63;
    const int l15 = lane & 15, quad = lane >> 4;
    const int wr = wave >> 1, wc = wave & 1;
#pragma unroll
    for (int i = 0; i < 4; ++i)
#pragma unroll
        for (int j = 0; j < 4; ++j) {
            const int row = m0 + wr * 64 + i * 16 + quad * 4;
            const int col = n0 + wc * 64 + j * 16 + l15;
#pragma unroll
            for (int r = 0; r < 4; ++r)
                C[(size_t)(row + r) * 2048 + col] = acc[i][j][r];
        }
}

// Fused down-proj: xb @ [wqdT;wkvdT]^T (contiguous [1408][2048] Bt).
// Grid 11x16 = 176 blocks; cols [0,768) -> qd (ldc 768), [768,1408) -> cb
// (ldc 640). 768 = 6*128 so each block lands wholly in one output.
__global__ __launch_bounds__(512, 2) void gemm_down256(
        const bf16* __restrict__ A, const bf16* __restrict__ Bt,
        bf16* __restrict__ C1, bf16* __restrict__ C2) {
    __shared__ __align__(16) bf16 sh[73728];   // 144 KB (3-buffer)
    const int m0 = blockIdx.y * 256, n0 = blockIdx.x * 128;
    f32x4 acc[4][4] = {};
    gemm256x128_acc(A, Bt, 2048, 2048, 32, m0, n0, sh, acc);
    bf16* Cp; int ldc, coff;
    if (n0 < 768) { Cp = C1; ldc = 768; coff = 0; }
    else          { Cp = C2; ldc = 640; coff = 768; }
    const int tid = threadIdx.x;
    const int wave = tid >> 6, lane = tid & 63;
    const int l15 = lane & 15, quad = lane >> 4;
    const int wr = wave >> 1, wc = wave & 1;
#pragma unroll
    for (int i = 0; i < 4; ++i)
#pragma unroll
        for (int j = 0; j < 4; ++j) {
            const int row = m0 + wr * 64 + i * 16 + quad * 4;
            const int col = n0 + wc * 64 + j * 16 + l15 - coff;
#pragma unroll
            for (int r = 0; r < 4; ++r)
                Cp[(size_t)(row + r) * ldc + col] = (bf16)acc[i][j][r];
        }
}

// ---------------------------------------------------------------------------
// Flash attention (causal), SPLIT-K flash-decoding style.  [round-5/7 config]
// 16 WAVES / 256 q-rows per block; kv tiles of 64; 80KB LDS dbuf K+V.
// waves 0-7 stage K (3 DMAs/tile, vmcnt(3)); waves 8-15 stage V (2, vmcnt(2)).
// Residency: 1 block/CU (register file: 64 arch VGPR + acc on unified file).
// ---------------------------------------------------------------------------
__global__ __launch_bounds__(1024, 4) void mla_attention_split(
        const bf16* __restrict__ qb, const bf16* __restrict__ kvb,
        const bf16* __restrict__ cb, const bf16* __restrict__ vtb,
        bf16* __restrict__ ob, bf16* __restrict__ part_o,
        float* __restrict__ part_ml) {
    constexpr int S = 2048;
    const signed char k_of[20]  = {7,7,7,7, 6,6,6,6, 5,5,5, 4,4,4, 3,3, 2,2, 1, 0};
    const signed char c_of[20]  = {0,1,2,3, 0,1,2,3, 0,1,2, 0,1,2, 0,1, 0,1, 0, 0};
    const signed char np_of[8]  = {1,1,2,2,3,3,4,4};
    const signed char pre_of[8] = {0,0,0,1,2,4,6,9};

    const int k  = k_of[blockIdx.x], c = c_of[blockIdx.x];
    const int np = np_of[k];
    const int h = blockIdx.y, b = blockIdx.z;
    const int T  = 4 * k + 4;
    const int t0 = (c * T) / np, t1 = ((c + 1) * T) / np;
    const int q0 = k * 256;

    const int tid = threadIdx.x, wave = tid >> 6, lane = tid & 63;
    const int l15 = lane & 15, quad = lane >> 4;

    __shared__ __align__(16) bf16 Ks[2][24 * 512];
    __shared__ __align__(16) bf16 Vs[2][8 * 1024];

    const int qrow = q0 + wave * 16 + l15;
    bf16x8 qf[6];
    {
        const bf16* qr = qb + (size_t)(b * S + qrow) * 3072 + h * 192;
#pragma unroll
        for (int ks = 0; ks < 6; ++ks)
            qf[ks] = *(const bf16x8*)(qr + ks * 32 + quad * 8);
    }

    const bf16* vt_head = vtb + (size_t)((b * 16 + h) * 128) * 2048;

    auto stage = [&](int kt, int bufi) {
        const int kv0 = kt * 64;
        if (wave < 8) {
            const int mt = wave >> 1;
            const size_t row = (size_t)(b * S + kv0 + mt * 16 + l15);
#pragma unroll
            for (int i = 0; i < 3; ++i) {
                const int ks = (wave & 1) * 3 + i;
                const bf16* g = (ks < 4)
                    ? kvb + row * 4096 + h * 256 + ks * 32 + quad * 8
                    : cb  + row * 640  + 512 + (ks - 4) * 32 + quad * 8;
                load_lds16(g, &Ks[bufi][(mt * 6 + ks) * 512]);
            }
        } else {
            const int nt = wave - 8;
#pragma unroll
            for (int i = 0; i < 2; ++i) {
                const bf16* g = vt_head + (size_t)(nt * 16 + l15) * 2048
                                + kv0 + (i * 4 + quad) * 8;
                load_lds16(g, &Vs[bufi][nt * 1024 + i * 512]);
            }
        }
    };

    f32x4 o[8] = {};
    float m_i = -1e30f, l_i = 0.f;
    const float sm_scale = 0.08838834764831845f * 1.4426950408889634f;
    const int qmin_w = q0 + wave * 16;

    stage(t0, 0);
    stage(t0 + 1, 1);

    int cur = 0;
    for (int kt = t0; kt < t1; ++kt, cur ^= 1) {
        const int kv0 = kt * 64;

        if (kt + 1 < t1) {
            if (wave < 8) asm volatile("s_waitcnt vmcnt(3)" ::: "memory");
            else          asm volatile("s_waitcnt vmcnt(2)" ::: "memory");
        } else {
            asm volatile("s_waitcnt vmcnt(0)" ::: "memory");
        }
        __builtin_amdgcn_s_barrier();
        __builtin_amdgcn_sched_barrier(0);

        f32x4 s[4];
        __builtin_amdgcn_s_setprio(1);
#pragma unroll
        for (int mt = 0; mt < 4; ++mt) {
            f32x4 a = {};
#pragma unroll
            for (int ks = 0; ks < 6; ++ks) {
                bf16x8 kf = *(const bf16x8*)&Ks[cur][(mt * 6 + ks) * 512 + lane * 8];
                a = __builtin_amdgcn_mfma_f32_16x16x32_bf16(kf, qf[ks], a, 0, 0, 0);
            }
            s[mt] = a;
        }
        __builtin_amdgcn_s_setprio(0);

        if (kv0 + 63 > qmin_w) {
#pragma unroll
            for (int mt = 0; mt < 4; ++mt)
#pragma unroll
                for (int r = 0; r < 4; ++r) {
                    int kvi = kv0 + mt * 16 + quad * 4 + r;
                    s[mt][r] = (kvi <= qrow) ? s[mt][r] * sm_scale : -1e30f;
                }
        } else {
#pragma unroll
            for (int mt = 0; mt < 4; ++mt)
#pragma unroll
                for (int r = 0; r < 4; ++r)
                    s[mt][r] = s[mt][r] * sm_scale;
        }
        float mx4[4];
#pragma unroll
        for (int mt = 0; mt < 4; ++mt)
            mx4[mt] = fmaxf(fmaxf(s[mt][0], s[mt][1]),
                            fmaxf(s[mt][2], s[mt][3]));
        float mx = fmaxf(fmaxf(mx4[0], mx4[1]), fmaxf(mx4[2], mx4[3]));
        mx = fmaxf(mx, __shfl_xor(mx, 16, 64));
        mx = fmaxf(mx, __shfl_xor(mx, 32, 64));
        float m_new = fmaxf(m_i, mx);
        float su4[4];
        bf16x4 pf[4];
#pragma unroll
        for (int mt = 0; mt < 4; ++mt) {
            float e0 = exp2f(s[mt][0] - m_new);
            float e1 = exp2f(s[mt][1] - m_new);
            float e2 = exp2f(s[mt][2] - m_new);
            float e3 = exp2f(s[mt][3] - m_new);
            su4[mt] = (e0 + e1) + (e2 + e3);
            pf[mt][0] = (bf16)e0; pf[mt][1] = (bf16)e1;
            pf[mt][2] = (bf16)e2; pf[mt][3] = (bf16)e3;
        }
        float su = (su4[0] + su4[1]) + (su4[2] + su4[3]);
        su += __shfl_xor(su, 16, 64);
        su += __shfl_xor(su, 32, 64);
        if (__all(mx <= m_i)) {
            l_i += su;
        } else {
            float alpha = exp2f(m_i - m_new);
            l_i = l_i * alpha + su;
            m_i = m_new;
            float alpha_r[4];
#pragma unroll
            for (int r = 0; r < 4; ++r)
                alpha_r[r] = __shfl(alpha, quad * 4 + r, 64);
#pragma unroll
            for (int nt = 0; nt < 8; ++nt)
#pragma unroll
                for (int r = 0; r < 4; ++r) o[nt][r] *= alpha_r[r];
        }

        __builtin_amdgcn_s_setprio(1);
#pragma unroll
        for (int ktk = 0; ktk < 4; ++ktk) {
            s16x4 a = __builtin_bit_cast(s16x4, pf[ktk]);
            const int voff = ktk * 256 + (quad >> 1) * 128 + l15 * 8 + (quad & 1) * 4;
#pragma unroll
            for (int nt = 0; nt < 8; ++nt) {
                s16x4 bfv = __builtin_bit_cast(s16x4,
                    *(const bf16x4*)&Vs[cur][nt * 1024 + voff]);
                o[nt] = __builtin_amdgcn_mfma_f32_16x16x16bf16_1k(a, bfv, o[nt], 0, 0, 0);
            }
        }
        __builtin_amdgcn_s_setprio(0);

        __builtin_amdgcn_s_barrier();
        if (kt + 2 < t1) stage(kt + 2, cur);
    }

    // epilogue
    if (np == 1) {
        float l_r[4];
#pragma unroll
        for (int r = 0; r < 4; ++r) l_r[r] = __shfl(l_i, quad * 4 + r, 64);
        bf16* obase = ob + (size_t)(b * S + q0 + wave * 16) * 2048 + h * 128;
#pragma unroll
        for (int nt = 0; nt < 8; ++nt)
#pragma unroll
            for (int r = 0; r < 4; ++r)
                obase[(size_t)(quad * 4 + r) * 2048 + nt * 16 + l15] =
                    (bf16)(o[nt][r] / l_r[r]);
    } else {
        const int bh = b * 16 + h;
        if (quad == 0) {
            const int qlocal = wave * 16 + l15;
            float* mlp = part_ml + ((size_t)(bh * 8 + k) * 4 + c) * 512;
            mlp[qlocal] = m_i;
            mlp[256 + qlocal] = l_i;
        }
        if (c == np - 1) {
            bf16* obase = ob + (size_t)(b * S + q0 + wave * 16) * 2048 + h * 128;
#pragma unroll
            for (int nt = 0; nt < 8; ++nt)
#pragma unroll
                for (int r = 0; r < 4; ++r)
                    obase[(size_t)(quad * 4 + r) * 2048 + nt * 16 + l15] =
                        (bf16)o[nt][r];
        } else {
            bf16* pb = part_o + (size_t)(bh * 12 + pre_of[k] + c) * 32768
                       + (size_t)(wave * 16) * 128;
#pragma unroll
            for (int nt = 0; nt < 8; ++nt)
#pragma unroll
                for (int r = 0; r < 4; ++r)
                    pb[(quad * 4 + r) * 128 + nt * 16 + l15] = (bf16)o[nt][r];
        }
    }
}

// ---------------------------------------------------------------------------
// Merge np partials for q-pair k>=2.
// ---------------------------------------------------------------------------
__global__ __launch_bounds__(256) void mla_merge(
        const bf16* __restrict__ part_o, const float* __restrict__ part_ml,
        bf16* __restrict__ ob) {
    const signed char np_of[8]  = {1,1,2,2,3,3,4,4};
    const signed char pre_of[8] = {0,0,0,1,2,4,6,9};
    const int k = 2 + blockIdx.x;              // 2..7
    const int h = blockIdx.y, b = blockIdx.z;
    const int bh = b * 16 + h;
    const int np = np_of[k];
    const int row = threadIdx.x;               // 0..255

    const float* mlb = part_ml + (size_t)(bh * 8 + k) * 4 * 512;
    const float m0 = mlb[row],            l0 = mlb[256 + row];
    const float m1 = mlb[512 + row],      l1 = mlb[512 + 256 + row];
    const float m2 = (np > 2) ? mlb[1024 + row] : -1e30f;
    const float l2 = (np > 2) ? mlb[1024 + 256 + row] : 0.f;
    const float m3 = (np > 3) ? mlb[1536 + row] : -1e30f;
    const float l3 = (np > 3) ? mlb[1536 + 256 + row] : 0.f;
    const float M = fmaxf(fmaxf(m0, m1), fmaxf(m2, m3));
    float a0 = exp2f(m0 - M), a1 = exp2f(m1 - M);
    float a2 = exp2f(m2 - M), a3 = exp2f(m3 - M);
    const float inv = 1.f / (l0 * a0 + l1 * a1 + l2 * a2 + l3 * a3);
    a0 *= inv; a1 *= inv; a2 *= inv; a3 *= inv;
    const float alast = (np == 2) ? a1 : (np == 3) ? a2 : a3;

    const bf16* p0 = part_o + (size_t)(bh * 12 + pre_of[k]) * 32768 + row * 128;
    const bf16* p1 = p0 + 32768;
    const bf16* p2 = p1 + 32768;
    bf16* po = ob + (size_t)(b * 2048 + k * 256 + row) * 2048 + h * 128;
#pragma unroll
    for (int i = 0; i < 16; ++i) {
        bf16x8 vb = *(const bf16x8*)(po + i * 8);
        bf16x8 v0 = *(const bf16x8*)(p0 + i * 8);
        float acc[8];
#pragma unroll
        for (int u = 0; u < 8; ++u)
            acc[u] = (float)vb[u] * alast + (float)v0[u] * a0;
        if (np > 2) {
            bf16x8 v1 = *(const bf16x8*)(p1 + i * 8);
#pragma unroll
            for (int u = 0; u < 8; ++u) acc[u] += (float)v1[u] * a1;
        }
        if (np > 3) {
            bf16x8 v2 = *(const bf16x8*)(p2 + i * 8);
#pragma unroll
            for (int u = 0; u < 8; ++u) acc[u] += (float)v2[u] * a2;
        }
        bf16x8 om;
#pragma unroll
        for (int u = 0; u < 8; ++u) om[u] = (bf16)acc[u];
        *(bf16x8*)(po + i * 8) = om;
    }
}

// ---------------------------------------------------------------------------
// launch
// ---------------------------------------------------------------------------
extern "C" void kernel_launch(void* const* d_in, const int* in_sizes, int n_in,
                              void* d_out, int out_size, void* d_ws, size_t ws_size,
                              hipStream_t stream) {
    const float* x    = (const float*)d_in[0];
    const float* wqd  = (const float*)d_in[3];
    const float* wqu  = (const float*)d_in[4];
    const float* wkvd = (const float*)d_in[5];
    const float* wkvu = (const float*)d_in[6];
    const float* wout = (const float*)d_in[7];
    float* out = (float*)d_out;
    char* ws = (char*)d_ws;

    bf16* xb    = (bf16*)(ws + 0);          // 4096x2048 ; reused as vtb
    bf16* vtb   = (bf16*)(ws + 0);          // aliases xb; xb dead after gemm_down
    bf16* wqdT  = (bf16*)(ws + 16777216);   // 768x2048  (dead at attention)
    bf16* wkvdT = (bf16*)(ws + 19922944);   // 640x2048  (dead at attention)
    bf16* wquT  = (bf16*)(ws + 22544384);   // 3072x768  (dead at attention)
    bf16* wkvuT = (bf16*)(ws + 27262976);   // 4096x512  (dead at attention)
    float* part_ml = (float*)(ws + 16777216); // 2 MB (aliases dead weights)
    bf16* part_o  = (bf16*)out;             // 24 MB (out dead until final GEMM)
    bf16* woutT = (bf16*)(ws + 31457280);   // 2048x2048
    bf16* qd    = (bf16*)(ws + 39845888);   // 4096x768
    bf16* qb    = (bf16*)(ws + 46137344);   // 4096x3072
    bf16* cb    = (bf16*)(ws + 71303168);   // 4096x640
    bf16* kvb   = (bf16*)(ws + 76546048);   // 4096x4096 (only k_nope halves written)
    bf16* attnb = (bf16*)(ws + 110100480);  // 4096x2048

    prep_fused<<<19456, 256, 0, stream>>>(x, xb, wqd, wqdT, wkvd, wkvdT,
                                          wqu, wquT, wkvu, wkvuT, wout, woutT);

    // 256x128-tile 8-phase down-proj, 3-buffer counted-vmcnt pipeline
    gemm_down256<<<dim3(11, 16), 512, 0, stream>>>(xb, wqdT, qd, cb);
    // 256^2 8-phase up-proj GEMMs with fused V-transpose
    gemm_up256<<<dim3(28, 16), 512, 0, stream>>>(qd, wquT, qb, cb, wkvuT, kvb, vtb);

    mla_attention_split<<<dim3(20, 16, 2), 1024, 0, stream>>>(
        qb, kvb, cb, vtb, attnb, part_o, part_ml);
    mla_merge<<<dim3(6, 16, 2), 256, 0, stream>>>(part_o, part_ml, attnb);

    // 256x128-tile 8-phase output GEMM, 3-buffer counted-vmcnt pipeline
    gemm_out256<<<dim3(16, 16), 512, 0, stream>>>(attnb, woutT, out);
}